// Round 1
// baseline (1997.282 us; speedup 1.0000x reference)
//
#include <hip/hip_runtime.h>
#include <cstdint>
#include <cstddef>

#define LSEQ   1024
#define BATCH  32
#define NFEAT  512
#define DMODEL 512
#define DINNER 1024
#define DSTATE 16
#define DTRANK 32
#define NCLASS 40
#define MROWS  (BATCH * LSEQ)   // 32768
#define NCHUNK 16
#define CLEN   (LSEQ / NCHUNK)  // 64

typedef unsigned short u16;
typedef __attribute__((ext_vector_type(8))) __bf16 bf16x8;
typedef __attribute__((ext_vector_type(4))) float f32x4;
typedef __attribute__((ext_vector_type(8))) unsigned short u16x8;

__device__ __forceinline__ u16 f2bf(float x) {
    union { float f; unsigned u; } v; v.f = x;
    unsigned r = v.u + 0x7fffu + ((v.u >> 16) & 1u);   // round-to-nearest-even
    return (u16)(r >> 16);
}
__device__ __forceinline__ float bf2f(u16 h) {
    union { unsigned u; float f; } v; v.u = ((unsigned)h) << 16;
    return v.f;
}

// dA[s] = g^(s+1), s=0..15, via 4-deep multiply tree (18 muls, no trans).
__device__ __forceinline__ void pow_dA(float g, float* dA) {
    float p2 = g * g, p4 = p2 * p2, p8 = p4 * p4;
    dA[0] = g;        dA[1] = p2;       dA[2] = p2 * g;   dA[3] = p4;
    dA[4] = p4 * g;   dA[5] = p4 * p2;  dA[6] = p4 * dA[2]; dA[7] = p8;
    dA[8] = p8 * g;   dA[9] = p8 * p2;  dA[10] = p8 * dA[2]; dA[11] = p8 * p4;
    dA[12] = p8 * dA[4]; dA[13] = p8 * dA[5]; dA[14] = p8 * dA[6]; dA[15] = p8 * p8;
}

// unpack 8 bf16 (packed in uint4) -> 8 floats; scalar-friendly (shift/and)
__device__ __forceinline__ void unpack8(uint4 w, float* f) {
    union { unsigned u; float v; } c;
    c.u = w.x << 16;         f[0] = c.v;
    c.u = w.x & 0xffff0000u; f[1] = c.v;
    c.u = w.y << 16;         f[2] = c.v;
    c.u = w.y & 0xffff0000u; f[3] = c.v;
    c.u = w.z << 16;         f[4] = c.v;
    c.u = w.z & 0xffff0000u; f[5] = c.v;
    c.u = w.w << 16;         f[6] = c.v;
    c.u = w.w & 0xffff0000u; f[7] = c.v;
}

#define GLL16(g, l) __builtin_amdgcn_global_load_lds( \
    (__attribute__((address_space(1))) void*)(g),     \
    (__attribute__((address_space(3))) void*)(l), 16, 0, 0)

// ---------------------------------------------------------------------------
// 256x256 8-phase GEMM (HK-style schedule, plain HIP).
// C[M,N] = A[M,K](bf16,lda) * B[N,K](bf16,ldb)^T (+bias) (+silu for col>=silu_from)
// BK=64, 512 threads (8 waves, 2M x 4N), per-wave 128x64 output.
// LDS 128 KiB: As/Bs[2][256][64] bf16, double-buffered.
// Swizzle: 16B block index ^= (row&7); GLL stages linear LDS with
// inverse-swizzled global source; ds_read applies the same XOR (involution).
// Per K-tile, 4 phases: {ds_read subtile | stage 2 quarter-regions |
// barrier | lgkmcnt(0) | 16 MFMA (setprio) | barrier}. Region staged in the
// same phase its last read completes:
//   P1 reads af0(Aq0/Aq2)+bf0  -> stage Aq0,Aq2 of tile t+2
//   P2 reads bf1 (B done)      -> stage Bq0,Bq1
//   P3 reads af1(Aq1/Aq3)      -> stage Aq1,Aq3
//   P4 (no reads)              -> stage Bq2,Bq3 ; vmcnt(8) (tile t+1 landed,
//                                 8 loads of t+2 still in flight)
// ---------------------------------------------------------------------------
template<int OUT_BF16, int ACCUM>
__global__ __launch_bounds__(512, 2) void gemm256(
    const u16* __restrict__ A, int lda,
    const u16* __restrict__ B, int ldb,
    void* __restrict__ Cv, int ldc,
    const float* __restrict__ bias, int K, int silu_from)
{
    __shared__ __align__(16) u16 As[2][256 * 64];
    __shared__ __align__(16) u16 Bs[2][256 * 64];
    const int tid  = threadIdx.x;
    const int lane = tid & 63;
    const int wave = tid >> 6;            // 0..7
    const int wr   = (wave >> 2) * 128;   // 0 or 128
    const int wc   = (wave & 3) * 64;     // 0,64,128,192
    const int frow = lane & 15;
    const int quad = lane >> 4;
    const int m0   = blockIdx.x * 256;
    const int n0   = blockIdx.y * 256;

    // staging map (constant per thread): one GLL sweep = 8KB = 64 rows
    const int srow = tid >> 3;                   // row within quarter (0..63)
    const int slb  = (tid & 7) ^ (srow & 7);     // logical 16B-block (inverse swz)
    const u16* gA = A + (size_t)(m0 + srow) * lda + slb * 8;
    const u16* gB = B + (size_t)(n0 + srow) * ldb + slb * 8;

    // read-side per-lane swizzled k-offsets (u16 units)
    const int cb0 = ((quad)     ^ (frow & 7)) * 8;   // kk=0
    const int cb1 = ((4 + quad) ^ (frow & 7)) * 8;   // kk=1

#define STAGE_A(sb, tt, q) GLL16(gA + (size_t)(q) * 64 * lda + (size_t)(tt) * 64, \
                                 &As[sb][(q) * 4096 + tid * 8])
#define STAGE_B(sb, tt, q) GLL16(gB + (size_t)(q) * 64 * ldb + (size_t)(tt) * 64, \
                                 &Bs[sb][(q) * 4096 + tid * 8])

    f32x4 acc[8][4];
#pragma unroll
    for (int i = 0; i < 8; ++i)
#pragma unroll
        for (int j = 0; j < 4; ++j) acc[i][j] = (f32x4){0.f, 0.f, 0.f, 0.f};

    const int NT = K >> 6;

    // prologue: stage tiles 0 and 1 (8 loads each), wait tile 0
#pragma unroll
    for (int q = 0; q < 4; ++q) STAGE_A(0, 0, q);
#pragma unroll
    for (int q = 0; q < 4; ++q) STAGE_B(0, 0, q);
#pragma unroll
    for (int q = 0; q < 4; ++q) STAGE_A(1, 1, q);
#pragma unroll
    for (int q = 0; q < 4; ++q) STAGE_B(1, 1, q);
    asm volatile("s_waitcnt vmcnt(8)" ::: "memory");
    __builtin_amdgcn_s_barrier();

    for (int t = 0; t < NT; ++t) {
        const int bsel = t & 1;
        const u16* __restrict__ Ab = &As[bsel][0];
        const u16* __restrict__ Bb = &Bs[bsel][0];
        const int stage = (t + 2 < NT);
        const int t2 = t + 2;
        const int rA = wr + frow;
        const int rB = wc + frow;
        bf16x8 af[4][2], b0[2][2], b1[2][2];

        // ---- P1: read af0 (M-half0) + bf0 (N-half0); stage Aq0,Aq2 ----
#pragma unroll
        for (int m = 0; m < 4; ++m) {
            const u16* p = Ab + (rA + m * 16) * 64;
            af[m][0] = *(const bf16x8*)(p + cb0);
            af[m][1] = *(const bf16x8*)(p + cb1);
        }
#pragma unroll
        for (int n = 0; n < 2; ++n) {
            const u16* p = Bb + (rB + n * 16) * 64;
            b0[n][0] = *(const bf16x8*)(p + cb0);
            b0[n][1] = *(const bf16x8*)(p + cb1);
        }
        if (stage) { STAGE_A(bsel, t2, 0); STAGE_A(bsel, t2, 2); }
        __builtin_amdgcn_s_barrier();
        asm volatile("s_waitcnt lgkmcnt(0)" ::: "memory");
        __builtin_amdgcn_sched_barrier(0);
        __builtin_amdgcn_s_setprio(1);
#pragma unroll
        for (int m = 0; m < 4; ++m)
#pragma unroll
            for (int n = 0; n < 2; ++n) {
                acc[m][n] = __builtin_amdgcn_mfma_f32_16x16x32_bf16(af[m][0], b0[n][0], acc[m][n], 0, 0, 0);
                acc[m][n] = __builtin_amdgcn_mfma_f32_16x16x32_bf16(af[m][1], b0[n][1], acc[m][n], 0, 0, 0);
            }
        __builtin_amdgcn_s_setprio(0);
        __builtin_amdgcn_s_barrier();

        // ---- P2: read bf1 (N-half1); stage Bq0,Bq1 ----
#pragma unroll
        for (int n = 0; n < 2; ++n) {
            const u16* p = Bb + (rB + 32 + n * 16) * 64;
            b1[n][0] = *(const bf16x8*)(p + cb0);
            b1[n][1] = *(const bf16x8*)(p + cb1);
        }
        if (stage) { STAGE_B(bsel, t2, 0); STAGE_B(bsel, t2, 1); }
        __builtin_amdgcn_s_barrier();
        asm volatile("s_waitcnt lgkmcnt(0)" ::: "memory");
        __builtin_amdgcn_sched_barrier(0);
        __builtin_amdgcn_s_setprio(1);
#pragma unroll
        for (int m = 0; m < 4; ++m)
#pragma unroll
            for (int n = 0; n < 2; ++n) {
                acc[m][2 + n] = __builtin_amdgcn_mfma_f32_16x16x32_bf16(af[m][0], b1[n][0], acc[m][2 + n], 0, 0, 0);
                acc[m][2 + n] = __builtin_amdgcn_mfma_f32_16x16x32_bf16(af[m][1], b1[n][1], acc[m][2 + n], 0, 0, 0);
            }
        __builtin_amdgcn_s_setprio(0);
        __builtin_amdgcn_s_barrier();

        // ---- P3: read af1 (M-half1, overwrite af regs); stage Aq1,Aq3 ----
#pragma unroll
        for (int m = 0; m < 4; ++m) {
            const u16* p = Ab + (rA + 64 + m * 16) * 64;
            af[m][0] = *(const bf16x8*)(p + cb0);
            af[m][1] = *(const bf16x8*)(p + cb1);
        }
        if (stage) { STAGE_A(bsel, t2, 1); STAGE_A(bsel, t2, 3); }
        __builtin_amdgcn_s_barrier();
        asm volatile("s_waitcnt lgkmcnt(0)" ::: "memory");
        __builtin_amdgcn_sched_barrier(0);
        __builtin_amdgcn_s_setprio(1);
#pragma unroll
        for (int m = 0; m < 4; ++m)
#pragma unroll
            for (int n = 0; n < 2; ++n) {
                acc[4 + m][2 + n] = __builtin_amdgcn_mfma_f32_16x16x32_bf16(af[m][0], b1[n][0], acc[4 + m][2 + n], 0, 0, 0);
                acc[4 + m][2 + n] = __builtin_amdgcn_mfma_f32_16x16x32_bf16(af[m][1], b1[n][1], acc[4 + m][2 + n], 0, 0, 0);
            }
        __builtin_amdgcn_s_setprio(0);
        __builtin_amdgcn_s_barrier();

        // ---- P4: no reads (bf0 live); stage Bq2,Bq3; counted vmcnt ----
        if (stage) {
            STAGE_B(bsel, t2, 2); STAGE_B(bsel, t2, 3);
            asm volatile("s_waitcnt vmcnt(8)" ::: "memory");
        } else {
            asm volatile("s_waitcnt vmcnt(0)" ::: "memory");
        }
        __builtin_amdgcn_s_barrier();
        __builtin_amdgcn_s_setprio(1);
#pragma unroll
        for (int m = 0; m < 4; ++m)
#pragma unroll
            for (int n = 0; n < 2; ++n) {
                acc[4 + m][n] = __builtin_amdgcn_mfma_f32_16x16x32_bf16(af[m][0], b0[n][0], acc[4 + m][n], 0, 0, 0);
                acc[4 + m][n] = __builtin_amdgcn_mfma_f32_16x16x32_bf16(af[m][1], b0[n][1], acc[4 + m][n], 0, 0, 0);
            }
        __builtin_amdgcn_s_setprio(0);
        __builtin_amdgcn_s_barrier();
    }
#undef STAGE_A
#undef STAGE_B

    // epilogue
    float bv[4];
#pragma unroll
    for (int n = 0; n < 4; ++n) {
        int col = n0 + wc + (n >> 1) * 32 + (n & 1) * 16 + frow;
        bv[n] = bias ? bias[col] : 0.f;
    }
#pragma unroll
    for (int m = 0; m < 8; ++m) {
        size_t row0 = (size_t)(m0 + wr + (m >> 2) * 64 + (m & 3) * 16 + quad * 4);
#pragma unroll
        for (int r = 0; r < 4; ++r) {
#pragma unroll
            for (int n = 0; n < 4; ++n) {
                int col = n0 + wc + (n >> 1) * 32 + (n & 1) * 16 + frow;
                size_t cidx = (row0 + r) * (size_t)ldc + (size_t)col;
                float v = acc[m][n][r] + bv[n];
                if (col >= silu_from) v = v / (1.f + expf(-v));
                if (OUT_BF16)      ((u16*)Cv)[cidx] = f2bf(v);
                else if (ACCUM)    ((float*)Cv)[cidx] += v;
                else               ((float*)Cv)[cidx] = v;
            }
        }
    }
}

// ---------------------------------------------------------------------------
// C[M,N] = A[M,K](bf16,lda) * B[N,K](bf16,ldb)^T  (+bias) (+softplus) ;
// OUT_BF16: store bf16; ACCUM: f32 +=. 128x128 tile, BK=32, 256 thr (4 waves).
// Kept for x_proj (N=128) and dt_proj (K=32).
// ---------------------------------------------------------------------------
template<int OUT_BF16, int ACCUM, int ACT>
__global__ __launch_bounds__(256) void gemm_bt(
    const u16* __restrict__ A, int lda,
    const u16* __restrict__ B, int ldb,
    void* __restrict__ Cv, int ldc,
    const float* __restrict__ bias, int K)
{
    __shared__ __align__(16) u16 As[128 * 32];
    __shared__ __align__(16) u16 Bs[128 * 32];
    const int tid  = threadIdx.x;
    const int m0   = blockIdx.x * 128;
    const int n0   = blockIdx.y * 128;
    const int r0   = tid >> 2;            // staging row (0..63), +64 for job 1
    const int c0   = (tid & 3) << 3;      // staging k-chunk (0,8,16,24)
    const int lane = tid & 63;
    const int wave = tid >> 6;
    const int wr   = (wave >> 1) << 6;    // wave row offset in tile
    const int wc   = (wave & 1) << 6;     // wave col offset in tile
    const int frow = lane & 15;
    const int fk   = (lane >> 4) << 3;
    const int quad = lane >> 4;

    const u16* Ap0 = A + (size_t)(m0 + r0) * lda + c0;
    const u16* Ap1 = Ap0 + (size_t)64 * lda;
    const u16* Bp0 = B + (size_t)(n0 + r0) * ldb + c0;
    const u16* Bp1 = Bp0 + (size_t)64 * ldb;
    u16* lA0 = As + tid * 8;  u16* lA1 = As + (tid + 256) * 8;
    u16* lB0 = Bs + tid * 8;  u16* lB1 = Bs + (tid + 256) * 8;

    f32x4 acc[4][4];
#pragma unroll
    for (int i = 0; i < 4; ++i)
#pragma unroll
        for (int j = 0; j < 4; ++j) acc[i][j] = (f32x4){0.f, 0.f, 0.f, 0.f};

    for (int k0 = 0; k0 < K; k0 += 32) {
        GLL16(Ap0 + k0, lA0);
        GLL16(Ap1 + k0, lA1);
        GLL16(Bp0 + k0, lB0);
        GLL16(Bp1 + k0, lB1);
        __syncthreads();
        bf16x8 af[4], bfr[4];
#pragma unroll
        for (int i = 0; i < 4; ++i) {
            af[i]  = *(const bf16x8*)(As + (wr + i * 16 + frow) * 32 + fk);
            bfr[i] = *(const bf16x8*)(Bs + (wc + i * 16 + frow) * 32 + fk);
        }
#pragma unroll
        for (int i = 0; i < 4; ++i)
#pragma unroll
            for (int j = 0; j < 4; ++j)
                acc[i][j] = __builtin_amdgcn_mfma_f32_16x16x32_bf16(
                    af[i], bfr[j], acc[i][j], 0, 0, 0);
        __syncthreads();
    }

    float bv[4];
#pragma unroll
    for (int j = 0; j < 4; ++j)
        bv[j] = bias ? bias[n0 + wc + j * 16 + frow] : 0.f;

#pragma unroll
    for (int i = 0; i < 4; ++i) {
#pragma unroll
        for (int r = 0; r < 4; ++r) {
            size_t row = (size_t)(m0 + wr + i * 16 + quad * 4 + r);
#pragma unroll
            for (int j = 0; j < 4; ++j) {
                size_t cidx = row * (size_t)ldc + (size_t)(n0 + wc + j * 16 + frow);
                float v = acc[i][j][r] + bv[j];
                if (ACT == 1) v = (v > 15.f) ? v : log1pf(expf(v));  // softplus
                if (OUT_BF16)      ((u16*)Cv)[cidx] = f2bf(v);
                else if (ACCUM)    ((float*)Cv)[cidx] += v;
                else               ((float*)Cv)[cidx] = v;
            }
        }
    }
}

// --------------------------- elementwise / prep ----------------------------

__global__ __launch_bounds__(256) void cvt_bf16_kernel(
    const float* __restrict__ src, u16* __restrict__ dst, int n4)
{
    int i = blockIdx.x * 256 + threadIdx.x;
    if (i >= n4) return;
    float4 v = ((const float4*)src)[i];
    ushort4 o; o.x = f2bf(v.x); o.y = f2bf(v.y); o.z = f2bf(v.z); o.w = f2bf(v.w);
    ((ushort4*)dst)[i] = o;
}

// x_proj_w (2,64,1024) f32 -> (2,128,1024) bf16, rows 64..127 zero
__global__ __launch_bounds__(256) void pad_xpw_kernel(
    const float* __restrict__ src, u16* __restrict__ dst)
{
    int i  = blockIdx.x * 256 + threadIdx.x;   // per float4; total 2*128*1024/4
    int k4 = i & 255;
    int r  = (i >> 8) & 127;
    int l  = i >> 15;
    ushort4 o;
    if (r < 64) {
        float4 v = ((const float4*)(src + ((size_t)l * 64 + r) * DINNER))[k4];
        o.x = f2bf(v.x); o.y = f2bf(v.y); o.z = f2bf(v.z); o.w = f2bf(v.w);
    } else { o.x = 0; o.y = 0; o.z = 0; o.w = 0; }
    ((ushort4*)dst)[i] = o;
}

// gathered_emb[m,:] = bf16(embeddings[sequence[m],:])
__global__ __launch_bounds__(256) void gather_kernel(
    const int* __restrict__ seq, const float* __restrict__ emb, u16* __restrict__ g)
{
    int i   = blockIdx.x * 256 + threadIdx.x;  // per float4; total MROWS*128
    int row = i >> 7, c = i & 127;
    int node = seq[row];
    float4 v = ((const float4*)(emb + (size_t)node * NFEAT))[c];
    ushort4 o; o.x = f2bf(v.x); o.y = f2bf(v.y); o.z = f2bf(v.z); o.w = f2bf(v.w);
    ((ushort4*)g)[i] = o;
}

// zi = scale * x / (||x||/sqrt(512) + 1e-8), one wave per row
__global__ __launch_bounds__(256) void rmsnorm_kernel(
    const float* __restrict__ x, const float* __restrict__ scale, u16* __restrict__ o)
{
    int wave = threadIdx.x >> 6, lane = threadIdx.x & 63;
    size_t row = (size_t)blockIdx.x * 4 + wave;
    const float4* xr = (const float4*)(x + row * DMODEL);
    float4 v0 = xr[lane], v1 = xr[lane + 64];
    float ss = v0.x*v0.x + v0.y*v0.y + v0.z*v0.z + v0.w*v0.w
             + v1.x*v1.x + v1.y*v1.y + v1.z*v1.z + v1.w*v1.w;
#pragma unroll
    for (int off = 32; off; off >>= 1) ss += __shfl_xor(ss, off, 64);
    float inv = 1.f / (sqrtf(ss * (1.f / DMODEL)) + 1e-8f);
    const float4* sc = (const float4*)scale;
    float4 s0 = sc[lane], s1 = sc[lane + 64];
    ushort4 o0, o1;
    o0.x = f2bf(v0.x * s0.x * inv); o0.y = f2bf(v0.y * s0.y * inv);
    o0.z = f2bf(v0.z * s0.z * inv); o0.w = f2bf(v0.w * s0.w * inv);
    o1.x = f2bf(v1.x * s1.x * inv); o1.y = f2bf(v1.y * s1.y * inv);
    o1.z = f2bf(v1.z * s1.z * inv); o1.w = f2bf(v1.w * s1.w * inv);
    ushort4* op = (ushort4*)(o + row * DMODEL);
    op[lane] = o0; op[lane + 64] = o1;
}

// causal depthwise conv (window 4) + bias + silu on x-half; 8 channels/thread.
// z-half already silu'd by in_proj GEMM epilogue.
__global__ __launch_bounds__(256) void conv_silu_kernel(
    const u16* __restrict__ xz,
    const float* __restrict__ w, const float* __restrict__ cbv,
    u16* __restrict__ xc)
{
    int i  = blockIdx.x * 256 + threadIdx.x;   // MROWS*128 total
    int d0 = (i & 127) << 3;
    int r  = i >> 7;
    int l  = r & (LSEQ - 1);
    const u16* bx = xz + (size_t)r * (2 * DINNER) + d0;
    u16x8 zero{};
    u16x8 t3 = *(const u16x8*)(bx);
    u16x8 t2 = (l >= 1) ? *(const u16x8*)(bx - 2 * DINNER) : zero;
    u16x8 t1 = (l >= 2) ? *(const u16x8*)(bx - 4 * DINNER) : zero;
    u16x8 t0 = (l >= 3) ? *(const u16x8*)(bx - 6 * DINNER) : zero;
    u16x8 oc;
#pragma unroll
    for (int c = 0; c < 8; ++c) {
        float4 wc = ((const float4*)w)[d0 + c];
        float acc = cbv[d0 + c]
                  + wc.x * bf2f(t0[c]) + wc.y * bf2f(t1[c])
                  + wc.z * bf2f(t2[c]) + wc.w * bf2f(t3[c]);
        oc[c] = f2bf(acc / (1.f + expf(-acc)));
    }
    *(u16x8*)(xc + (size_t)r * DINNER + d0) = oc;
}

// ---------------------------------------------------------------------------
// Chunked selective scan, v3 (unchanged).
// ---------------------------------------------------------------------------
__device__ __forceinline__ int detect_s4d(const float* a2) {
    int fast = 1;
#pragma unroll
    for (int s = 1; s < DSTATE; ++s)
        fast &= (__builtin_fabsf(a2[s] - (float)(s + 1) * a2[0]) <=
                 1e-4f * (float)(s + 1) * __builtin_fabsf(a2[0]) + 1e-6f);
    return fast;
}

__global__ __launch_bounds__(256) void scan_p1(
    const u16* __restrict__ delta, const u16* __restrict__ xconv,
    const u16* __restrict__ xdbl, const float* __restrict__ alog,
    float* __restrict__ states, float* __restrict__ dtsums)
{
    const int bid = blockIdx.x;
    const int d0  = (bid & 3) << 8;
    const int k   = (bid >> 2) & (NCHUNK - 1);
    const int b   = bid >> 6;
    const int d   = d0 + threadIdx.x;

    float a2[DSTATE];
#pragma unroll
    for (int s = 0; s < DSTATE; ++s)
        a2[s] = -expf(alog[d * DSTATE + s]) * 1.44269504f;
    const int fastA = detect_s4d(a2);
    const float ab = a2[0];

    float h[DSTATE];
#pragma unroll
    for (int s = 0; s < DSTATE; ++s) h[s] = 0.f;
    float dtsum = 0.f;

    const size_t r0 = (size_t)b * LSEQ + (size_t)k * CLEN;
    const u16* pd = delta + r0 * DINNER + d;
    const u16* px = xconv + r0 * DINNER + d;
    const unsigned* pB = (const unsigned*)(xdbl + r0 * 128) + 16;  // uniform

    float dt = bf2f(*pd), xv = bf2f(*px);
    uint4 wB  = *(const uint4*)(pB);
    uint4 wB2 = *(const uint4*)(pB + 4);

    if (fastA) {
        for (int j = 0; j < CLEN; ++j) {
            pd += DINNER; px += DINNER; pB += 64;
            float dt_n = bf2f(*pd), xv_n = bf2f(*px);
            uint4 wBn  = *(const uint4*)(pB);
            uint4 wB2n = *(const uint4*)(pB + 4);
            float dx = dt * xv;
            dtsum += dt;
            float dA[DSTATE];
            pow_dA(__builtin_amdgcn_exp2f(dt * ab), dA);
            float Bv[DSTATE];
            unpack8(wB, Bv); unpack8(wB2, Bv + 8);
#pragma unroll
            for (int s = 0; s < DSTATE; ++s)
                h[s] = __builtin_fmaf(h[s], dA[s], dx * Bv[s]);
            dt = dt_n; xv = xv_n; wB = wBn; wB2 = wB2n;
        }
    } else {
        for (int j = 0; j < CLEN; ++j) {
            pd += DINNER; px += DINNER; pB += 64;
            float dt_n = bf2f(*pd), xv_n = bf2f(*px);
            uint4 wBn  = *(const uint4*)(pB);
            uint4 wB2n = *(const uint4*)(pB + 4);
            float dx = dt * xv;
            dtsum += dt;
            float Bv[DSTATE];
            unpack8(wB, Bv); unpack8(wB2, Bv + 8);
#pragma unroll
            for (int s = 0; s < DSTATE; ++s)
                h[s] = __builtin_fmaf(h[s], __builtin_amdgcn_exp2f(dt * a2[s]),
                                      dx * Bv[s]);
            dt = dt_n; xv = xv_n; wB = wBn; wB2 = wB2n;
        }
    }

    size_t t = (size_t)(b * NCHUNK + k) * DINNER + d;
    f32x4* st = (f32x4*)(states + t * DSTATE);
#pragma unroll
    for (int q = 0; q < 4; ++q)
        st[q] = (f32x4){h[q * 4], h[q * 4 + 1], h[q * 4 + 2], h[q * 4 + 3]};
    dtsums[t] = dtsum;
}

__global__ __launch_bounds__(256) void scan_p2(
    float* __restrict__ states, const float* __restrict__ dtsums,
    const float* __restrict__ alog)
{
    int t = blockIdx.x * 256 + threadIdx.x;   // 0 .. B*DINNER*DSTATE-1
    int s = t & (DSTATE - 1);
    int d = (t >> 4) & (DINNER - 1);
    int b = t >> 14;
    float a2 = -expf(alog[d * DSTATE + s]) * 1.44269504f;
    float H = 0.f;
    for (int k = 0; k < NCHUNK; ++k) {
        size_t ci = ((size_t)b * NCHUNK + k) * DINNER + d;
        size_t idx = ci * DSTATE + s;
        float hk = states[idx];
        float P = __builtin_amdgcn_exp2f(a2 * dtsums[ci]);
        states[idx] = H;                 // exclusive incoming state for chunk k
        H = hk + P * H;
    }
}

__global__ __launch_bounds__(256) void scan_p3(
    const u16* __restrict__ delta, const u16* __restrict__ xconv,
    const u16* __restrict__ zsil, const u16* __restrict__ xdbl,
    const float* __restrict__ alog, const float* __restrict__ Dvec,
    const float* __restrict__ states, u16* __restrict__ ybuf)
{
    const int bid = blockIdx.x;
    const int d0  = (bid & 3) << 8;
    const int k   = (bid >> 2) & (NCHUNK - 1);
    const int b   = bid >> 6;
    const int d   = d0 + threadIdx.x;

    float a2[DSTATE];
#pragma unroll
    for (int s = 0; s < DSTATE; ++s)
        a2[s] = -expf(alog[d * DSTATE + s]) * 1.44269504f;
    const int fastA = detect_s4d(a2);
    const float ab = a2[0];
    const float Dd = Dvec[d];

    float h[DSTATE];
    size_t t = (size_t)(b * NCHUNK + k) * DINNER + d;
    const f32x4* st = (const f32x4*)(states + t * DSTATE);
#pragma unroll
    for (int q = 0; q < 4; ++q) {
        f32x4 v = st[q];
        h[q * 4] = v[0]; h[q * 4 + 1] = v[1]; h[q * 4 + 2] = v[2]; h[q * 4 + 3] = v[3];
    }

    const size_t r0 = (size_t)b * LSEQ + (size_t)k * CLEN;
    const u16* pd = delta + r0 * DINNER + d;
    const u16* px = xconv + r0 * DINNER + d;
    const u16* pz = zsil + r0 * (2 * DINNER) + DINNER + d;
    const unsigned* pB = (const unsigned*)(xdbl + r0 * 128) + 16;  // uniform
    u16* py = ybuf + r0 * DINNER + d;

    float dt = bf2f(*pd), xv = bf2f(*px), zs = bf2f(*pz);
    uint4 wB  = *(const uint4*)(pB);
    uint4 wB2 = *(const uint4*)(pB + 4);
    uint4 wC  = *(const uint4*)(pB + 8);
    uint4 wC2 = *(const uint4*)(pB + 12);

    if (fastA) {
        for (int j = 0; j < CLEN; ++j) {
            pd += DINNER; px += DINNER; pz += 2 * DINNER; pB += 64;
            float dt_n = bf2f(*pd), xv_n = bf2f(*px), zs_n = bf2f(*pz);
            uint4 wBn  = *(const uint4*)(pB);
            uint4 wB2n = *(const uint4*)(pB + 4);
            uint4 wCn  = *(const uint4*)(pB + 8);
            uint4 wC2n = *(const uint4*)(pB + 12);
            float dx = dt * xv;
            float dA[DSTATE];
            pow_dA(__builtin_amdgcn_exp2f(dt * ab), dA);
            float Bv[DSTATE], Cv[DSTATE];
            unpack8(wB, Bv); unpack8(wB2, Bv + 8);
            unpack8(wC, Cv); unpack8(wC2, Cv + 8);
            float y0 = 0.f, y1 = 0.f, y2 = 0.f, y3 = 0.f;
#pragma unroll
            for (int s = 0; s < DSTATE; ++s)
                h[s] = __builtin_fmaf(h[s], dA[s], dx * Bv[s]);
#pragma unroll
            for (int s = 0; s < DSTATE; s += 4) {
                y0 = __builtin_fmaf(h[s],     Cv[s],     y0);
                y1 = __builtin_fmaf(h[s + 1], Cv[s + 1], y1);
                y2 = __builtin_fmaf(h[s + 2], Cv[s + 2], y2);
                y3 = __builtin_fmaf(h[s + 3], Cv[s + 3], y3);
            }
            float yv = ((y0 + y1) + (y2 + y3)) + Dd * xv;
            *py = f2bf(yv * zs); py += DINNER;
            dt = dt_n; xv = xv_n; zs = zs_n;
            wB = wBn; wB2 = wB2n; wC = wCn; wC2 = wC2n;
        }
    } else {
        for (int j = 0; j < CLEN; ++j) {
            pd += DINNER; px += DINNER; pz += 2 * DINNER; pB += 64;
            float dt_n = bf2f(*pd), xv_n = bf2f(*px), zs_n = bf2f(*pz);
            uint4 wBn  = *(const uint4*)(pB);
            uint4 wB2n = *(const uint4*)(pB + 4);
            uint4 wCn  = *(const uint4*)(pB + 8);
            uint4 wC2n = *(const uint4*)(pB + 12);
            float dx = dt * xv;
            float Bv[DSTATE], Cv[DSTATE];
            unpack8(wB, Bv); unpack8(wB2, Bv + 8);
            unpack8(wC, Cv); unpack8(wC2, Cv + 8);
            float y0 = 0.f, y1 = 0.f, y2 = 0.f, y3 = 0.f;
#pragma unroll
            for (int s = 0; s < DSTATE; ++s) {
                h[s] = __builtin_fmaf(h[s], __builtin_amdgcn_exp2f(dt * a2[s]),
                                      dx * Bv[s]);
            }
#pragma unroll
            for (int s = 0; s < DSTATE; s += 4) {
                y0 = __builtin_fmaf(h[s],     Cv[s],     y0);
                y1 = __builtin_fmaf(h[s + 1], Cv[s + 1], y1);
                y2 = __builtin_fmaf(h[s + 2], Cv[s + 2], y2);
                y3 = __builtin_fmaf(h[s + 3], Cv[s + 3], y3);
            }
            float yv = ((y0 + y1) + (y2 + y3)) + Dd * xv;
            *py = f2bf(yv * zs); py += DINNER;
            dt = dt_n; xv = xv_n; zs = zs_n;
            wB = wBn; wB2 = wB2n; wC = wCn; wC2 = wC2n;
        }
    }
}

// masked-mean partials: grid (8 chunks, 32 b)
__global__ __launch_bounds__(256) void pool_partial_kernel(
    const float* __restrict__ subg, const float* __restrict__ incl,
    float* __restrict__ part, float* __restrict__ msump)
{
    int chunk = blockIdx.x, b = blockIdx.y, tid = threadIdx.x;
    float a0 = 0.f, a1 = 0.f, ms = 0.f;
    for (int l0 = 0; l0 < 128; ++l0) {
        int l = chunk * 128 + l0;
        float m = incl[b * LSEQ + l];
        const float* row = subg + ((size_t)b * LSEQ + l) * DMODEL;
        a0 += m * row[tid];
        a1 += m * row[tid + 256];
        ms += m;
    }
    int pi = (b * 8 + chunk) * DMODEL;
    part[pi + tid] = a0;
    part[pi + tid + 256] = a1;
    if (tid == 0) msump[b * 8 + chunk] = ms;
}

__global__ __launch_bounds__(256) void fc2_kernel(
    const float* __restrict__ part, const float* __restrict__ msump,
    const float* __restrict__ fc2w, const float* __restrict__ fc2b,
    float* __restrict__ out)
{
    int b = blockIdx.x, tid = threadIdx.x;
    __shared__ float pooled[DMODEL];
    float s0 = 0.f, s1 = 0.f, ms = 0.f;
#pragma unroll
    for (int c = 0; c < 8; ++c) {
        s0 += part[(b * 8 + c) * DMODEL + tid];
        s1 += part[(b * 8 + c) * DMODEL + tid + 256];
        ms += msump[b * 8 + c];
    }
    float inv = 1.f / (ms + 1e-5f);
    pooled[tid] = s0 * inv; pooled[tid + 256] = s1 * inv;
    __syncthreads();
    int wave = tid >> 6, lane = tid & 63;
    for (int c = wave; c < NCLASS; c += 4) {
        float s = 0.f;
#pragma unroll
        for (int k = lane; k < DMODEL; k += 64) s += pooled[k] * fc2w[c * DMODEL + k];
#pragma unroll
        for (int off = 32; off; off >>= 1) s += __shfl_xor(s, off, 64);
        if (lane == 0) out[b * NCLASS + c] = s + fc2b[c];
    }
}

// ---------------------------------------------------------------------------

extern "C" void kernel_launch(void* const* d_in, const int* in_sizes, int n_in,
                              void* d_out, int out_size, void* d_ws, size_t ws_size,
                              hipStream_t stream)
{
    (void)in_sizes; (void)n_in; (void)out_size; (void)ws_size;
    const int*   seq    = (const int*)  d_in[0];
    const float* incl   = (const float*)d_in[1];
    const float* emb    = (const float*)d_in[2];
    const float* fc1w   = (const float*)d_in[3];
    const float* fc1b   = (const float*)d_in[4];
    const float* fc2w   = (const float*)d_in[5];
    const float* fc2b   = (const float*)d_in[6];
    const float* nscale = (const float*)d_in[7];
    const float* ipw    = (const float*)d_in[8];
    const float* cw     = (const float*)d_in[9];
    const float* cbv    = (const float*)d_in[10];
    const float* xpw    = (const float*)d_in[11];
    const float* dtw    = (const float*)d_in[12];
    const float* dtb    = (const float*)d_in[13];
    const float* alog   = (const float*)d_in[14];
    const float* Dvec   = (const float*)d_in[15];
    const float* opw    = (const float*)d_in[16];
    float* outp = (float*)d_out;

    char* w = (char*)d_ws;
    size_t off = 0;
    auto take = [&](size_t bytes) {
        char* p = w + off; off += (bytes + 255) & ~(size_t)255; return p;
    };
    float* subg  = (float*)take((size_t)MROWS * DMODEL * 4);       // fp32 residual stream
    u16*   zi    = (u16*)  take((size_t)MROWS * DMODEL * 2);       // rmsnorm out (33.5MB)
    u16*   xzb   = (u16*)  take((size_t)MROWS * 2 * DINNER * 2);   // in_proj out (xin|silu(z))
    u16*   xconv = (u16*)  take((size_t)MROWS * DINNER * 2);       // conv+silu out
    u16*   xdbl  = (u16*)  take((size_t)MROWS * 128 * 2);          // x_proj out (pad 128)
    u16*   delta = (u16*)  take((size_t)MROWS * DINNER * 2);       // softplus(dt_proj)
    u16*   ybuf  = (u16*)  take((size_t)MROWS * DINNER * 2);       // scan out (gated)
    u16*   wip   = (u16*)  take((size_t)2 * 2 * DINNER * DMODEL * 2);
    u16*   wop   = (u16*)  take((size_t)2 * DMODEL * DINNER * 2);
    u16*   wxp   = (u16*)  take((size_t)2 * 128 * DINNER * 2);
    u16*   wdt   = (u16*)  take((size_t)2 * DINNER * DTRANK * 2);
    u16*   wfc1  = (u16*)  take((size_t)DMODEL * NFEAT * 2);
    float* part  = (float*)take((size_t)BATCH * 8 * DMODEL * 4);
    float* msump = (float*)take((size_t)BATCH * 8 * 4);
    float* dtsums= (float*)take((size_t)BATCH * NCHUNK * DINNER * 4);  // 2 MB
    u16*   gemb  = (u16*)delta;   // alias: gathered emb consumed before delta written
    float* states= (float*)zi;    // alias: zi dead after in_proj GEMM each layer (same 33.5MB)

    const int NOSILU = 0x7fffffff;

    // weight prep (ws re-poisoned every call, so redo each call)
    cvt_bf16_kernel<<<(DMODEL * NFEAT / 4 + 255) / 256, 256, 0, stream>>>(fc1w, wfc1, DMODEL * NFEAT / 4);
    cvt_bf16_kernel<<<(2 * 2 * DINNER * DMODEL / 4 + 255) / 256, 256, 0, stream>>>(ipw, wip, 2 * 2 * DINNER * DMODEL / 4);
    cvt_bf16_kernel<<<(2 * DMODEL * DINNER / 4 + 255) / 256, 256, 0, stream>>>(opw, wop, 2 * DMODEL * DINNER / 4);
    cvt_bf16_kernel<<<(2 * DINNER * DTRANK / 4 + 255) / 256, 256, 0, stream>>>(dtw, wdt, 2 * DINNER * DTRANK / 4);
    pad_xpw_kernel<<<(2 * 128 * DINNER / 4) / 256, 256, 0, stream>>>(xpw, wxp);
    gather_kernel<<<MROWS * (NFEAT / 4) / 256, 256, 0, stream>>>(seq, emb, gemb);

    // subg = gathered_emb @ fc1_w^T + fc1_b   (f32 out)  [256^2 8-phase]
    gemm256<0, 0><<<dim3(MROWS / 256, DMODEL / 256), 512, 0, stream>>>(
        gemb, NFEAT, wfc1, NFEAT, subg, DMODEL, fc1b, NFEAT, NOSILU);

    const int scan_blocks = (BATCH * NCHUNK * DINNER) / 256;   // 2048
    for (int i = 0; i < 2; ++i) {
        const float* al = alog + i * DINNER * DSTATE;
        rmsnorm_kernel<<<MROWS / 4, 256, 0, stream>>>(subg, nscale + i * DMODEL, zi);
        // xz = zi @ in_proj_w^T  (bf16 out; silu fused on z-half cols >= DINNER)
        gemm256<1, 0><<<dim3(MROWS / 256, 2 * DINNER / 256), 512, 0, stream>>>(
            zi, DMODEL, wip + (size_t)i * 2 * DINNER * DMODEL, DMODEL,
            xzb, 2 * DINNER, nullptr, DMODEL, DINNER);
        conv_silu_kernel<<<MROWS * 128 / 256, 256, 0, stream>>>(
            xzb, cw + i * DINNER * 4, cbv + i * DINNER, xconv);
        // x_dbl = xconv @ x_proj_w^T (N padded to 128)  [128^2 kernel, N=128]
        gemm_bt<1, 0, 0><<<dim3(MROWS / 128, 1), 256, 0, stream>>>(
            xconv, DINNER, wxp + (size_t)i * 128 * DINNER, DINNER,
            xdbl, 128, nullptr, DINNER);
        // delta = softplus(dt @ dt_proj_w^T + dt_proj_b)  (K=32) [128^2 kernel]
        gemm_bt<1, 0, 1><<<dim3(MROWS / 128, DINNER / 128), 256, 0, stream>>>(
            xdbl, 128, wdt + (size_t)i * DINNER * DTRANK, DTRANK,
            delta, DINNER, dtb + i * DINNER, DTRANK);
        // chunked scan
        scan_p1<<<scan_blocks, 256, 0, stream>>>(delta, xconv, xdbl, al, states, dtsums);
        scan_p2<<<scan_blocks, 256, 0, stream>>>(states, dtsums, al);
        scan_p3<<<scan_blocks, 256, 0, stream>>>(delta, xconv, xzb, xdbl, al,
                                                 Dvec + i * DINNER, states, ybuf);
        // subg += y @ out_proj_w^T  (f32 accumulate)  [256^2 8-phase]
        gemm256<0, 1><<<dim3(MROWS / 256, DMODEL / 256), 512, 0, stream>>>(
            ybuf, DINNER, wop + (size_t)i * DMODEL * DINNER, DINNER,
            subg, DMODEL, nullptr, DINNER, NOSILU);
    }

    pool_partial_kernel<<<dim3(8, BATCH), 256, 0, stream>>>(subg, incl, part, msump);
    fc2_kernel<<<BATCH, 256, 0, stream>>>(part, msump, fc2w, fc2b, outp);
}

// Round 2
// 1362.230 us; speedup vs baseline: 1.4662x; 1.4662x over previous
//
#include <hip/hip_runtime.h>
#include <cstdint>
#include <cstddef>

#define LSEQ   1024
#define BATCH  32
#define NFEAT  512
#define DMODEL 512
#define DINNER 1024
#define DSTATE 16
#define DTRANK 32
#define NCLASS 40
#define MROWS  (BATCH * LSEQ)   // 32768
#define NCHUNK 16
#define CLEN   (LSEQ / NCHUNK)  // 64

typedef unsigned short u16;
typedef __attribute__((ext_vector_type(8))) __bf16 bf16x8;
typedef __attribute__((ext_vector_type(4))) float f32x4;
typedef __attribute__((ext_vector_type(8))) unsigned short u16x8;

__device__ __forceinline__ u16 f2bf(float x) {
    union { float f; unsigned u; } v; v.f = x;
    unsigned r = v.u + 0x7fffu + ((v.u >> 16) & 1u);   // round-to-nearest-even
    return (u16)(r >> 16);
}
__device__ __forceinline__ float bf2f(u16 h) {
    union { unsigned u; float f; } v; v.u = ((unsigned)h) << 16;
    return v.f;
}

// hw-approx silu: x * rcp(1 + exp2(-x*log2e)).  ~1ulp trans; output bf16.
__device__ __forceinline__ float silu_hw(float x) {
    float e = __builtin_amdgcn_exp2f(-1.44269504089f * x);
    return x * __builtin_amdgcn_rcpf(1.f + e);
}
// hw-approx softplus: ln2 * log2(1 + exp2(x*log2e)); branch for large x.
__device__ __forceinline__ float softplus_hw(float x) {
    if (x > 15.f) return x;
    float e = __builtin_amdgcn_exp2f(1.44269504089f * x);
    return 0.69314718056f * __builtin_amdgcn_logf(1.f + e);
}

// dA[s] = g^(s+1), s=0..15, via 4-deep multiply tree (18 muls, no trans).
__device__ __forceinline__ void pow_dA(float g, float* dA) {
    float p2 = g * g, p4 = p2 * p2, p8 = p4 * p4;
    dA[0] = g;        dA[1] = p2;       dA[2] = p2 * g;   dA[3] = p4;
    dA[4] = p4 * g;   dA[5] = p4 * p2;  dA[6] = p4 * dA[2]; dA[7] = p8;
    dA[8] = p8 * g;   dA[9] = p8 * p2;  dA[10] = p8 * dA[2]; dA[11] = p8 * p4;
    dA[12] = p8 * dA[4]; dA[13] = p8 * dA[5]; dA[14] = p8 * dA[6]; dA[15] = p8 * p8;
}

// unpack 8 bf16 (packed in uint4) -> 8 floats; scalar-friendly (shift/and)
__device__ __forceinline__ void unpack8(uint4 w, float* f) {
    union { unsigned u; float v; } c;
    c.u = w.x << 16;         f[0] = c.v;
    c.u = w.x & 0xffff0000u; f[1] = c.v;
    c.u = w.y << 16;         f[2] = c.v;
    c.u = w.y & 0xffff0000u; f[3] = c.v;
    c.u = w.z << 16;         f[4] = c.v;
    c.u = w.z & 0xffff0000u; f[5] = c.v;
    c.u = w.w << 16;         f[6] = c.v;
    c.u = w.w & 0xffff0000u; f[7] = c.v;
}

#define GLL16(g, l) __builtin_amdgcn_global_load_lds( \
    (__attribute__((address_space(1))) void*)(g),     \
    (__attribute__((address_space(3))) void*)(l), 16, 0, 0)

// ---------------------------------------------------------------------------
// 256x256 8-phase GEMM (HK-style schedule, plain HIP).  Used ONLY for
// in_proj (M=32768, N=2048, K=512; 1024 blocks) this round -- diagnostic A/B
// vs the 128^2 kernel's 131us.  silu fused on cols >= silu_from.
// ---------------------------------------------------------------------------
template<int OUT_BF16, int ACCUM>
__global__ __launch_bounds__(512, 2) void gemm256(
    const u16* __restrict__ A, int lda,
    const u16* __restrict__ B, int ldb,
    void* __restrict__ Cv, int ldc,
    const float* __restrict__ bias, int K, int silu_from)
{
    __shared__ __align__(16) u16 As[2][256 * 64];
    __shared__ __align__(16) u16 Bs[2][256 * 64];
    const int tid  = threadIdx.x;
    const int lane = tid & 63;
    const int wave = tid >> 6;            // 0..7
    const int wr   = (wave >> 2) * 128;   // 0 or 128
    const int wc   = (wave & 3) * 64;     // 0,64,128,192
    const int frow = lane & 15;
    const int quad = lane >> 4;
    const int m0   = blockIdx.x * 256;
    const int n0   = blockIdx.y * 256;

    // staging map (constant per thread): one GLL sweep = 8KB = 64 rows
    const int srow = tid >> 3;                   // row within quarter (0..63)
    const int slb  = (tid & 7) ^ (srow & 7);     // logical 16B-block (inverse swz)
    const u16* gA = A + (size_t)(m0 + srow) * lda + slb * 8;
    const u16* gB = B + (size_t)(n0 + srow) * ldb + slb * 8;

    // read-side per-lane swizzled k-offsets (u16 units)
    const int cb0 = ((quad)     ^ (frow & 7)) * 8;   // kk=0
    const int cb1 = ((4 + quad) ^ (frow & 7)) * 8;   // kk=1

#define STAGE_A(sb, tt, q) GLL16(gA + (size_t)(q) * 64 * lda + (size_t)(tt) * 64, \
                                 &As[sb][(q) * 4096 + tid * 8])
#define STAGE_B(sb, tt, q) GLL16(gB + (size_t)(q) * 64 * ldb + (size_t)(tt) * 64, \
                                 &Bs[sb][(q) * 4096 + tid * 8])

    f32x4 acc[8][4];
#pragma unroll
    for (int i = 0; i < 8; ++i)
#pragma unroll
        for (int j = 0; j < 4; ++j) acc[i][j] = (f32x4){0.f, 0.f, 0.f, 0.f};

    const int NT = K >> 6;

    // prologue: stage tiles 0 and 1 (8 loads each), wait tile 0
#pragma unroll
    for (int q = 0; q < 4; ++q) STAGE_A(0, 0, q);
#pragma unroll
    for (int q = 0; q < 4; ++q) STAGE_B(0, 0, q);
#pragma unroll
    for (int q = 0; q < 4; ++q) STAGE_A(1, 1, q);
#pragma unroll
    for (int q = 0; q < 4; ++q) STAGE_B(1, 1, q);
    asm volatile("s_waitcnt vmcnt(8)" ::: "memory");
    __builtin_amdgcn_s_barrier();

    for (int t = 0; t < NT; ++t) {
        const int bsel = t & 1;
        const u16* __restrict__ Ab = &As[bsel][0];
        const u16* __restrict__ Bb = &Bs[bsel][0];
        const int stage = (t + 2 < NT);
        const int t2 = t + 2;
        const int rA = wr + frow;
        const int rB = wc + frow;
        bf16x8 af[4][2], b0[2][2], b1[2][2];

        // ---- P1: read af0 (M-half0) + bf0 (N-half0); stage Aq0,Aq2 ----
#pragma unroll
        for (int m = 0; m < 4; ++m) {
            const u16* p = Ab + (rA + m * 16) * 64;
            af[m][0] = *(const bf16x8*)(p + cb0);
            af[m][1] = *(const bf16x8*)(p + cb1);
        }
#pragma unroll
        for (int n = 0; n < 2; ++n) {
            const u16* p = Bb + (rB + n * 16) * 64;
            b0[n][0] = *(const bf16x8*)(p + cb0);
            b0[n][1] = *(const bf16x8*)(p + cb1);
        }
        if (stage) { STAGE_A(bsel, t2, 0); STAGE_A(bsel, t2, 2); }
        __builtin_amdgcn_s_barrier();
        asm volatile("s_waitcnt lgkmcnt(0)" ::: "memory");
        __builtin_amdgcn_sched_barrier(0);
        __builtin_amdgcn_s_setprio(1);
#pragma unroll
        for (int m = 0; m < 4; ++m)
#pragma unroll
            for (int n = 0; n < 2; ++n) {
                acc[m][n] = __builtin_amdgcn_mfma_f32_16x16x32_bf16(af[m][0], b0[n][0], acc[m][n], 0, 0, 0);
                acc[m][n] = __builtin_amdgcn_mfma_f32_16x16x32_bf16(af[m][1], b0[n][1], acc[m][n], 0, 0, 0);
            }
        __builtin_amdgcn_s_setprio(0);
        __builtin_amdgcn_s_barrier();

        // ---- P2: read bf1 (N-half1); stage Bq0,Bq1 ----
#pragma unroll
        for (int n = 0; n < 2; ++n) {
            const u16* p = Bb + (rB + 32 + n * 16) * 64;
            b1[n][0] = *(const bf16x8*)(p + cb0);
            b1[n][1] = *(const bf16x8*)(p + cb1);
        }
        if (stage) { STAGE_B(bsel, t2, 0); STAGE_B(bsel, t2, 1); }
        __builtin_amdgcn_s_barrier();
        asm volatile("s_waitcnt lgkmcnt(0)" ::: "memory");
        __builtin_amdgcn_sched_barrier(0);
        __builtin_amdgcn_s_setprio(1);
#pragma unroll
        for (int m = 0; m < 4; ++m)
#pragma unroll
            for (int n = 0; n < 2; ++n) {
                acc[m][2 + n] = __builtin_amdgcn_mfma_f32_16x16x32_bf16(af[m][0], b1[n][0], acc[m][2 + n], 0, 0, 0);
                acc[m][2 + n] = __builtin_amdgcn_mfma_f32_16x16x32_bf16(af[m][1], b1[n][1], acc[m][2 + n], 0, 0, 0);
            }
        __builtin_amdgcn_s_setprio(0);
        __builtin_amdgcn_s_barrier();

        // ---- P3: read af1 (M-half1, overwrite af regs); stage Aq1,Aq3 ----
#pragma unroll
        for (int m = 0; m < 4; ++m) {
            const u16* p = Ab + (rA + 64 + m * 16) * 64;
            af[m][0] = *(const bf16x8*)(p + cb0);
            af[m][1] = *(const bf16x8*)(p + cb1);
        }
        if (stage) { STAGE_A(bsel, t2, 1); STAGE_A(bsel, t2, 3); }
        __builtin_amdgcn_s_barrier();
        asm volatile("s_waitcnt lgkmcnt(0)" ::: "memory");
        __builtin_amdgcn_sched_barrier(0);
        __builtin_amdgcn_s_setprio(1);
#pragma unroll
        for (int m = 0; m < 4; ++m)
#pragma unroll
            for (int n = 0; n < 2; ++n) {
                acc[4 + m][2 + n] = __builtin_amdgcn_mfma_f32_16x16x32_bf16(af[m][0], b1[n][0], acc[4 + m][2 + n], 0, 0, 0);
                acc[4 + m][2 + n] = __builtin_amdgcn_mfma_f32_16x16x32_bf16(af[m][1], b1[n][1], acc[4 + m][2 + n], 0, 0, 0);
            }
        __builtin_amdgcn_s_setprio(0);
        __builtin_amdgcn_s_barrier();

        // ---- P4: no reads (bf0 live); stage Bq2,Bq3; counted vmcnt ----
        if (stage) {
            STAGE_B(bsel, t2, 2); STAGE_B(bsel, t2, 3);
            asm volatile("s_waitcnt vmcnt(8)" ::: "memory");
        } else {
            asm volatile("s_waitcnt vmcnt(0)" ::: "memory");
        }
        __builtin_amdgcn_s_barrier();
        __builtin_amdgcn_s_setprio(1);
#pragma unroll
        for (int m = 0; m < 4; ++m)
#pragma unroll
            for (int n = 0; n < 2; ++n) {
                acc[4 + m][n] = __builtin_amdgcn_mfma_f32_16x16x32_bf16(af[m][0], b0[n][0], acc[4 + m][n], 0, 0, 0);
                acc[4 + m][n] = __builtin_amdgcn_mfma_f32_16x16x32_bf16(af[m][1], b0[n][1], acc[4 + m][n], 0, 0, 0);
            }
        __builtin_amdgcn_s_setprio(0);
        __builtin_amdgcn_s_barrier();
    }
#undef STAGE_A
#undef STAGE_B

    // epilogue
    float bv[4];
#pragma unroll
    for (int n = 0; n < 4; ++n) {
        int col = n0 + wc + (n >> 1) * 32 + (n & 1) * 16 + frow;
        bv[n] = bias ? bias[col] : 0.f;
    }
#pragma unroll
    for (int m = 0; m < 8; ++m) {
        size_t row0 = (size_t)(m0 + wr + (m >> 2) * 64 + (m & 3) * 16 + quad * 4);
#pragma unroll
        for (int r = 0; r < 4; ++r) {
#pragma unroll
            for (int n = 0; n < 4; ++n) {
                int col = n0 + wc + (n >> 1) * 32 + (n & 1) * 16 + frow;
                size_t cidx = (row0 + r) * (size_t)ldc + (size_t)col;
                float v = acc[m][n][r] + bv[n];
                if (col >= silu_from) v = silu_hw(v);
                if (OUT_BF16)      ((u16*)Cv)[cidx] = f2bf(v);
                else if (ACCUM)    ((float*)Cv)[cidx] += v;
                else               ((float*)Cv)[cidx] = v;
            }
        }
    }
}

// ---------------------------------------------------------------------------
// C[M,N] = A[M,K](bf16,lda) * B[N,K](bf16,ldb)^T  (+bias) (+softplus) ;
// OUT_BF16: store bf16; ACCUM: f32 +=. 128x128 tile, BK=32, 256 thr (4 waves).
// Used for fc1, x_proj, dt_proj, out_proj.  Softplus is HW exp2/log2
// (libm log1pf/expf was 57% VALUBusy, 205us on dt_proj).
// ---------------------------------------------------------------------------
template<int OUT_BF16, int ACCUM, int ACT>
__global__ __launch_bounds__(256) void gemm_bt(
    const u16* __restrict__ A, int lda,
    const u16* __restrict__ B, int ldb,
    void* __restrict__ Cv, int ldc,
    const float* __restrict__ bias, int K)
{
    __shared__ __align__(16) u16 As[128 * 32];
    __shared__ __align__(16) u16 Bs[128 * 32];
    const int tid  = threadIdx.x;
    const int m0   = blockIdx.x * 128;
    const int n0   = blockIdx.y * 128;
    const int r0   = tid >> 2;            // staging row (0..63), +64 for job 1
    const int c0   = (tid & 3) << 3;      // staging k-chunk (0,8,16,24)
    const int lane = tid & 63;
    const int wave = tid >> 6;
    const int wr   = (wave >> 1) << 6;    // wave row offset in tile
    const int wc   = (wave & 1) << 6;     // wave col offset in tile
    const int frow = lane & 15;
    const int fk   = (lane >> 4) << 3;
    const int quad = lane >> 4;

    const u16* Ap0 = A + (size_t)(m0 + r0) * lda + c0;
    const u16* Ap1 = Ap0 + (size_t)64 * lda;
    const u16* Bp0 = B + (size_t)(n0 + r0) * ldb + c0;
    const u16* Bp1 = Bp0 + (size_t)64 * ldb;
    u16* lA0 = As + tid * 8;  u16* lA1 = As + (tid + 256) * 8;
    u16* lB0 = Bs + tid * 8;  u16* lB1 = Bs + (tid + 256) * 8;

    f32x4 acc[4][4];
#pragma unroll
    for (int i = 0; i < 4; ++i)
#pragma unroll
        for (int j = 0; j < 4; ++j) acc[i][j] = (f32x4){0.f, 0.f, 0.f, 0.f};

    for (int k0 = 0; k0 < K; k0 += 32) {
        GLL16(Ap0 + k0, lA0);
        GLL16(Ap1 + k0, lA1);
        GLL16(Bp0 + k0, lB0);
        GLL16(Bp1 + k0, lB1);
        __syncthreads();
        bf16x8 af[4], bfr[4];
#pragma unroll
        for (int i = 0; i < 4; ++i) {
            af[i]  = *(const bf16x8*)(As + (wr + i * 16 + frow) * 32 + fk);
            bfr[i] = *(const bf16x8*)(Bs + (wc + i * 16 + frow) * 32 + fk);
        }
#pragma unroll
        for (int i = 0; i < 4; ++i)
#pragma unroll
            for (int j = 0; j < 4; ++j)
                acc[i][j] = __builtin_amdgcn_mfma_f32_16x16x32_bf16(
                    af[i], bfr[j], acc[i][j], 0, 0, 0);
        __syncthreads();
    }

    float bv[4];
#pragma unroll
    for (int j = 0; j < 4; ++j)
        bv[j] = bias ? bias[n0 + wc + j * 16 + frow] : 0.f;

#pragma unroll
    for (int i = 0; i < 4; ++i) {
#pragma unroll
        for (int r = 0; r < 4; ++r) {
            size_t row = (size_t)(m0 + wr + i * 16 + quad * 4 + r);
#pragma unroll
            for (int j = 0; j < 4; ++j) {
                size_t cidx = row * (size_t)ldc + (size_t)(n0 + wc + j * 16 + frow);
                float v = acc[i][j][r] + bv[j];
                if (ACT == 1) v = softplus_hw(v);
                if (OUT_BF16)      ((u16*)Cv)[cidx] = f2bf(v);
                else if (ACCUM)    ((float*)Cv)[cidx] += v;
                else               ((float*)Cv)[cidx] = v;
            }
        }
    }
}

// --------------------------- elementwise / prep ----------------------------

__global__ __launch_bounds__(256) void cvt_bf16_kernel(
    const float* __restrict__ src, u16* __restrict__ dst, int n4)
{
    int i = blockIdx.x * 256 + threadIdx.x;
    if (i >= n4) return;
    float4 v = ((const float4*)src)[i];
    ushort4 o; o.x = f2bf(v.x); o.y = f2bf(v.y); o.z = f2bf(v.z); o.w = f2bf(v.w);
    ((ushort4*)dst)[i] = o;
}

// x_proj_w (2,64,1024) f32 -> (2,128,1024) bf16, rows 64..127 zero
__global__ __launch_bounds__(256) void pad_xpw_kernel(
    const float* __restrict__ src, u16* __restrict__ dst)
{
    int i  = blockIdx.x * 256 + threadIdx.x;   // per float4; total 2*128*1024/4
    int k4 = i & 255;
    int r  = (i >> 8) & 127;
    int l  = i >> 15;
    ushort4 o;
    if (r < 64) {
        float4 v = ((const float4*)(src + ((size_t)l * 64 + r) * DINNER))[k4];
        o.x = f2bf(v.x); o.y = f2bf(v.y); o.z = f2bf(v.z); o.w = f2bf(v.w);
    } else { o.x = 0; o.y = 0; o.z = 0; o.w = 0; }
    ((ushort4*)dst)[i] = o;
}

// gathered_emb[m,:] = bf16(embeddings[sequence[m],:])
__global__ __launch_bounds__(256) void gather_kernel(
    const int* __restrict__ seq, const float* __restrict__ emb, u16* __restrict__ g)
{
    int i   = blockIdx.x * 256 + threadIdx.x;  // per float4; total MROWS*128
    int row = i >> 7, c = i & 127;
    int node = seq[row];
    float4 v = ((const float4*)(emb + (size_t)node * NFEAT))[c];
    ushort4 o; o.x = f2bf(v.x); o.y = f2bf(v.y); o.z = f2bf(v.z); o.w = f2bf(v.w);
    ((ushort4*)g)[i] = o;
}

// zi = scale * x / (||x||/sqrt(512) + 1e-8), one wave per row
__global__ __launch_bounds__(256) void rmsnorm_kernel(
    const float* __restrict__ x, const float* __restrict__ scale, u16* __restrict__ o)
{
    int wave = threadIdx.x >> 6, lane = threadIdx.x & 63;
    size_t row = (size_t)blockIdx.x * 4 + wave;
    const float4* xr = (const float4*)(x + row * DMODEL);
    float4 v0 = xr[lane], v1 = xr[lane + 64];
    float ss = v0.x*v0.x + v0.y*v0.y + v0.z*v0.z + v0.w*v0.w
             + v1.x*v1.x + v1.y*v1.y + v1.z*v1.z + v1.w*v1.w;
#pragma unroll
    for (int off = 32; off; off >>= 1) ss += __shfl_xor(ss, off, 64);
    float inv = 1.f / (sqrtf(ss * (1.f / DMODEL)) + 1e-8f);
    const float4* sc = (const float4*)scale;
    float4 s0 = sc[lane], s1 = sc[lane + 64];
    ushort4 o0, o1;
    o0.x = f2bf(v0.x * s0.x * inv); o0.y = f2bf(v0.y * s0.y * inv);
    o0.z = f2bf(v0.z * s0.z * inv); o0.w = f2bf(v0.w * s0.w * inv);
    o1.x = f2bf(v1.x * s1.x * inv); o1.y = f2bf(v1.y * s1.y * inv);
    o1.z = f2bf(v1.z * s1.z * inv); o1.w = f2bf(v1.w * s1.w * inv);
    ushort4* op = (ushort4*)(o + row * DMODEL);
    op[lane] = o0; op[lane + 64] = o1;
}

// causal depthwise conv (window 4) + bias + silu on x-half; 8 channels/thread.
// z-half already silu'd by in_proj GEMM epilogue.
__global__ __launch_bounds__(256) void conv_silu_kernel(
    const u16* __restrict__ xz,
    const float* __restrict__ w, const float* __restrict__ cbv,
    u16* __restrict__ xc)
{
    int i  = blockIdx.x * 256 + threadIdx.x;   // MROWS*128 total
    int d0 = (i & 127) << 3;
    int r  = i >> 7;
    int l  = r & (LSEQ - 1);
    const u16* bx = xz + (size_t)r * (2 * DINNER) + d0;
    u16x8 zero{};
    u16x8 t3 = *(const u16x8*)(bx);
    u16x8 t2 = (l >= 1) ? *(const u16x8*)(bx - 2 * DINNER) : zero;
    u16x8 t1 = (l >= 2) ? *(const u16x8*)(bx - 4 * DINNER) : zero;
    u16x8 t0 = (l >= 3) ? *(const u16x8*)(bx - 6 * DINNER) : zero;
    u16x8 oc;
#pragma unroll
    for (int c = 0; c < 8; ++c) {
        float4 wc = ((const float4*)w)[d0 + c];
        float acc = cbv[d0 + c]
                  + wc.x * bf2f(t0[c]) + wc.y * bf2f(t1[c])
                  + wc.z * bf2f(t2[c]) + wc.w * bf2f(t3[c]);
        oc[c] = f2bf(silu_hw(acc));
    }
    *(u16x8*)(xc + (size_t)r * DINNER + d0) = oc;
}

// ---------------------------------------------------------------------------
// Chunked selective scan, v3 (unchanged).
// ---------------------------------------------------------------------------
__device__ __forceinline__ int detect_s4d(const float* a2) {
    int fast = 1;
#pragma unroll
    for (int s = 1; s < DSTATE; ++s)
        fast &= (__builtin_fabsf(a2[s] - (float)(s + 1) * a2[0]) <=
                 1e-4f * (float)(s + 1) * __builtin_fabsf(a2[0]) + 1e-6f);
    return fast;
}

__global__ __launch_bounds__(256) void scan_p1(
    const u16* __restrict__ delta, const u16* __restrict__ xconv,
    const u16* __restrict__ xdbl, const float* __restrict__ alog,
    float* __restrict__ states, float* __restrict__ dtsums)
{
    const int bid = blockIdx.x;
    const int d0  = (bid & 3) << 8;
    const int k   = (bid >> 2) & (NCHUNK - 1);
    const int b   = bid >> 6;
    const int d   = d0 + threadIdx.x;

    float a2[DSTATE];
#pragma unroll
    for (int s = 0; s < DSTATE; ++s)
        a2[s] = -expf(alog[d * DSTATE + s]) * 1.44269504f;
    const int fastA = detect_s4d(a2);
    const float ab = a2[0];

    float h[DSTATE];
#pragma unroll
    for (int s = 0; s < DSTATE; ++s) h[s] = 0.f;
    float dtsum = 0.f;

    const size_t r0 = (size_t)b * LSEQ + (size_t)k * CLEN;
    const u16* pd = delta + r0 * DINNER + d;
    const u16* px = xconv + r0 * DINNER + d;
    const unsigned* pB = (const unsigned*)(xdbl + r0 * 128) + 16;  // uniform

    float dt = bf2f(*pd), xv = bf2f(*px);
    uint4 wB  = *(const uint4*)(pB);
    uint4 wB2 = *(const uint4*)(pB + 4);

    if (fastA) {
        for (int j = 0; j < CLEN; ++j) {
            pd += DINNER; px += DINNER; pB += 64;
            float dt_n = bf2f(*pd), xv_n = bf2f(*px);
            uint4 wBn  = *(const uint4*)(pB);
            uint4 wB2n = *(const uint4*)(pB + 4);
            float dx = dt * xv;
            dtsum += dt;
            float dA[DSTATE];
            pow_dA(__builtin_amdgcn_exp2f(dt * ab), dA);
            float Bv[DSTATE];
            unpack8(wB, Bv); unpack8(wB2, Bv + 8);
#pragma unroll
            for (int s = 0; s < DSTATE; ++s)
                h[s] = __builtin_fmaf(h[s], dA[s], dx * Bv[s]);
            dt = dt_n; xv = xv_n; wB = wBn; wB2 = wB2n;
        }
    } else {
        for (int j = 0; j < CLEN; ++j) {
            pd += DINNER; px += DINNER; pB += 64;
            float dt_n = bf2f(*pd), xv_n = bf2f(*px);
            uint4 wBn  = *(const uint4*)(pB);
            uint4 wB2n = *(const uint4*)(pB + 4);
            float dx = dt * xv;
            dtsum += dt;
            float Bv[DSTATE];
            unpack8(wB, Bv); unpack8(wB2, Bv + 8);
#pragma unroll
            for (int s = 0; s < DSTATE; ++s)
                h[s] = __builtin_fmaf(h[s], __builtin_amdgcn_exp2f(dt * a2[s]),
                                      dx * Bv[s]);
            dt = dt_n; xv = xv_n; wB = wBn; wB2 = wB2n;
        }
    }

    size_t t = (size_t)(b * NCHUNK + k) * DINNER + d;
    f32x4* st = (f32x4*)(states + t * DSTATE);
#pragma unroll
    for (int q = 0; q < 4; ++q)
        st[q] = (f32x4){h[q * 4], h[q * 4 + 1], h[q * 4 + 2], h[q * 4 + 3]};
    dtsums[t] = dtsum;
}

__global__ __launch_bounds__(256) void scan_p2(
    float* __restrict__ states, const float* __restrict__ dtsums,
    const float* __restrict__ alog)
{
    int t = blockIdx.x * 256 + threadIdx.x;   // 0 .. B*DINNER*DSTATE-1
    int s = t & (DSTATE - 1);
    int d = (t >> 4) & (DINNER - 1);
    int b = t >> 14;
    float a2 = -expf(alog[d * DSTATE + s]) * 1.44269504f;
    float H = 0.f;
    for (int k = 0; k < NCHUNK; ++k) {
        size_t ci = ((size_t)b * NCHUNK + k) * DINNER + d;
        size_t idx = ci * DSTATE + s;
        float hk = states[idx];
        float P = __builtin_amdgcn_exp2f(a2 * dtsums[ci]);
        states[idx] = H;                 // exclusive incoming state for chunk k
        H = hk + P * H;
    }
}

__global__ __launch_bounds__(256) void scan_p3(
    const u16* __restrict__ delta, const u16* __restrict__ xconv,
    const u16* __restrict__ zsil, const u16* __restrict__ xdbl,
    const float* __restrict__ alog, const float* __restrict__ Dvec,
    const float* __restrict__ states, u16* __restrict__ ybuf)
{
    const int bid = blockIdx.x;
    const int d0  = (bid & 3) << 8;
    const int k   = (bid >> 2) & (NCHUNK - 1);
    const int b   = bid >> 6;
    const int d   = d0 + threadIdx.x;

    float a2[DSTATE];
#pragma unroll
    for (int s = 0; s < DSTATE; ++s)
        a2[s] = -expf(alog[d * DSTATE + s]) * 1.44269504f;
    const int fastA = detect_s4d(a2);
    const float ab = a2[0];
    const float Dd = Dvec[d];

    float h[DSTATE];
    size_t t = (size_t)(b * NCHUNK + k) * DINNER + d;
    const f32x4* st = (const f32x4*)(states + t * DSTATE);
#pragma unroll
    for (int q = 0; q < 4; ++q) {
        f32x4 v = st[q];
        h[q * 4] = v[0]; h[q * 4 + 1] = v[1]; h[q * 4 + 2] = v[2]; h[q * 4 + 3] = v[3];
    }

    const size_t r0 = (size_t)b * LSEQ + (size_t)k * CLEN;
    const u16* pd = delta + r0 * DINNER + d;
    const u16* px = xconv + r0 * DINNER + d;
    const u16* pz = zsil + r0 * (2 * DINNER) + DINNER + d;
    const unsigned* pB = (const unsigned*)(xdbl + r0 * 128) + 16;  // uniform
    u16* py = ybuf + r0 * DINNER + d;

    float dt = bf2f(*pd), xv = bf2f(*px), zs = bf2f(*pz);
    uint4 wB  = *(const uint4*)(pB);
    uint4 wB2 = *(const uint4*)(pB + 4);
    uint4 wC  = *(const uint4*)(pB + 8);
    uint4 wC2 = *(const uint4*)(pB + 12);

    if (fastA) {
        for (int j = 0; j < CLEN; ++j) {
            pd += DINNER; px += DINNER; pz += 2 * DINNER; pB += 64;
            float dt_n = bf2f(*pd), xv_n = bf2f(*px), zs_n = bf2f(*pz);
            uint4 wBn  = *(const uint4*)(pB);
            uint4 wB2n = *(const uint4*)(pB + 4);
            uint4 wCn  = *(const uint4*)(pB + 8);
            uint4 wC2n = *(const uint4*)(pB + 12);
            float dx = dt * xv;
            float dA[DSTATE];
            pow_dA(__builtin_amdgcn_exp2f(dt * ab), dA);
            float Bv[DSTATE], Cv[DSTATE];
            unpack8(wB, Bv); unpack8(wB2, Bv + 8);
            unpack8(wC, Cv); unpack8(wC2, Cv + 8);
            float y0 = 0.f, y1 = 0.f, y2 = 0.f, y3 = 0.f;
#pragma unroll
            for (int s = 0; s < DSTATE; ++s)
                h[s] = __builtin_fmaf(h[s], dA[s], dx * Bv[s]);
#pragma unroll
            for (int s = 0; s < DSTATE; s += 4) {
                y0 = __builtin_fmaf(h[s],     Cv[s],     y0);
                y1 = __builtin_fmaf(h[s + 1], Cv[s + 1], y1);
                y2 = __builtin_fmaf(h[s + 2], Cv[s + 2], y2);
                y3 = __builtin_fmaf(h[s + 3], Cv[s + 3], y3);
            }
            float yv = ((y0 + y1) + (y2 + y3)) + Dd * xv;
            *py = f2bf(yv * zs); py += DINNER;
            dt = dt_n; xv = xv_n; zs = zs_n;
            wB = wBn; wB2 = wB2n; wC = wCn; wC2 = wC2n;
        }
    } else {
        for (int j = 0; j < CLEN; ++j) {
            pd += DINNER; px += DINNER; pz += 2 * DINNER; pB += 64;
            float dt_n = bf2f(*pd), xv_n = bf2f(*px), zs_n = bf2f(*pz);
            uint4 wBn  = *(const uint4*)(pB);
            uint4 wB2n = *(const uint4*)(pB + 4);
            uint4 wCn  = *(const uint4*)(pB + 8);
            uint4 wC2n = *(const uint4*)(pB + 12);
            float dx = dt * xv;
            float Bv[DSTATE], Cv[DSTATE];
            unpack8(wB, Bv); unpack8(wB2, Bv + 8);
            unpack8(wC, Cv); unpack8(wC2, Cv + 8);
            float y0 = 0.f, y1 = 0.f, y2 = 0.f, y3 = 0.f;
#pragma unroll
            for (int s = 0; s < DSTATE; ++s) {
                h[s] = __builtin_fmaf(h[s], __builtin_amdgcn_exp2f(dt * a2[s]),
                                      dx * Bv[s]);
            }
#pragma unroll
            for (int s = 0; s < DSTATE; s += 4) {
                y0 = __builtin_fmaf(h[s],     Cv[s],     y0);
                y1 = __builtin_fmaf(h[s + 1], Cv[s + 1], y1);
                y2 = __builtin_fmaf(h[s + 2], Cv[s + 2], y2);
                y3 = __builtin_fmaf(h[s + 3], Cv[s + 3], y3);
            }
            float yv = ((y0 + y1) + (y2 + y3)) + Dd * xv;
            *py = f2bf(yv * zs); py += DINNER;
            dt = dt_n; xv = xv_n; zs = zs_n;
            wB = wBn; wB2 = wB2n; wC = wCn; wC2 = wC2n;
        }
    }
}

// masked-mean partials: grid (8 chunks, 32 b)
__global__ __launch_bounds__(256) void pool_partial_kernel(
    const float* __restrict__ subg, const float* __restrict__ incl,
    float* __restrict__ part, float* __restrict__ msump)
{
    int chunk = blockIdx.x, b = blockIdx.y, tid = threadIdx.x;
    float a0 = 0.f, a1 = 0.f, ms = 0.f;
    for (int l0 = 0; l0 < 128; ++l0) {
        int l = chunk * 128 + l0;
        float m = incl[b * LSEQ + l];
        const float* row = subg + ((size_t)b * LSEQ + l) * DMODEL;
        a0 += m * row[tid];
        a1 += m * row[tid + 256];
        ms += m;
    }
    int pi = (b * 8 + chunk) * DMODEL;
    part[pi + tid] = a0;
    part[pi + tid + 256] = a1;
    if (tid == 0) msump[b * 8 + chunk] = ms;
}

__global__ __launch_bounds__(256) void fc2_kernel(
    const float* __restrict__ part, const float* __restrict__ msump,
    const float* __restrict__ fc2w, const float* __restrict__ fc2b,
    float* __restrict__ out)
{
    int b = blockIdx.x, tid = threadIdx.x;
    __shared__ float pooled[DMODEL];
    float s0 = 0.f, s1 = 0.f, ms = 0.f;
#pragma unroll
    for (int c = 0; c < 8; ++c) {
        s0 += part[(b * 8 + c) * DMODEL + tid];
        s1 += part[(b * 8 + c) * DMODEL + tid + 256];
        ms += msump[b * 8 + c];
    }
    float inv = 1.f / (ms + 1e-5f);
    pooled[tid] = s0 * inv; pooled[tid + 256] = s1 * inv;
    __syncthreads();
    int wave = tid >> 6, lane = tid & 63;
    for (int c = wave; c < NCLASS; c += 4) {
        float s = 0.f;
#pragma unroll
        for (int k = lane; k < DMODEL; k += 64) s += pooled[k] * fc2w[c * DMODEL + k];
#pragma unroll
        for (int off = 32; off; off >>= 1) s += __shfl_xor(s, off, 64);
        if (lane == 0) out[b * NCLASS + c] = s + fc2b[c];
    }
}

// ---------------------------------------------------------------------------

extern "C" void kernel_launch(void* const* d_in, const int* in_sizes, int n_in,
                              void* d_out, int out_size, void* d_ws, size_t ws_size,
                              hipStream_t stream)
{
    (void)in_sizes; (void)n_in; (void)out_size; (void)ws_size;
    const int*   seq    = (const int*)  d_in[0];
    const float* incl   = (const float*)d_in[1];
    const float* emb    = (const float*)d_in[2];
    const float* fc1w   = (const float*)d_in[3];
    const float* fc1b   = (const float*)d_in[4];
    const float* fc2w   = (const float*)d_in[5];
    const float* fc2b   = (const float*)d_in[6];
    const float* nscale = (const float*)d_in[7];
    const float* ipw    = (const float*)d_in[8];
    const float* cw     = (const float*)d_in[9];
    const float* cbv    = (const float*)d_in[10];
    const float* xpw    = (const float*)d_in[11];
    const float* dtw    = (const float*)d_in[12];
    const float* dtb    = (const float*)d_in[13];
    const float* alog   = (const float*)d_in[14];
    const float* Dvec   = (const float*)d_in[15];
    const float* opw    = (const float*)d_in[16];
    float* outp = (float*)d_out;

    char* w = (char*)d_ws;
    size_t off = 0;
    auto take = [&](size_t bytes) {
        char* p = w + off; off += (bytes + 255) & ~(size_t)255; return p;
    };
    float* subg  = (float*)take((size_t)MROWS * DMODEL * 4);       // fp32 residual stream
    u16*   zi    = (u16*)  take((size_t)MROWS * DMODEL * 2);       // rmsnorm out (33.5MB)
    u16*   xzb   = (u16*)  take((size_t)MROWS * 2 * DINNER * 2);   // in_proj out (xin|silu(z))
    u16*   xconv = (u16*)  take((size_t)MROWS * DINNER * 2);       // conv+silu out
    u16*   xdbl  = (u16*)  take((size_t)MROWS * 128 * 2);          // x_proj out (pad 128)
    u16*   delta = (u16*)  take((size_t)MROWS * DINNER * 2);       // softplus(dt_proj)
    u16*   ybuf  = (u16*)  take((size_t)MROWS * DINNER * 2);       // scan out (gated)
    u16*   wip   = (u16*)  take((size_t)2 * 2 * DINNER * DMODEL * 2);
    u16*   wop   = (u16*)  take((size_t)2 * DMODEL * DINNER * 2);
    u16*   wxp   = (u16*)  take((size_t)2 * 128 * DINNER * 2);
    u16*   wdt   = (u16*)  take((size_t)2 * DINNER * DTRANK * 2);
    u16*   wfc1  = (u16*)  take((size_t)DMODEL * NFEAT * 2);
    float* part  = (float*)take((size_t)BATCH * 8 * DMODEL * 4);
    float* msump = (float*)take((size_t)BATCH * 8 * 4);
    float* dtsums= (float*)take((size_t)BATCH * NCHUNK * DINNER * 4);  // 2 MB
    u16*   gemb  = (u16*)delta;   // alias: gathered emb consumed before delta written
    float* states= (float*)zi;    // alias: zi dead after in_proj GEMM each layer (same 33.5MB)

    // weight prep (ws re-poisoned every call, so redo each call)
    cvt_bf16_kernel<<<(DMODEL * NFEAT / 4 + 255) / 256, 256, 0, stream>>>(fc1w, wfc1, DMODEL * NFEAT / 4);
    cvt_bf16_kernel<<<(2 * 2 * DINNER * DMODEL / 4 + 255) / 256, 256, 0, stream>>>(ipw, wip, 2 * 2 * DINNER * DMODEL / 4);
    cvt_bf16_kernel<<<(2 * DMODEL * DINNER / 4 + 255) / 256, 256, 0, stream>>>(opw, wop, 2 * DMODEL * DINNER / 4);
    cvt_bf16_kernel<<<(2 * DINNER * DTRANK / 4 + 255) / 256, 256, 0, stream>>>(dtw, wdt, 2 * DINNER * DTRANK / 4);
    pad_xpw_kernel<<<(2 * 128 * DINNER / 4) / 256, 256, 0, stream>>>(xpw, wxp);
    gather_kernel<<<MROWS * (NFEAT / 4) / 256, 256, 0, stream>>>(seq, emb, gemb);

    // subg = gathered_emb @ fc1_w^T + fc1_b   (f32 out)  [128^2, proven]
    gemm_bt<0, 0, 0><<<dim3(MROWS / 128, DMODEL / 128), 256, 0, stream>>>(
        gemb, NFEAT, wfc1, NFEAT, subg, DMODEL, fc1b, NFEAT);

    const int scan_blocks = (BATCH * NCHUNK * DINNER) / 256;   // 2048
    for (int i = 0; i < 2; ++i) {
        const float* al = alog + i * DINNER * DSTATE;
        rmsnorm_kernel<<<MROWS / 4, 256, 0, stream>>>(subg, nscale + i * DMODEL, zi);
        // xz = zi @ in_proj_w^T  (bf16 out; silu fused on z-half cols >= DINNER)
        // [256^2 8-phase -- diagnostic A/B vs 131us round-0 number]
        gemm256<1, 0><<<dim3(MROWS / 256, 2 * DINNER / 256), 512, 0, stream>>>(
            zi, DMODEL, wip + (size_t)i * 2 * DINNER * DMODEL, DMODEL,
            xzb, 2 * DINNER, nullptr, DMODEL, DINNER);
        conv_silu_kernel<<<MROWS * 128 / 256, 256, 0, stream>>>(
            xzb, cw + i * DINNER * 4, cbv + i * DINNER, xconv);
        // x_dbl = xconv @ x_proj_w^T (N padded to 128)  [128^2 kernel, N=128]
        gemm_bt<1, 0, 0><<<dim3(MROWS / 128, 1), 256, 0, stream>>>(
            xconv, DINNER, wxp + (size_t)i * 128 * DINNER, DINNER,
            xdbl, 128, nullptr, DINNER);
        // delta = softplus(dt @ dt_proj_w^T + dt_proj_b)  (K=32) [hw softplus]
        gemm_bt<1, 0, 1><<<dim3(MROWS / 128, DINNER / 128), 256, 0, stream>>>(
            xdbl, 128, wdt + (size_t)i * DINNER * DTRANK, DTRANK,
            delta, DINNER, dtb + i * DINNER, DTRANK);
        // chunked scan
        scan_p1<<<scan_blocks, 256, 0, stream>>>(delta, xconv, xdbl, al, states, dtsums);
        scan_p2<<<scan_blocks, 256, 0, stream>>>(states, dtsums, al);
        scan_p3<<<scan_blocks, 256, 0, stream>>>(delta, xconv, xzb, xdbl, al,
                                                 Dvec + i * DINNER, states, ybuf);
        // subg += y @ out_proj_w^T  (f32 accumulate)  [128^2, proven]
        gemm_bt<0, 1, 0><<<dim3(MROWS / 128, DMODEL / 128), 256, 0, stream>>>(
            ybuf, DINNER, wop + (size_t)i * DMODEL * DINNER, DINNER,
            subg, DMODEL, nullptr, DINNER);
    }

    pool_partial_kernel<<<dim3(8, BATCH), 256, 0, stream>>>(subg, incl, part, msump);
    fc2_kernel<<<BATCH, 256, 0, stream>>>(part, msump, fc2w, fc2b, outp);
}

// Round 3
// 1293.405 us; speedup vs baseline: 1.5442x; 1.0532x over previous
//
#include <hip/hip_runtime.h>
#include <cstdint>
#include <cstddef>

#define LSEQ   1024
#define BATCH  32
#define NFEAT  512
#define DMODEL 512
#define DINNER 1024
#define DSTATE 16
#define DTRANK 32
#define NCLASS 40
#define MROWS  (BATCH * LSEQ)   // 32768
#define NCHUNK 16
#define CLEN   (LSEQ / NCHUNK)  // 64

typedef unsigned short u16;
typedef __attribute__((ext_vector_type(8))) __bf16 bf16x8;
typedef __attribute__((ext_vector_type(4))) float f32x4;
typedef __attribute__((ext_vector_type(8))) unsigned short u16x8;

__device__ __forceinline__ u16 f2bf(float x) {
    union { float f; unsigned u; } v; v.f = x;
    unsigned r = v.u + 0x7fffu + ((v.u >> 16) & 1u);   // round-to-nearest-even
    return (u16)(r >> 16);
}
__device__ __forceinline__ float bf2f(u16 h) {
    union { unsigned u; float f; } v; v.u = ((unsigned)h) << 16;
    return v.f;
}

// hw-approx silu: x * rcp(1 + exp2(-x*log2e)).
__device__ __forceinline__ float silu_hw(float x) {
    float e = __builtin_amdgcn_exp2f(-1.44269504089f * x);
    return x * __builtin_amdgcn_rcpf(1.f + e);
}
// hw-approx softplus: ln2 * log2(1 + exp2(x*log2e)); branch for large x.
__device__ __forceinline__ float softplus_hw(float x) {
    if (x > 15.f) return x;
    float e = __builtin_amdgcn_exp2f(1.44269504089f * x);
    return 0.69314718056f * __builtin_amdgcn_logf(1.f + e);
}

// dA[s] = g^(s+1), s=0..15, via 4-deep multiply tree (18 muls, no trans).
__device__ __forceinline__ void pow_dA(float g, float* dA) {
    float p2 = g * g, p4 = p2 * p2, p8 = p4 * p4;
    dA[0] = g;        dA[1] = p2;       dA[2] = p2 * g;   dA[3] = p4;
    dA[4] = p4 * g;   dA[5] = p4 * p2;  dA[6] = p4 * dA[2]; dA[7] = p8;
    dA[8] = p8 * g;   dA[9] = p8 * p2;  dA[10] = p8 * dA[2]; dA[11] = p8 * p4;
    dA[12] = p8 * dA[4]; dA[13] = p8 * dA[5]; dA[14] = p8 * dA[6]; dA[15] = p8 * p8;
}

// unpack 8 bf16 (packed in uint4) -> 8 floats; scalar-friendly (shift/and)
__device__ __forceinline__ void unpack8(uint4 w, float* f) {
    union { unsigned u; float v; } c;
    c.u = w.x << 16;         f[0] = c.v;
    c.u = w.x & 0xffff0000u; f[1] = c.v;
    c.u = w.y << 16;         f[2] = c.v;
    c.u = w.y & 0xffff0000u; f[3] = c.v;
    c.u = w.z << 16;         f[4] = c.v;
    c.u = w.z & 0xffff0000u; f[5] = c.v;
    c.u = w.w << 16;         f[6] = c.v;
    c.u = w.w & 0xffff0000u; f[7] = c.v;
}

#define GLL16(g, l) __builtin_amdgcn_global_load_lds( \
    (__attribute__((address_space(1))) void*)(g),     \
    (__attribute__((address_space(3))) void*)(l), 16, 0, 0)

// ---------------------------------------------------------------------------
// 256x256 8-phase GEMM (HK-style schedule, plain HIP).
// This round: in_proj, out_proj, fc1 all run here (A/B vs 128^2 gemm_bt).
// silu fused on cols >= silu_from.
// ---------------------------------------------------------------------------
template<int OUT_BF16, int ACCUM>
__global__ __launch_bounds__(512, 2) void gemm256(
    const u16* __restrict__ A, int lda,
    const u16* __restrict__ B, int ldb,
    void* __restrict__ Cv, int ldc,
    const float* __restrict__ bias, int K, int silu_from)
{
    __shared__ __align__(16) u16 As[2][256 * 64];
    __shared__ __align__(16) u16 Bs[2][256 * 64];
    const int tid  = threadIdx.x;
    const int lane = tid & 63;
    const int wave = tid >> 6;            // 0..7
    const int wr   = (wave >> 2) * 128;   // 0 or 128
    const int wc   = (wave & 3) * 64;     // 0,64,128,192
    const int frow = lane & 15;
    const int quad = lane >> 4;
    const int m0   = blockIdx.x * 256;
    const int n0   = blockIdx.y * 256;

    // staging map (constant per thread): one GLL sweep = 8KB = 64 rows
    const int srow = tid >> 3;                   // row within quarter (0..63)
    const int slb  = (tid & 7) ^ (srow & 7);     // logical 16B-block (inverse swz)
    const u16* gA = A + (size_t)(m0 + srow) * lda + slb * 8;
    const u16* gB = B + (size_t)(n0 + srow) * ldb + slb * 8;

    // read-side per-lane swizzled k-offsets (u16 units)
    const int cb0 = ((quad)     ^ (frow & 7)) * 8;   // kk=0
    const int cb1 = ((4 + quad) ^ (frow & 7)) * 8;   // kk=1

#define STAGE_A(sb, tt, q) GLL16(gA + (size_t)(q) * 64 * lda + (size_t)(tt) * 64, \
                                 &As[sb][(q) * 4096 + tid * 8])
#define STAGE_B(sb, tt, q) GLL16(gB + (size_t)(q) * 64 * ldb + (size_t)(tt) * 64, \
                                 &Bs[sb][(q) * 4096 + tid * 8])

    f32x4 acc[8][4];
#pragma unroll
    for (int i = 0; i < 8; ++i)
#pragma unroll
        for (int j = 0; j < 4; ++j) acc[i][j] = (f32x4){0.f, 0.f, 0.f, 0.f};

    const int NT = K >> 6;

    // prologue: stage tiles 0 and 1 (8 loads each), wait tile 0
#pragma unroll
    for (int q = 0; q < 4; ++q) STAGE_A(0, 0, q);
#pragma unroll
    for (int q = 0; q < 4; ++q) STAGE_B(0, 0, q);
#pragma unroll
    for (int q = 0; q < 4; ++q) STAGE_A(1, 1, q);
#pragma unroll
    for (int q = 0; q < 4; ++q) STAGE_B(1, 1, q);
    asm volatile("s_waitcnt vmcnt(8)" ::: "memory");
    __builtin_amdgcn_s_barrier();

    for (int t = 0; t < NT; ++t) {
        const int bsel = t & 1;
        const u16* __restrict__ Ab = &As[bsel][0];
        const u16* __restrict__ Bb = &Bs[bsel][0];
        const int stage = (t + 2 < NT);
        const int t2 = t + 2;
        const int rA = wr + frow;
        const int rB = wc + frow;
        bf16x8 af[4][2], b0[2][2], b1[2][2];

        // ---- P1: read af0 (M-half0) + bf0 (N-half0); stage Aq0,Aq2 ----
#pragma unroll
        for (int m = 0; m < 4; ++m) {
            const u16* p = Ab + (rA + m * 16) * 64;
            af[m][0] = *(const bf16x8*)(p + cb0);
            af[m][1] = *(const bf16x8*)(p + cb1);
        }
#pragma unroll
        for (int n = 0; n < 2; ++n) {
            const u16* p = Bb + (rB + n * 16) * 64;
            b0[n][0] = *(const bf16x8*)(p + cb0);
            b0[n][1] = *(const bf16x8*)(p + cb1);
        }
        if (stage) { STAGE_A(bsel, t2, 0); STAGE_A(bsel, t2, 2); }
        __builtin_amdgcn_s_barrier();
        asm volatile("s_waitcnt lgkmcnt(0)" ::: "memory");
        __builtin_amdgcn_sched_barrier(0);
        __builtin_amdgcn_s_setprio(1);
#pragma unroll
        for (int m = 0; m < 4; ++m)
#pragma unroll
            for (int n = 0; n < 2; ++n) {
                acc[m][n] = __builtin_amdgcn_mfma_f32_16x16x32_bf16(af[m][0], b0[n][0], acc[m][n], 0, 0, 0);
                acc[m][n] = __builtin_amdgcn_mfma_f32_16x16x32_bf16(af[m][1], b0[n][1], acc[m][n], 0, 0, 0);
            }
        __builtin_amdgcn_s_setprio(0);
        __builtin_amdgcn_s_barrier();

        // ---- P2: read bf1 (N-half1); stage Bq0,Bq1 ----
#pragma unroll
        for (int n = 0; n < 2; ++n) {
            const u16* p = Bb + (rB + 32 + n * 16) * 64;
            b1[n][0] = *(const bf16x8*)(p + cb0);
            b1[n][1] = *(const bf16x8*)(p + cb1);
        }
        if (stage) { STAGE_B(bsel, t2, 0); STAGE_B(bsel, t2, 1); }
        __builtin_amdgcn_s_barrier();
        asm volatile("s_waitcnt lgkmcnt(0)" ::: "memory");
        __builtin_amdgcn_sched_barrier(0);
        __builtin_amdgcn_s_setprio(1);
#pragma unroll
        for (int m = 0; m < 4; ++m)
#pragma unroll
            for (int n = 0; n < 2; ++n) {
                acc[m][2 + n] = __builtin_amdgcn_mfma_f32_16x16x32_bf16(af[m][0], b1[n][0], acc[m][2 + n], 0, 0, 0);
                acc[m][2 + n] = __builtin_amdgcn_mfma_f32_16x16x32_bf16(af[m][1], b1[n][1], acc[m][2 + n], 0, 0, 0);
            }
        __builtin_amdgcn_s_setprio(0);
        __builtin_amdgcn_s_barrier();

        // ---- P3: read af1 (M-half1, overwrite af regs); stage Aq1,Aq3 ----
#pragma unroll
        for (int m = 0; m < 4; ++m) {
            const u16* p = Ab + (rA + 64 + m * 16) * 64;
            af[m][0] = *(const bf16x8*)(p + cb0);
            af[m][1] = *(const bf16x8*)(p + cb1);
        }
        if (stage) { STAGE_A(bsel, t2, 1); STAGE_A(bsel, t2, 3); }
        __builtin_amdgcn_s_barrier();
        asm volatile("s_waitcnt lgkmcnt(0)" ::: "memory");
        __builtin_amdgcn_sched_barrier(0);
        __builtin_amdgcn_s_setprio(1);
#pragma unroll
        for (int m = 0; m < 4; ++m)
#pragma unroll
            for (int n = 0; n < 2; ++n) {
                acc[4 + m][2 + n] = __builtin_amdgcn_mfma_f32_16x16x32_bf16(af[m][0], b1[n][0], acc[4 + m][2 + n], 0, 0, 0);
                acc[4 + m][2 + n] = __builtin_amdgcn_mfma_f32_16x16x32_bf16(af[m][1], b1[n][1], acc[4 + m][2 + n], 0, 0, 0);
            }
        __builtin_amdgcn_s_setprio(0);
        __builtin_amdgcn_s_barrier();

        // ---- P4: no reads (bf0 live); stage Bq2,Bq3; counted vmcnt ----
        if (stage) {
            STAGE_B(bsel, t2, 2); STAGE_B(bsel, t2, 3);
            asm volatile("s_waitcnt vmcnt(8)" ::: "memory");
        } else {
            asm volatile("s_waitcnt vmcnt(0)" ::: "memory");
        }
        __builtin_amdgcn_s_barrier();
        __builtin_amdgcn_s_setprio(1);
#pragma unroll
        for (int m = 0; m < 4; ++m)
#pragma unroll
            for (int n = 0; n < 2; ++n) {
                acc[4 + m][n] = __builtin_amdgcn_mfma_f32_16x16x32_bf16(af[m][0], b0[n][0], acc[4 + m][n], 0, 0, 0);
                acc[4 + m][n] = __builtin_amdgcn_mfma_f32_16x16x32_bf16(af[m][1], b0[n][1], acc[4 + m][n], 0, 0, 0);
            }
        __builtin_amdgcn_s_setprio(0);
        __builtin_amdgcn_s_barrier();
    }
#undef STAGE_A
#undef STAGE_B

    // epilogue
    float bv[4];
#pragma unroll
    for (int n = 0; n < 4; ++n) {
        int col = n0 + wc + (n >> 1) * 32 + (n & 1) * 16 + frow;
        bv[n] = bias ? bias[col] : 0.f;
    }
#pragma unroll
    for (int m = 0; m < 8; ++m) {
        size_t row0 = (size_t)(m0 + wr + (m >> 2) * 64 + (m & 3) * 16 + quad * 4);
#pragma unroll
        for (int r = 0; r < 4; ++r) {
#pragma unroll
            for (int n = 0; n < 4; ++n) {
                int col = n0 + wc + (n >> 1) * 32 + (n & 1) * 16 + frow;
                size_t cidx = (row0 + r) * (size_t)ldc + (size_t)col;
                float v = acc[m][n][r] + bv[n];
                if (col >= silu_from) v = silu_hw(v);
                if (OUT_BF16)      ((u16*)Cv)[cidx] = f2bf(v);
                else if (ACCUM)    ((float*)Cv)[cidx] += v;
                else               ((float*)Cv)[cidx] = v;
            }
        }
    }
}

// ---------------------------------------------------------------------------
// 128x128 / BK=32 GEMM (m97-structure).  Kept for x_proj (N=128) and
// dt_proj (K=32).  Softplus is HW exp2/log2.
// ---------------------------------------------------------------------------
template<int OUT_BF16, int ACCUM, int ACT>
__global__ __launch_bounds__(256) void gemm_bt(
    const u16* __restrict__ A, int lda,
    const u16* __restrict__ B, int ldb,
    void* __restrict__ Cv, int ldc,
    const float* __restrict__ bias, int K)
{
    __shared__ __align__(16) u16 As[128 * 32];
    __shared__ __align__(16) u16 Bs[128 * 32];
    const int tid  = threadIdx.x;
    const int m0   = blockIdx.x * 128;
    const int n0   = blockIdx.y * 128;
    const int r0   = tid >> 2;            // staging row (0..63), +64 for job 1
    const int c0   = (tid & 3) << 3;      // staging k-chunk (0,8,16,24)
    const int lane = tid & 63;
    const int wave = tid >> 6;
    const int wr   = (wave >> 1) << 6;    // wave row offset in tile
    const int wc   = (wave & 1) << 6;     // wave col offset in tile
    const int frow = lane & 15;
    const int fk   = (lane >> 4) << 3;
    const int quad = lane >> 4;

    const u16* Ap0 = A + (size_t)(m0 + r0) * lda + c0;
    const u16* Ap1 = Ap0 + (size_t)64 * lda;
    const u16* Bp0 = B + (size_t)(n0 + r0) * ldb + c0;
    const u16* Bp1 = Bp0 + (size_t)64 * ldb;
    u16* lA0 = As + tid * 8;  u16* lA1 = As + (tid + 256) * 8;
    u16* lB0 = Bs + tid * 8;  u16* lB1 = Bs + (tid + 256) * 8;

    f32x4 acc[4][4];
#pragma unroll
    for (int i = 0; i < 4; ++i)
#pragma unroll
        for (int j = 0; j < 4; ++j) acc[i][j] = (f32x4){0.f, 0.f, 0.f, 0.f};

    for (int k0 = 0; k0 < K; k0 += 32) {
        GLL16(Ap0 + k0, lA0);
        GLL16(Ap1 + k0, lA1);
        GLL16(Bp0 + k0, lB0);
        GLL16(Bp1 + k0, lB1);
        __syncthreads();
        bf16x8 af[4], bfr[4];
#pragma unroll
        for (int i = 0; i < 4; ++i) {
            af[i]  = *(const bf16x8*)(As + (wr + i * 16 + frow) * 32 + fk);
            bfr[i] = *(const bf16x8*)(Bs + (wc + i * 16 + frow) * 32 + fk);
        }
#pragma unroll
        for (int i = 0; i < 4; ++i)
#pragma unroll
            for (int j = 0; j < 4; ++j)
                acc[i][j] = __builtin_amdgcn_mfma_f32_16x16x32_bf16(
                    af[i], bfr[j], acc[i][j], 0, 0, 0);
        __syncthreads();
    }

    float bv[4];
#pragma unroll
    for (int j = 0; j < 4; ++j)
        bv[j] = bias ? bias[n0 + wc + j * 16 + frow] : 0.f;

#pragma unroll
    for (int i = 0; i < 4; ++i) {
#pragma unroll
        for (int r = 0; r < 4; ++r) {
            size_t row = (size_t)(m0 + wr + i * 16 + quad * 4 + r);
#pragma unroll
            for (int j = 0; j < 4; ++j) {
                size_t cidx = row * (size_t)ldc + (size_t)(n0 + wc + j * 16 + frow);
                float v = acc[i][j][r] + bv[j];
                if (ACT == 1) v = softplus_hw(v);
                if (OUT_BF16)      ((u16*)Cv)[cidx] = f2bf(v);
                else if (ACCUM)    ((float*)Cv)[cidx] += v;
                else               ((float*)Cv)[cidx] = v;
            }
        }
    }
}

// --------------------------- elementwise / prep ----------------------------

// merged f32->bf16 weight conversion: fc1 | ip | op | dt ranges (float4 units)
#define CVT_N_FC1 65536      // 512*512/4
#define CVT_N_IP  524288     // 2*2048*512/4
#define CVT_N_OP  262144     // 2*512*1024/4
#define CVT_N_DT  16384      // 2*1024*32/4
#define CVT_TOTAL (CVT_N_FC1 + CVT_N_IP + CVT_N_OP + CVT_N_DT)

__global__ __launch_bounds__(256) void prep_weights_kernel(
    const float* __restrict__ fc1w, u16* __restrict__ wfc1,
    const float* __restrict__ ipw,  u16* __restrict__ wip,
    const float* __restrict__ opw,  u16* __restrict__ wop,
    const float* __restrict__ dtw,  u16* __restrict__ wdt)
{
    int i = blockIdx.x * 256 + threadIdx.x;
    if (i >= CVT_TOTAL) return;
    const float* src; u16* dst; int j = i;
    if (j < CVT_N_FC1)                    { src = fc1w; dst = wfc1; }
    else if ((j -= CVT_N_FC1) < CVT_N_IP) { src = ipw;  dst = wip;  }
    else if ((j -= CVT_N_IP) < CVT_N_OP)  { src = opw;  dst = wop;  }
    else { j -= CVT_N_OP;                   src = dtw;  dst = wdt;  }
    float4 v = ((const float4*)src)[j];
    ushort4 o; o.x = f2bf(v.x); o.y = f2bf(v.y); o.z = f2bf(v.z); o.w = f2bf(v.w);
    ((ushort4*)dst)[j] = o;
}

// x_proj_w (2,64,1024) f32 -> (2,128,1024) bf16, rows 64..127 zero
__global__ __launch_bounds__(256) void pad_xpw_kernel(
    const float* __restrict__ src, u16* __restrict__ dst)
{
    int i  = blockIdx.x * 256 + threadIdx.x;   // per float4; total 2*128*1024/4
    int k4 = i & 255;
    int r  = (i >> 8) & 127;
    int l  = i >> 15;
    ushort4 o;
    if (r < 64) {
        float4 v = ((const float4*)(src + ((size_t)l * 64 + r) * DINNER))[k4];
        o.x = f2bf(v.x); o.y = f2bf(v.y); o.z = f2bf(v.z); o.w = f2bf(v.w);
    } else { o.x = 0; o.y = 0; o.z = 0; o.w = 0; }
    ((ushort4*)dst)[i] = o;
}

// gathered_emb[m,:] = bf16(embeddings[sequence[m],:])
__global__ __launch_bounds__(256) void gather_kernel(
    const int* __restrict__ seq, const float* __restrict__ emb, u16* __restrict__ g)
{
    int i   = blockIdx.x * 256 + threadIdx.x;  // per float4; total MROWS*128
    int row = i >> 7, c = i & 127;
    int node = seq[row];
    float4 v = ((const float4*)(emb + (size_t)node * NFEAT))[c];
    ushort4 o; o.x = f2bf(v.x); o.y = f2bf(v.y); o.z = f2bf(v.z); o.w = f2bf(v.w);
    ((ushort4*)g)[i] = o;
}

// zi = scale * x / (||x||/sqrt(512) + 1e-8), one wave per row
__global__ __launch_bounds__(256) void rmsnorm_kernel(
    const float* __restrict__ x, const float* __restrict__ scale, u16* __restrict__ o)
{
    int wave = threadIdx.x >> 6, lane = threadIdx.x & 63;
    size_t row = (size_t)blockIdx.x * 4 + wave;
    const float4* xr = (const float4*)(x + row * DMODEL);
    float4 v0 = xr[lane], v1 = xr[lane + 64];
    float ss = v0.x*v0.x + v0.y*v0.y + v0.z*v0.z + v0.w*v0.w
             + v1.x*v1.x + v1.y*v1.y + v1.z*v1.z + v1.w*v1.w;
#pragma unroll
    for (int off = 32; off; off >>= 1) ss += __shfl_xor(ss, off, 64);
    float inv = 1.f / (sqrtf(ss * (1.f / DMODEL)) + 1e-8f);
    const float4* sc = (const float4*)scale;
    float4 s0 = sc[lane], s1 = sc[lane + 64];
    ushort4 o0, o1;
    o0.x = f2bf(v0.x * s0.x * inv); o0.y = f2bf(v0.y * s0.y * inv);
    o0.z = f2bf(v0.z * s0.z * inv); o0.w = f2bf(v0.w * s0.w * inv);
    o1.x = f2bf(v1.x * s1.x * inv); o1.y = f2bf(v1.y * s1.y * inv);
    o1.z = f2bf(v1.z * s1.z * inv); o1.w = f2bf(v1.w * s1.w * inv);
    ushort4* op = (ushort4*)(o + row * DMODEL);
    op[lane] = o0; op[lane + 64] = o1;
}

// causal depthwise conv (window 4) + bias + silu on x-half; 8 channels/thread.
// z-half already silu'd by in_proj GEMM epilogue.
__global__ __launch_bounds__(256) void conv_silu_kernel(
    const u16* __restrict__ xz,
    const float* __restrict__ w, const float* __restrict__ cbv,
    u16* __restrict__ xc)
{
    int i  = blockIdx.x * 256 + threadIdx.x;   // MROWS*128 total
    int d0 = (i & 127) << 3;
    int r  = i >> 7;
    int l  = r & (LSEQ - 1);
    const u16* bx = xz + (size_t)r * (2 * DINNER) + d0;
    u16x8 zero{};
    u16x8 t3 = *(const u16x8*)(bx);
    u16x8 t2 = (l >= 1) ? *(const u16x8*)(bx - 2 * DINNER) : zero;
    u16x8 t1 = (l >= 2) ? *(const u16x8*)(bx - 4 * DINNER) : zero;
    u16x8 t0 = (l >= 3) ? *(const u16x8*)(bx - 6 * DINNER) : zero;
    u16x8 oc;
#pragma unroll
    for (int c = 0; c < 8; ++c) {
        float4 wc = ((const float4*)w)[d0 + c];
        float acc = cbv[d0 + c]
                  + wc.x * bf2f(t0[c]) + wc.y * bf2f(t1[c])
                  + wc.z * bf2f(t2[c]) + wc.w * bf2f(t3[c]);
        oc[c] = f2bf(silu_hw(acc));
    }
    *(u16x8*)(xc + (size_t)r * DINNER + d0) = oc;
}

// ---------------------------------------------------------------------------
// Chunked selective scan, v3 (unchanged).
// ---------------------------------------------------------------------------
__device__ __forceinline__ int detect_s4d(const float* a2) {
    int fast = 1;
#pragma unroll
    for (int s = 1; s < DSTATE; ++s)
        fast &= (__builtin_fabsf(a2[s] - (float)(s + 1) * a2[0]) <=
                 1e-4f * (float)(s + 1) * __builtin_fabsf(a2[0]) + 1e-6f);
    return fast;
}

__global__ __launch_bounds__(256) void scan_p1(
    const u16* __restrict__ delta, const u16* __restrict__ xconv,
    const u16* __restrict__ xdbl, const float* __restrict__ alog,
    float* __restrict__ states, float* __restrict__ dtsums)
{
    const int bid = blockIdx.x;
    const int d0  = (bid & 3) << 8;
    const int k   = (bid >> 2) & (NCHUNK - 1);
    const int b   = bid >> 6;
    const int d   = d0 + threadIdx.x;

    float a2[DSTATE];
#pragma unroll
    for (int s = 0; s < DSTATE; ++s)
        a2[s] = -expf(alog[d * DSTATE + s]) * 1.44269504f;
    const int fastA = detect_s4d(a2);
    const float ab = a2[0];

    float h[DSTATE];
#pragma unroll
    for (int s = 0; s < DSTATE; ++s) h[s] = 0.f;
    float dtsum = 0.f;

    const size_t r0 = (size_t)b * LSEQ + (size_t)k * CLEN;
    const u16* pd = delta + r0 * DINNER + d;
    const u16* px = xconv + r0 * DINNER + d;
    const unsigned* pB = (const unsigned*)(xdbl + r0 * 128) + 16;  // uniform

    float dt = bf2f(*pd), xv = bf2f(*px);
    uint4 wB  = *(const uint4*)(pB);
    uint4 wB2 = *(const uint4*)(pB + 4);

    if (fastA) {
        for (int j = 0; j < CLEN; ++j) {
            pd += DINNER; px += DINNER; pB += 64;
            float dt_n = bf2f(*pd), xv_n = bf2f(*px);
            uint4 wBn  = *(const uint4*)(pB);
            uint4 wB2n = *(const uint4*)(pB + 4);
            float dx = dt * xv;
            dtsum += dt;
            float dA[DSTATE];
            pow_dA(__builtin_amdgcn_exp2f(dt * ab), dA);
            float Bv[DSTATE];
            unpack8(wB, Bv); unpack8(wB2, Bv + 8);
#pragma unroll
            for (int s = 0; s < DSTATE; ++s)
                h[s] = __builtin_fmaf(h[s], dA[s], dx * Bv[s]);
            dt = dt_n; xv = xv_n; wB = wBn; wB2 = wB2n;
        }
    } else {
        for (int j = 0; j < CLEN; ++j) {
            pd += DINNER; px += DINNER; pB += 64;
            float dt_n = bf2f(*pd), xv_n = bf2f(*px);
            uint4 wBn  = *(const uint4*)(pB);
            uint4 wB2n = *(const uint4*)(pB + 4);
            float dx = dt * xv;
            dtsum += dt;
            float Bv[DSTATE];
            unpack8(wB, Bv); unpack8(wB2, Bv + 8);
#pragma unroll
            for (int s = 0; s < DSTATE; ++s)
                h[s] = __builtin_fmaf(h[s], __builtin_amdgcn_exp2f(dt * a2[s]),
                                      dx * Bv[s]);
            dt = dt_n; xv = xv_n; wB = wBn; wB2 = wB2n;
        }
    }

    size_t t = (size_t)(b * NCHUNK + k) * DINNER + d;
    f32x4* st = (f32x4*)(states + t * DSTATE);
#pragma unroll
    for (int q = 0; q < 4; ++q)
        st[q] = (f32x4){h[q * 4], h[q * 4 + 1], h[q * 4 + 2], h[q * 4 + 3]};
    dtsums[t] = dtsum;
}

__global__ __launch_bounds__(256) void scan_p2(
    float* __restrict__ states, const float* __restrict__ dtsums,
    const float* __restrict__ alog)
{
    int t = blockIdx.x * 256 + threadIdx.x;   // 0 .. B*DINNER*DSTATE-1
    int s = t & (DSTATE - 1);
    int d = (t >> 4) & (DINNER - 1);
    int b = t >> 14;
    float a2 = -expf(alog[d * DSTATE + s]) * 1.44269504f;
    float H = 0.f;
    for (int k = 0; k < NCHUNK; ++k) {
        size_t ci = ((size_t)b * NCHUNK + k) * DINNER + d;
        size_t idx = ci * DSTATE + s;
        float hk = states[idx];
        float P = __builtin_amdgcn_exp2f(a2 * dtsums[ci]);
        states[idx] = H;                 // exclusive incoming state for chunk k
        H = hk + P * H;
    }
}

__global__ __launch_bounds__(256) void scan_p3(
    const u16* __restrict__ delta, const u16* __restrict__ xconv,
    const u16* __restrict__ zsil, const u16* __restrict__ xdbl,
    const float* __restrict__ alog, const float* __restrict__ Dvec,
    const float* __restrict__ states, u16* __restrict__ ybuf)
{
    const int bid = blockIdx.x;
    const int d0  = (bid & 3) << 8;
    const int k   = (bid >> 2) & (NCHUNK - 1);
    const int b   = bid >> 6;
    const int d   = d0 + threadIdx.x;

    float a2[DSTATE];
#pragma unroll
    for (int s = 0; s < DSTATE; ++s)
        a2[s] = -expf(alog[d * DSTATE + s]) * 1.44269504f;
    const int fastA = detect_s4d(a2);
    const float ab = a2[0];
    const float Dd = Dvec[d];

    float h[DSTATE];
    size_t t = (size_t)(b * NCHUNK + k) * DINNER + d;
    const f32x4* st = (const f32x4*)(states + t * DSTATE);
#pragma unroll
    for (int q = 0; q < 4; ++q) {
        f32x4 v = st[q];
        h[q * 4] = v[0]; h[q * 4 + 1] = v[1]; h[q * 4 + 2] = v[2]; h[q * 4 + 3] = v[3];
    }

    const size_t r0 = (size_t)b * LSEQ + (size_t)k * CLEN;
    const u16* pd = delta + r0 * DINNER + d;
    const u16* px = xconv + r0 * DINNER + d;
    const u16* pz = zsil + r0 * (2 * DINNER) + DINNER + d;
    const unsigned* pB = (const unsigned*)(xdbl + r0 * 128) + 16;  // uniform
    u16* py = ybuf + r0 * DINNER + d;

    float dt = bf2f(*pd), xv = bf2f(*px), zs = bf2f(*pz);
    uint4 wB  = *(const uint4*)(pB);
    uint4 wB2 = *(const uint4*)(pB + 4);
    uint4 wC  = *(const uint4*)(pB + 8);
    uint4 wC2 = *(const uint4*)(pB + 12);

    if (fastA) {
        for (int j = 0; j < CLEN; ++j) {
            pd += DINNER; px += DINNER; pz += 2 * DINNER; pB += 64;
            float dt_n = bf2f(*pd), xv_n = bf2f(*px), zs_n = bf2f(*pz);
            uint4 wBn  = *(const uint4*)(pB);
            uint4 wB2n = *(const uint4*)(pB + 4);
            uint4 wCn  = *(const uint4*)(pB + 8);
            uint4 wC2n = *(const uint4*)(pB + 12);
            float dx = dt * xv;
            float dA[DSTATE];
            pow_dA(__builtin_amdgcn_exp2f(dt * ab), dA);
            float Bv[DSTATE], Cv[DSTATE];
            unpack8(wB, Bv); unpack8(wB2, Bv + 8);
            unpack8(wC, Cv); unpack8(wC2, Cv + 8);
            float y0 = 0.f, y1 = 0.f, y2 = 0.f, y3 = 0.f;
#pragma unroll
            for (int s = 0; s < DSTATE; ++s)
                h[s] = __builtin_fmaf(h[s], dA[s], dx * Bv[s]);
#pragma unroll
            for (int s = 0; s < DSTATE; s += 4) {
                y0 = __builtin_fmaf(h[s],     Cv[s],     y0);
                y1 = __builtin_fmaf(h[s + 1], Cv[s + 1], y1);
                y2 = __builtin_fmaf(h[s + 2], Cv[s + 2], y2);
                y3 = __builtin_fmaf(h[s + 3], Cv[s + 3], y3);
            }
            float yv = ((y0 + y1) + (y2 + y3)) + Dd * xv;
            *py = f2bf(yv * zs); py += DINNER;
            dt = dt_n; xv = xv_n; zs = zs_n;
            wB = wBn; wB2 = wB2n; wC = wCn; wC2 = wC2n;
        }
    } else {
        for (int j = 0; j < CLEN; ++j) {
            pd += DINNER; px += DINNER; pz += 2 * DINNER; pB += 64;
            float dt_n = bf2f(*pd), xv_n = bf2f(*px), zs_n = bf2f(*pz);
            uint4 wBn  = *(const uint4*)(pB);
            uint4 wB2n = *(const uint4*)(pB + 4);
            uint4 wCn  = *(const uint4*)(pB + 8);
            uint4 wC2n = *(const uint4*)(pB + 12);
            float dx = dt * xv;
            float Bv[DSTATE], Cv[DSTATE];
            unpack8(wB, Bv); unpack8(wB2, Bv + 8);
            unpack8(wC, Cv); unpack8(wC2, Cv + 8);
            float y0 = 0.f, y1 = 0.f, y2 = 0.f, y3 = 0.f;
#pragma unroll
            for (int s = 0; s < DSTATE; ++s) {
                h[s] = __builtin_fmaf(h[s], __builtin_amdgcn_exp2f(dt * a2[s]),
                                      dx * Bv[s]);
            }
#pragma unroll
            for (int s = 0; s < DSTATE; s += 4) {
                y0 = __builtin_fmaf(h[s],     Cv[s],     y0);
                y1 = __builtin_fmaf(h[s + 1], Cv[s + 1], y1);
                y2 = __builtin_fmaf(h[s + 2], Cv[s + 2], y2);
                y3 = __builtin_fmaf(h[s + 3], Cv[s + 3], y3);
            }
            float yv = ((y0 + y1) + (y2 + y3)) + Dd * xv;
            *py = f2bf(yv * zs); py += DINNER;
            dt = dt_n; xv = xv_n; zs = zs_n;
            wB = wBn; wB2 = wB2n; wC = wCn; wC2 = wC2n;
        }
    }
}

// masked-mean partials: grid (8 chunks, 32 b)
__global__ __launch_bounds__(256) void pool_partial_kernel(
    const float* __restrict__ subg, const float* __restrict__ incl,
    float* __restrict__ part, float* __restrict__ msump)
{
    int chunk = blockIdx.x, b = blockIdx.y, tid = threadIdx.x;
    float a0 = 0.f, a1 = 0.f, ms = 0.f;
    for (int l0 = 0; l0 < 128; ++l0) {
        int l = chunk * 128 + l0;
        float m = incl[b * LSEQ + l];
        const float* row = subg + ((size_t)b * LSEQ + l) * DMODEL;
        a0 += m * row[tid];
        a1 += m * row[tid + 256];
        ms += m;
    }
    int pi = (b * 8 + chunk) * DMODEL;
    part[pi + tid] = a0;
    part[pi + tid + 256] = a1;
    if (tid == 0) msump[b * 8 + chunk] = ms;
}

__global__ __launch_bounds__(256) void fc2_kernel(
    const float* __restrict__ part, const float* __restrict__ msump,
    const float* __restrict__ fc2w, const float* __restrict__ fc2b,
    float* __restrict__ out)
{
    int b = blockIdx.x, tid = threadIdx.x;
    __shared__ float pooled[DMODEL];
    float s0 = 0.f, s1 = 0.f, ms = 0.f;
#pragma unroll
    for (int c = 0; c < 8; ++c) {
        s0 += part[(b * 8 + c) * DMODEL + tid];
        s1 += part[(b * 8 + c) * DMODEL + tid + 256];
        ms += msump[b * 8 + c];
    }
    float inv = 1.f / (ms + 1e-5f);
    pooled[tid] = s0 * inv; pooled[tid + 256] = s1 * inv;
    __syncthreads();
    int wave = tid >> 6, lane = tid & 63;
    for (int c = wave; c < NCLASS; c += 4) {
        float s = 0.f;
#pragma unroll
        for (int k = lane; k < DMODEL; k += 64) s += pooled[k] * fc2w[c * DMODEL + k];
#pragma unroll
        for (int off = 32; off; off >>= 1) s += __shfl_xor(s, off, 64);
        if (lane == 0) out[b * NCLASS + c] = s + fc2b[c];
    }
}

// ---------------------------------------------------------------------------

extern "C" void kernel_launch(void* const* d_in, const int* in_sizes, int n_in,
                              void* d_out, int out_size, void* d_ws, size_t ws_size,
                              hipStream_t stream)
{
    (void)in_sizes; (void)n_in; (void)out_size; (void)ws_size;
    const int*   seq    = (const int*)  d_in[0];
    const float* incl   = (const float*)d_in[1];
    const float* emb    = (const float*)d_in[2];
    const float* fc1w   = (const float*)d_in[3];
    const float* fc1b   = (const float*)d_in[4];
    const float* fc2w   = (const float*)d_in[5];
    const float* fc2b   = (const float*)d_in[6];
    const float* nscale = (const float*)d_in[7];
    const float* ipw    = (const float*)d_in[8];
    const float* cw     = (const float*)d_in[9];
    const float* cbv    = (const float*)d_in[10];
    const float* xpw    = (const float*)d_in[11];
    const float* dtw    = (const float*)d_in[12];
    const float* dtb    = (const float*)d_in[13];
    const float* alog   = (const float*)d_in[14];
    const float* Dvec   = (const float*)d_in[15];
    const float* opw    = (const float*)d_in[16];
    float* outp = (float*)d_out;

    char* w = (char*)d_ws;
    size_t off = 0;
    auto take = [&](size_t bytes) {
        char* p = w + off; off += (bytes + 255) & ~(size_t)255; return p;
    };
    float* subg  = (float*)take((size_t)MROWS * DMODEL * 4);       // fp32 residual stream
    u16*   zi    = (u16*)  take((size_t)MROWS * DMODEL * 2);       // rmsnorm out (33.5MB)
    u16*   xzb   = (u16*)  take((size_t)MROWS * 2 * DINNER * 2);   // in_proj out (xin|silu(z))
    u16*   xconv = (u16*)  take((size_t)MROWS * DINNER * 2);       // conv+silu out
    u16*   xdbl  = (u16*)  take((size_t)MROWS * 128 * 2);          // x_proj out (pad 128)
    u16*   delta = (u16*)  take((size_t)MROWS * DINNER * 2);       // softplus(dt_proj)
    u16*   ybuf  = (u16*)  take((size_t)MROWS * DINNER * 2);       // scan out (gated)
    u16*   wip   = (u16*)  take((size_t)2 * 2 * DINNER * DMODEL * 2);
    u16*   wop   = (u16*)  take((size_t)2 * DMODEL * DINNER * 2);
    u16*   wxp   = (u16*)  take((size_t)2 * 128 * DINNER * 2);
    u16*   wdt   = (u16*)  take((size_t)2 * DINNER * DTRANK * 2);
    u16*   wfc1  = (u16*)  take((size_t)DMODEL * NFEAT * 2);
    float* part  = (float*)take((size_t)BATCH * 8 * DMODEL * 4);
    float* msump = (float*)take((size_t)BATCH * 8 * 4);
    float* dtsums= (float*)take((size_t)BATCH * NCHUNK * DINNER * 4);  // 2 MB
    u16*   gemb  = (u16*)delta;   // alias: gathered emb consumed before delta written
    float* states= (float*)zi;    // alias: zi dead after in_proj GEMM each layer (same 33.5MB)

    const int NOSILU = 0x7fffffff;

    // weight prep (ws re-poisoned every call, so redo each call)
    prep_weights_kernel<<<(CVT_TOTAL + 255) / 256, 256, 0, stream>>>(
        fc1w, wfc1, ipw, wip, opw, wop, dtw, wdt);
    pad_xpw_kernel<<<(2 * 128 * DINNER / 4) / 256, 256, 0, stream>>>(xpw, wxp);
    gather_kernel<<<MROWS * (NFEAT / 4) / 256, 256, 0, stream>>>(seq, emb, gemb);

    // subg = gathered_emb @ fc1_w^T + fc1_b   (f32 out)  [256^2 8-phase]
    gemm256<0, 0><<<dim3(MROWS / 256, DMODEL / 256), 512, 0, stream>>>(
        gemb, NFEAT, wfc1, NFEAT, subg, DMODEL, fc1b, NFEAT, NOSILU);

    const int scan_blocks = (BATCH * NCHUNK * DINNER) / 256;   // 2048
    for (int i = 0; i < 2; ++i) {
        const float* al = alog + i * DINNER * DSTATE;
        rmsnorm_kernel<<<MROWS / 4, 256, 0, stream>>>(subg, nscale + i * DMODEL, zi);
        // xz = zi @ in_proj_w^T  (bf16 out; silu fused on z-half cols >= DINNER)
        gemm256<1, 0><<<dim3(MROWS / 256, 2 * DINNER / 256), 512, 0, stream>>>(
            zi, DMODEL, wip + (size_t)i * 2 * DINNER * DMODEL, DMODEL,
            xzb, 2 * DINNER, nullptr, DMODEL, DINNER);
        conv_silu_kernel<<<MROWS * 128 / 256, 256, 0, stream>>>(
            xzb, cw + i * DINNER * 4, cbv + i * DINNER, xconv);
        // x_dbl = xconv @ x_proj_w^T (N padded to 128)  [128^2 kernel, N=128]
        gemm_bt<1, 0, 0><<<dim3(MROWS / 128, 1), 256, 0, stream>>>(
            xconv, DINNER, wxp + (size_t)i * 128 * DINNER, DINNER,
            xdbl, 128, nullptr, DINNER);
        // delta = softplus(dt @ dt_proj_w^T + dt_proj_b)  (K=32) [hw softplus]
        gemm_bt<1, 0, 1><<<dim3(MROWS / 128, DINNER / 128), 256, 0, stream>>>(
            xdbl, 128, wdt + (size_t)i * DINNER * DTRANK, DTRANK,
            delta, DINNER, dtb + i * DINNER, DTRANK);
        // chunked scan
        scan_p1<<<scan_blocks, 256, 0, stream>>>(delta, xconv, xdbl, al, states, dtsums);
        scan_p2<<<scan_blocks, 256, 0, stream>>>(states, dtsums, al);
        scan_p3<<<scan_blocks, 256, 0, stream>>>(delta, xconv, xzb, xdbl, al,
                                                 Dvec + i * DINNER, states, ybuf);
        // subg += y @ out_proj_w^T  (f32 accumulate)  [256^2 8-phase]
        gemm256<0, 1><<<dim3(MROWS / 256, DMODEL / 256), 512, 0, stream>>>(
            ybuf, DINNER, wop + (size_t)i * DMODEL * DINNER, DINNER,
            subg, DMODEL, nullptr, DINNER, NOSILU);
    }

    pool_partial_kernel<<<dim3(8, BATCH), 256, 0, stream>>>(subg, incl, part, msump);
    fc2_kernel<<<BATCH, 256, 0, stream>>>(part, msump, fc2w, fc2b, outp);
}

// Round 4
// 1279.457 us; speedup vs baseline: 1.5610x; 1.0109x over previous
//
#include <hip/hip_runtime.h>
#include <cstdint>
#include <cstddef>

#define LSEQ   1024
#define BATCH  32
#define NFEAT  512
#define DMODEL 512
#define DINNER 1024
#define DSTATE 16
#define DTRANK 32
#define NCLASS 40
#define MROWS  (BATCH * LSEQ)   // 32768
#define NCHUNK 16
#define CLEN   (LSEQ / NCHUNK)  // 64

typedef unsigned short u16;
typedef __attribute__((ext_vector_type(8))) __bf16 bf16x8;
typedef __attribute__((ext_vector_type(4))) float f32x4;
typedef __attribute__((ext_vector_type(8))) unsigned short u16x8;

__device__ __forceinline__ u16 f2bf(float x) {
    union { float f; unsigned u; } v; v.f = x;
    unsigned r = v.u + 0x7fffu + ((v.u >> 16) & 1u);   // round-to-nearest-even
    return (u16)(r >> 16);
}
__device__ __forceinline__ float bf2f(u16 h) {
    union { unsigned u; float f; } v; v.u = ((unsigned)h) << 16;
    return v.f;
}

// hw-approx silu: x * rcp(1 + exp2(-x*log2e)).
__device__ __forceinline__ float silu_hw(float x) {
    float e = __builtin_amdgcn_exp2f(-1.44269504089f * x);
    return x * __builtin_amdgcn_rcpf(1.f + e);
}
// hw-approx softplus: ln2 * log2(1 + exp2(x*log2e)); branch for large x.
__device__ __forceinline__ float softplus_hw(float x) {
    if (x > 15.f) return x;
    float e = __builtin_amdgcn_exp2f(1.44269504089f * x);
    return 0.69314718056f * __builtin_amdgcn_logf(1.f + e);
}

// dA[s] = g^(s+1), s=0..15, via 4-deep multiply tree (18 muls, no trans).
__device__ __forceinline__ void pow_dA(float g, float* dA) {
    float p2 = g * g, p4 = p2 * p2, p8 = p4 * p4;
    dA[0] = g;        dA[1] = p2;       dA[2] = p2 * g;   dA[3] = p4;
    dA[4] = p4 * g;   dA[5] = p4 * p2;  dA[6] = p4 * dA[2]; dA[7] = p8;
    dA[8] = p8 * g;   dA[9] = p8 * p2;  dA[10] = p8 * dA[2]; dA[11] = p8 * p4;
    dA[12] = p8 * dA[4]; dA[13] = p8 * dA[5]; dA[14] = p8 * dA[6]; dA[15] = p8 * p8;
}

// unpack 8 bf16 (packed in uint4) -> 8 floats; scalar-friendly (shift/and)
__device__ __forceinline__ void unpack8(uint4 w, float* f) {
    union { unsigned u; float v; } c;
    c.u = w.x << 16;         f[0] = c.v;
    c.u = w.x & 0xffff0000u; f[1] = c.v;
    c.u = w.y << 16;         f[2] = c.v;
    c.u = w.y & 0xffff0000u; f[3] = c.v;
    c.u = w.z << 16;         f[4] = c.v;
    c.u = w.z & 0xffff0000u; f[5] = c.v;
    c.u = w.w << 16;         f[6] = c.v;
    c.u = w.w & 0xffff0000u; f[7] = c.v;
}

#define GLL16(g, l) __builtin_amdgcn_global_load_lds( \
    (__attribute__((address_space(1))) void*)(g),     \
    (__attribute__((address_space(3))) void*)(l), 16, 0, 0)

// ---------------------------------------------------------------------------
// 256x256 8-phase GEMM (HK-style schedule, plain HIP).
// fc1, in_proj, out_proj.  silu fused on cols >= silu_from.
// ---------------------------------------------------------------------------
template<int OUT_BF16, int ACCUM>
__global__ __launch_bounds__(512, 2) void gemm256(
    const u16* __restrict__ A, int lda,
    const u16* __restrict__ B, int ldb,
    void* __restrict__ Cv, int ldc,
    const float* __restrict__ bias, int K, int silu_from)
{
    __shared__ __align__(16) u16 As[2][256 * 64];
    __shared__ __align__(16) u16 Bs[2][256 * 64];
    const int tid  = threadIdx.x;
    const int lane = tid & 63;
    const int wave = tid >> 6;            // 0..7
    const int wr   = (wave >> 2) * 128;   // 0 or 128
    const int wc   = (wave & 3) * 64;     // 0,64,128,192
    const int frow = lane & 15;
    const int quad = lane >> 4;
    const int m0   = blockIdx.x * 256;
    const int n0   = blockIdx.y * 256;

    // staging map (constant per thread): one GLL sweep = 8KB = 64 rows
    const int srow = tid >> 3;                   // row within quarter (0..63)
    const int slb  = (tid & 7) ^ (srow & 7);     // logical 16B-block (inverse swz)
    const u16* gA = A + (size_t)(m0 + srow) * lda + slb * 8;
    const u16* gB = B + (size_t)(n0 + srow) * ldb + slb * 8;

    // read-side per-lane swizzled k-offsets (u16 units)
    const int cb0 = ((quad)     ^ (frow & 7)) * 8;   // kk=0
    const int cb1 = ((4 + quad) ^ (frow & 7)) * 8;   // kk=1

#define STAGE_A(sb, tt, q) GLL16(gA + (size_t)(q) * 64 * lda + (size_t)(tt) * 64, \
                                 &As[sb][(q) * 4096 + tid * 8])
#define STAGE_B(sb, tt, q) GLL16(gB + (size_t)(q) * 64 * ldb + (size_t)(tt) * 64, \
                                 &Bs[sb][(q) * 4096 + tid * 8])

    f32x4 acc[8][4];
#pragma unroll
    for (int i = 0; i < 8; ++i)
#pragma unroll
        for (int j = 0; j < 4; ++j) acc[i][j] = (f32x4){0.f, 0.f, 0.f, 0.f};

    const int NT = K >> 6;

    // prologue: stage tiles 0 and 1 (8 loads each), wait tile 0
#pragma unroll
    for (int q = 0; q < 4; ++q) STAGE_A(0, 0, q);
#pragma unroll
    for (int q = 0; q < 4; ++q) STAGE_B(0, 0, q);
#pragma unroll
    for (int q = 0; q < 4; ++q) STAGE_A(1, 1, q);
#pragma unroll
    for (int q = 0; q < 4; ++q) STAGE_B(1, 1, q);
    asm volatile("s_waitcnt vmcnt(8)" ::: "memory");
    __builtin_amdgcn_s_barrier();

    for (int t = 0; t < NT; ++t) {
        const int bsel = t & 1;
        const u16* __restrict__ Ab = &As[bsel][0];
        const u16* __restrict__ Bb = &Bs[bsel][0];
        const int stage = (t + 2 < NT);
        const int t2 = t + 2;
        const int rA = wr + frow;
        const int rB = wc + frow;
        bf16x8 af[4][2], b0[2][2], b1[2][2];

        // ---- P1: read af0 (M-half0) + bf0 (N-half0); stage Aq0,Aq2 ----
#pragma unroll
        for (int m = 0; m < 4; ++m) {
            const u16* p = Ab + (rA + m * 16) * 64;
            af[m][0] = *(const bf16x8*)(p + cb0);
            af[m][1] = *(const bf16x8*)(p + cb1);
        }
#pragma unroll
        for (int n = 0; n < 2; ++n) {
            const u16* p = Bb + (rB + n * 16) * 64;
            b0[n][0] = *(const bf16x8*)(p + cb0);
            b0[n][1] = *(const bf16x8*)(p + cb1);
        }
        if (stage) { STAGE_A(bsel, t2, 0); STAGE_A(bsel, t2, 2); }
        __builtin_amdgcn_s_barrier();
        asm volatile("s_waitcnt lgkmcnt(0)" ::: "memory");
        __builtin_amdgcn_sched_barrier(0);
        __builtin_amdgcn_s_setprio(1);
#pragma unroll
        for (int m = 0; m < 4; ++m)
#pragma unroll
            for (int n = 0; n < 2; ++n) {
                acc[m][n] = __builtin_amdgcn_mfma_f32_16x16x32_bf16(af[m][0], b0[n][0], acc[m][n], 0, 0, 0);
                acc[m][n] = __builtin_amdgcn_mfma_f32_16x16x32_bf16(af[m][1], b0[n][1], acc[m][n], 0, 0, 0);
            }
        __builtin_amdgcn_s_setprio(0);
        __builtin_amdgcn_s_barrier();

        // ---- P2: read bf1 (N-half1); stage Bq0,Bq1 ----
#pragma unroll
        for (int n = 0; n < 2; ++n) {
            const u16* p = Bb + (rB + 32 + n * 16) * 64;
            b1[n][0] = *(const bf16x8*)(p + cb0);
            b1[n][1] = *(const bf16x8*)(p + cb1);
        }
        if (stage) { STAGE_B(bsel, t2, 0); STAGE_B(bsel, t2, 1); }
        __builtin_amdgcn_s_barrier();
        asm volatile("s_waitcnt lgkmcnt(0)" ::: "memory");
        __builtin_amdgcn_sched_barrier(0);
        __builtin_amdgcn_s_setprio(1);
#pragma unroll
        for (int m = 0; m < 4; ++m)
#pragma unroll
            for (int n = 0; n < 2; ++n) {
                acc[m][2 + n] = __builtin_amdgcn_mfma_f32_16x16x32_bf16(af[m][0], b1[n][0], acc[m][2 + n], 0, 0, 0);
                acc[m][2 + n] = __builtin_amdgcn_mfma_f32_16x16x32_bf16(af[m][1], b1[n][1], acc[m][2 + n], 0, 0, 0);
            }
        __builtin_amdgcn_s_setprio(0);
        __builtin_amdgcn_s_barrier();

        // ---- P3: read af1 (M-half1, overwrite af regs); stage Aq1,Aq3 ----
#pragma unroll
        for (int m = 0; m < 4; ++m) {
            const u16* p = Ab + (rA + 64 + m * 16) * 64;
            af[m][0] = *(const bf16x8*)(p + cb0);
            af[m][1] = *(const bf16x8*)(p + cb1);
        }
        if (stage) { STAGE_A(bsel, t2, 1); STAGE_A(bsel, t2, 3); }
        __builtin_amdgcn_s_barrier();
        asm volatile("s_waitcnt lgkmcnt(0)" ::: "memory");
        __builtin_amdgcn_sched_barrier(0);
        __builtin_amdgcn_s_setprio(1);
#pragma unroll
        for (int m = 0; m < 4; ++m)
#pragma unroll
            for (int n = 0; n < 2; ++n) {
                acc[4 + m][2 + n] = __builtin_amdgcn_mfma_f32_16x16x32_bf16(af[m][0], b1[n][0], acc[4 + m][2 + n], 0, 0, 0);
                acc[4 + m][2 + n] = __builtin_amdgcn_mfma_f32_16x16x32_bf16(af[m][1], b1[n][1], acc[4 + m][2 + n], 0, 0, 0);
            }
        __builtin_amdgcn_s_setprio(0);
        __builtin_amdgcn_s_barrier();

        // ---- P4: no reads (bf0 live); stage Bq2,Bq3; counted vmcnt ----
        if (stage) {
            STAGE_B(bsel, t2, 2); STAGE_B(bsel, t2, 3);
            asm volatile("s_waitcnt vmcnt(8)" ::: "memory");
        } else {
            asm volatile("s_waitcnt vmcnt(0)" ::: "memory");
        }
        __builtin_amdgcn_s_barrier();
        __builtin_amdgcn_s_setprio(1);
#pragma unroll
        for (int m = 0; m < 4; ++m)
#pragma unroll
            for (int n = 0; n < 2; ++n) {
                acc[4 + m][n] = __builtin_amdgcn_mfma_f32_16x16x32_bf16(af[m][0], b0[n][0], acc[4 + m][n], 0, 0, 0);
                acc[4 + m][n] = __builtin_amdgcn_mfma_f32_16x16x32_bf16(af[m][1], b0[n][1], acc[4 + m][n], 0, 0, 0);
            }
        __builtin_amdgcn_s_setprio(0);
        __builtin_amdgcn_s_barrier();
    }
#undef STAGE_A
#undef STAGE_B

    // epilogue
    float bv[4];
#pragma unroll
    for (int n = 0; n < 4; ++n) {
        int col = n0 + wc + (n >> 1) * 32 + (n & 1) * 16 + frow;
        bv[n] = bias ? bias[col] : 0.f;
    }
#pragma unroll
    for (int m = 0; m < 8; ++m) {
        size_t row0 = (size_t)(m0 + wr + (m >> 2) * 64 + (m & 3) * 16 + quad * 4);
#pragma unroll
        for (int r = 0; r < 4; ++r) {
#pragma unroll
            for (int n = 0; n < 4; ++n) {
                int col = n0 + wc + (n >> 1) * 32 + (n & 1) * 16 + frow;
                size_t cidx = (row0 + r) * (size_t)ldc + (size_t)col;
                float v = acc[m][n][r] + bv[n];
                if (col >= silu_from) v = silu_hw(v);
                if (OUT_BF16)      ((u16*)Cv)[cidx] = f2bf(v);
                else if (ACCUM)    ((float*)Cv)[cidx] += v;
                else               ((float*)Cv)[cidx] = v;
            }
        }
    }
}

// ---------------------------------------------------------------------------
// x_dbl = x_proj( silu(conv(x)) ), conv fused into A-operand staging.
// B = x_proj_w (64x1024 f32) cvt->bf16, fully LDS-resident (128KB, XOR-swz,
// no K-loop barriers).  Out: xdbl[M][64] bf16 (cols: dt32 | B16 | C16).
// Block: 256 thr / 4 waves; 64 rows/block; grid M/64 = 512.
// ---------------------------------------------------------------------------
__global__ __launch_bounds__(256) void xp_conv_kernel(
    const u16* __restrict__ xz, const float* __restrict__ xpw_l,
    const float* __restrict__ cw, const float* __restrict__ cbv,
    u16* __restrict__ xdbl)
{
    __shared__ __align__(16) u16 Bs[64 * 1024];   // 128KB
    const int tid  = threadIdx.x;
    const int lane = tid & 63;
    const int wave = tid >> 6;
    const int frow = lane & 15;
    const int quad = lane >> 4;

    // stage B: thread t -> row n = t>>2, 8-elt blocks kb = (t&3)*32..+31
    {
        const int n   = tid >> 2;
        const int kb0 = (tid & 3) * 32;
        const float* src = xpw_l + (size_t)n * 1024 + (size_t)kb0 * 8;
        u16* dstrow = Bs + n * 1024;
        for (int i = 0; i < 32; ++i) {
            float4 a = ((const float4*)src)[i * 2];
            float4 b = ((const float4*)src)[i * 2 + 1];
            u16x8 o;
            o[0] = f2bf(a.x); o[1] = f2bf(a.y); o[2] = f2bf(a.z); o[3] = f2bf(a.w);
            o[4] = f2bf(b.x); o[5] = f2bf(b.y); o[6] = f2bf(b.z); o[7] = f2bf(b.w);
            int kb = kb0 + i;
            *(u16x8*)(dstrow + ((kb ^ (n & 7)) << 3)) = o;
        }
    }
    __syncthreads();

    const int r0 = blockIdx.x * 64;
    const int ra = r0 + wave * 16 + frow;            // this lane's A row
    const int l  = ra & (LSEQ - 1);
    const u16* xrow = xz + (size_t)ra * (2 * DINNER);  // x-half base
    f32x4 acc[4];
#pragma unroll
    for (int c = 0; c < 4; ++c) acc[c] = (f32x4){0.f, 0.f, 0.f, 0.f};

    for (int kk = 0; kk < 32; ++kk) {
        const int d0 = kk * 32 + quad * 8;
        u16x8 zero{};
        u16x8 t3 = *(const u16x8*)(xrow + d0);
        u16x8 t2 = (l >= 1) ? *(const u16x8*)(xrow - 2 * DINNER + d0) : zero;
        u16x8 t1 = (l >= 2) ? *(const u16x8*)(xrow - 4 * DINNER + d0) : zero;
        u16x8 t0 = (l >= 3) ? *(const u16x8*)(xrow - 6 * DINNER + d0) : zero;
        u16x8 afr;
#pragma unroll
        for (int c = 0; c < 8; ++c) {
            float4 wv = ((const float4*)cw)[d0 + c];
            float a = cbv[d0 + c]
                    + wv.x * bf2f(t0[c]) + wv.y * bf2f(t1[c])
                    + wv.z * bf2f(t2[c]) + wv.w * bf2f(t3[c]);
            afr[c] = f2bf(silu_hw(a));
        }
        bf16x8 af = *(bf16x8*)&afr;
#pragma unroll
        for (int c = 0; c < 4; ++c) {
            const int col = c * 16 + frow;
            const int kb  = (kk * 4 + quad) ^ (col & 7);
            bf16x8 bf = *(const bf16x8*)(Bs + col * 1024 + kb * 8);
            acc[c] = __builtin_amdgcn_mfma_f32_16x16x32_bf16(af, bf, acc[c], 0, 0, 0);
        }
    }
#pragma unroll
    for (int c = 0; c < 4; ++c)
#pragma unroll
        for (int r = 0; r < 4; ++r) {
            int row = r0 + wave * 16 + quad * 4 + r;
            xdbl[(size_t)row * 64 + c * 16 + frow] = f2bf(acc[c][r]);
        }
}

// ---------------------------------------------------------------------------
// delta = softplus(xdbl[:, :32] @ dtw^T + dtb).  K=32 = ONE MFMA step.
// dtw 256-col tile LDS-resident (16KB, cvt f32->bf16, light swz).
// Block: 256 thr / 4 waves; 64 rows x 256 cols; grid (512, 4).
// ---------------------------------------------------------------------------
__global__ __launch_bounds__(256) void dt_kernel(
    const u16* __restrict__ xdbl, const float* __restrict__ dtw_l,
    const float* __restrict__ dtb_l, u16* __restrict__ delta)
{
    __shared__ __align__(16) u16 Bs[256 * 32];    // 16KB
    const int tid  = threadIdx.x;
    const int lane = tid & 63;
    const int wave = tid >> 6;
    const int frow = lane & 15;
    const int quad = lane >> 4;
    const int n0   = blockIdx.y * 256;
    {
        const int n = tid;                        // one 32-elt row per thread
        const float* src = dtw_l + (size_t)(n0 + n) * 32;
        u16* dstrow = Bs + n * 32;
        for (int i = 0; i < 4; ++i) {
            float4 a = ((const float4*)src)[i * 2];
            float4 b = ((const float4*)src)[i * 2 + 1];
            u16x8 o;
            o[0] = f2bf(a.x); o[1] = f2bf(a.y); o[2] = f2bf(a.z); o[3] = f2bf(a.w);
            o[4] = f2bf(b.x); o[5] = f2bf(b.y); o[6] = f2bf(b.z); o[7] = f2bf(b.w);
            *(u16x8*)(dstrow + ((i ^ (n & 3)) << 3)) = o;
        }
    }
    __syncthreads();

    const int r0 = blockIdx.x * 64 + wave * 16;
    bf16x8 af = *(const bf16x8*)(xdbl + (size_t)(r0 + frow) * 64 + quad * 8);
    f32x4 acc[16];
#pragma unroll
    for (int c = 0; c < 16; ++c) acc[c] = (f32x4){0.f, 0.f, 0.f, 0.f};
#pragma unroll
    for (int c = 0; c < 16; ++c) {
        const int col = c * 16 + frow;
        const int kb  = quad ^ (col & 3);
        bf16x8 bf = *(const bf16x8*)(Bs + col * 32 + kb * 8);
        acc[c] = __builtin_amdgcn_mfma_f32_16x16x32_bf16(af, bf, acc[c], 0, 0, 0);
    }
#pragma unroll
    for (int c = 0; c < 16; ++c) {
        float bv = dtb_l[n0 + c * 16 + frow];
#pragma unroll
        for (int r = 0; r < 4; ++r) {
            int row = r0 + quad * 4 + r;
            float v = softplus_hw(acc[c][r] + bv);
            delta[(size_t)row * DINNER + n0 + c * 16 + frow] = f2bf(v);
        }
    }
}

// --------------------------- elementwise / prep ----------------------------

// merged f32->bf16 weight conversion: fc1 | ip | op ranges (float4 units)
#define CVT_N_FC1 65536      // 512*512/4
#define CVT_N_IP  524288     // 2*2048*512/4
#define CVT_N_OP  262144     // 2*512*1024/4
#define CVT_TOTAL (CVT_N_FC1 + CVT_N_IP + CVT_N_OP)

__global__ __launch_bounds__(256) void prep_weights_kernel(
    const float* __restrict__ fc1w, u16* __restrict__ wfc1,
    const float* __restrict__ ipw,  u16* __restrict__ wip,
    const float* __restrict__ opw,  u16* __restrict__ wop)
{
    int i = blockIdx.x * 256 + threadIdx.x;
    if (i >= CVT_TOTAL) return;
    const float* src; u16* dst; int j = i;
    if (j < CVT_N_FC1)                    { src = fc1w; dst = wfc1; }
    else if ((j -= CVT_N_FC1) < CVT_N_IP) { src = ipw;  dst = wip;  }
    else { j -= CVT_N_IP;                   src = opw;  dst = wop;  }
    float4 v = ((const float4*)src)[j];
    ushort4 o; o.x = f2bf(v.x); o.y = f2bf(v.y); o.z = f2bf(v.z); o.w = f2bf(v.w);
    ((ushort4*)dst)[j] = o;
}

// gathered_emb[m,:] = bf16(embeddings[sequence[m],:])
__global__ __launch_bounds__(256) void gather_kernel(
    const int* __restrict__ seq, const float* __restrict__ emb, u16* __restrict__ g)
{
    int i   = blockIdx.x * 256 + threadIdx.x;  // per float4; total MROWS*128
    int row = i >> 7, c = i & 127;
    int node = seq[row];
    float4 v = ((const float4*)(emb + (size_t)node * NFEAT))[c];
    ushort4 o; o.x = f2bf(v.x); o.y = f2bf(v.y); o.z = f2bf(v.z); o.w = f2bf(v.w);
    ((ushort4*)g)[i] = o;
}

// zi = scale * x / (||x||/sqrt(512) + 1e-8), one wave per row
__global__ __launch_bounds__(256) void rmsnorm_kernel(
    const float* __restrict__ x, const float* __restrict__ scale, u16* __restrict__ o)
{
    int wave = threadIdx.x >> 6, lane = threadIdx.x & 63;
    size_t row = (size_t)blockIdx.x * 4 + wave;
    const float4* xr = (const float4*)(x + row * DMODEL);
    float4 v0 = xr[lane], v1 = xr[lane + 64];
    float ss = v0.x*v0.x + v0.y*v0.y + v0.z*v0.z + v0.w*v0.w
             + v1.x*v1.x + v1.y*v1.y + v1.z*v1.z + v1.w*v1.w;
#pragma unroll
    for (int off = 32; off; off >>= 1) ss += __shfl_xor(ss, off, 64);
    float inv = 1.f / (sqrtf(ss * (1.f / DMODEL)) + 1e-8f);
    const float4* sc = (const float4*)scale;
    float4 s0 = sc[lane], s1 = sc[lane + 64];
    ushort4 o0, o1;
    o0.x = f2bf(v0.x * s0.x * inv); o0.y = f2bf(v0.y * s0.y * inv);
    o0.z = f2bf(v0.z * s0.z * inv); o0.w = f2bf(v0.w * s0.w * inv);
    o1.x = f2bf(v1.x * s1.x * inv); o1.y = f2bf(v1.y * s1.y * inv);
    o1.z = f2bf(v1.z * s1.z * inv); o1.w = f2bf(v1.w * s1.w * inv);
    ushort4* op = (ushort4*)(o + row * DMODEL);
    op[lane] = o0; op[lane + 64] = o1;
}

// ---------------------------------------------------------------------------
// Chunked selective scan; conv+silu computed INLINE from xzb (3-reg rolling
// window) -- xconv is never materialized.
// ---------------------------------------------------------------------------
__device__ __forceinline__ int detect_s4d(const float* a2) {
    int fast = 1;
#pragma unroll
    for (int s = 1; s < DSTATE; ++s)
        fast &= (__builtin_fabsf(a2[s] - (float)(s + 1) * a2[0]) <=
                 1e-4f * (float)(s + 1) * __builtin_fabsf(a2[0]) + 1e-6f);
    return fast;
}

__global__ __launch_bounds__(256) void scan_p1(
    const u16* __restrict__ delta, const u16* __restrict__ xz,
    const u16* __restrict__ xdbl, const float* __restrict__ cw,
    const float* __restrict__ cbv, const float* __restrict__ alog,
    float* __restrict__ states, float* __restrict__ dtsums)
{
    const int bid = blockIdx.x;
    const int d0  = (bid & 3) << 8;
    const int k   = (bid >> 2) & (NCHUNK - 1);
    const int b   = bid >> 6;
    const int d   = d0 + threadIdx.x;

    float a2[DSTATE];
#pragma unroll
    for (int s = 0; s < DSTATE; ++s)
        a2[s] = -expf(alog[d * DSTATE + s]) * 1.44269504f;
    const int fastA = detect_s4d(a2);
    const float ab = a2[0];
    const float4 wcv = ((const float4*)cw)[d];
    const float cb = cbv[d];

    float h[DSTATE];
#pragma unroll
    for (int s = 0; s < DSTATE; ++s) h[s] = 0.f;
    float dtsum = 0.f;

    const size_t r0 = (size_t)b * LSEQ + (size_t)k * CLEN;
    const u16* pd  = delta + r0 * DINNER + d;
    const u16* pxz = xz + r0 * (2 * DINNER) + d;
    const unsigned* pB = (const unsigned*)(xdbl + r0 * 64) + 16;  // uniform

    // conv window (rows before chunk start; zero only for k==0)
    float xm3 = (k > 0) ? bf2f(pxz[-6 * DINNER]) : 0.f;
    float xm2 = (k > 0) ? bf2f(pxz[-4 * DINNER]) : 0.f;
    float xm1 = (k > 0) ? bf2f(pxz[-2 * DINNER]) : 0.f;

    float dt = bf2f(*pd), xraw = bf2f(*pxz);
    uint4 wB  = *(const uint4*)(pB);
    uint4 wB2 = *(const uint4*)(pB + 4);

    if (fastA) {
        for (int j = 0; j < CLEN; ++j) {
            pd += DINNER; pxz += 2 * DINNER; pB += 32;
            float dt_n = bf2f(*pd), xraw_n = bf2f(*pxz);
            uint4 wBn  = *(const uint4*)(pB);
            uint4 wB2n = *(const uint4*)(pB + 4);
            float xc = silu_hw(cb + wcv.x * xm3 + wcv.y * xm2
                             + wcv.z * xm1 + wcv.w * xraw);
            xm3 = xm2; xm2 = xm1; xm1 = xraw;
            float dx = dt * xc;
            dtsum += dt;
            float dA[DSTATE];
            pow_dA(__builtin_amdgcn_exp2f(dt * ab), dA);
            float Bv[DSTATE];
            unpack8(wB, Bv); unpack8(wB2, Bv + 8);
#pragma unroll
            for (int s = 0; s < DSTATE; ++s)
                h[s] = __builtin_fmaf(h[s], dA[s], dx * Bv[s]);
            dt = dt_n; xraw = xraw_n; wB = wBn; wB2 = wB2n;
        }
    } else {
        for (int j = 0; j < CLEN; ++j) {
            pd += DINNER; pxz += 2 * DINNER; pB += 32;
            float dt_n = bf2f(*pd), xraw_n = bf2f(*pxz);
            uint4 wBn  = *(const uint4*)(pB);
            uint4 wB2n = *(const uint4*)(pB + 4);
            float xc = silu_hw(cb + wcv.x * xm3 + wcv.y * xm2
                             + wcv.z * xm1 + wcv.w * xraw);
            xm3 = xm2; xm2 = xm1; xm1 = xraw;
            float dx = dt * xc;
            dtsum += dt;
            float Bv[DSTATE];
            unpack8(wB, Bv); unpack8(wB2, Bv + 8);
#pragma unroll
            for (int s = 0; s < DSTATE; ++s)
                h[s] = __builtin_fmaf(h[s], __builtin_amdgcn_exp2f(dt * a2[s]),
                                      dx * Bv[s]);
            dt = dt_n; xraw = xraw_n; wB = wBn; wB2 = wB2n;
        }
    }

    size_t t = (size_t)(b * NCHUNK + k) * DINNER + d;
    f32x4* st = (f32x4*)(states + t * DSTATE);
#pragma unroll
    for (int q = 0; q < 4; ++q)
        st[q] = (f32x4){h[q * 4], h[q * 4 + 1], h[q * 4 + 2], h[q * 4 + 3]};
    dtsums[t] = dtsum;
}

__global__ __launch_bounds__(256) void scan_p2(
    float* __restrict__ states, const float* __restrict__ dtsums,
    const float* __restrict__ alog)
{
    int t = blockIdx.x * 256 + threadIdx.x;   // 0 .. B*DINNER*DSTATE-1
    int s = t & (DSTATE - 1);
    int d = (t >> 4) & (DINNER - 1);
    int b = t >> 14;
    float a2 = -expf(alog[d * DSTATE + s]) * 1.44269504f;
    float H = 0.f;
    for (int k = 0; k < NCHUNK; ++k) {
        size_t ci = ((size_t)b * NCHUNK + k) * DINNER + d;
        size_t idx = ci * DSTATE + s;
        float hk = states[idx];
        float P = __builtin_amdgcn_exp2f(a2 * dtsums[ci]);
        states[idx] = H;                 // exclusive incoming state for chunk k
        H = hk + P * H;
    }
}

__global__ __launch_bounds__(256) void scan_p3(
    const u16* __restrict__ delta, const u16* __restrict__ xz,
    const u16* __restrict__ xdbl, const float* __restrict__ cw,
    const float* __restrict__ cbv, const float* __restrict__ alog,
    const float* __restrict__ Dvec, const float* __restrict__ states,
    u16* __restrict__ ybuf)
{
    const int bid = blockIdx.x;
    const int d0  = (bid & 3) << 8;
    const int k   = (bid >> 2) & (NCHUNK - 1);
    const int b   = bid >> 6;
    const int d   = d0 + threadIdx.x;

    float a2[DSTATE];
#pragma unroll
    for (int s = 0; s < DSTATE; ++s)
        a2[s] = -expf(alog[d * DSTATE + s]) * 1.44269504f;
    const int fastA = detect_s4d(a2);
    const float ab = a2[0];
    const float Dd = Dvec[d];
    const float4 wcv = ((const float4*)cw)[d];
    const float cb = cbv[d];

    float h[DSTATE];
    size_t t = (size_t)(b * NCHUNK + k) * DINNER + d;
    const f32x4* st = (const f32x4*)(states + t * DSTATE);
#pragma unroll
    for (int q = 0; q < 4; ++q) {
        f32x4 v = st[q];
        h[q * 4] = v[0]; h[q * 4 + 1] = v[1]; h[q * 4 + 2] = v[2]; h[q * 4 + 3] = v[3];
    }

    const size_t r0 = (size_t)b * LSEQ + (size_t)k * CLEN;
    const u16* pd  = delta + r0 * DINNER + d;
    const u16* pxz = xz + r0 * (2 * DINNER) + d;
    const u16* pz  = xz + r0 * (2 * DINNER) + DINNER + d;
    const unsigned* pB = (const unsigned*)(xdbl + r0 * 64) + 16;  // uniform
    u16* py = ybuf + r0 * DINNER + d;

    float xm3 = (k > 0) ? bf2f(pxz[-6 * DINNER]) : 0.f;
    float xm2 = (k > 0) ? bf2f(pxz[-4 * DINNER]) : 0.f;
    float xm1 = (k > 0) ? bf2f(pxz[-2 * DINNER]) : 0.f;

    float dt = bf2f(*pd), xraw = bf2f(*pxz), zs = bf2f(*pz);
    uint4 wB  = *(const uint4*)(pB);
    uint4 wB2 = *(const uint4*)(pB + 4);
    uint4 wC  = *(const uint4*)(pB + 8);
    uint4 wC2 = *(const uint4*)(pB + 12);

    if (fastA) {
        for (int j = 0; j < CLEN; ++j) {
            pd += DINNER; pxz += 2 * DINNER; pz += 2 * DINNER; pB += 32;
            float dt_n = bf2f(*pd), xraw_n = bf2f(*pxz), zs_n = bf2f(*pz);
            uint4 wBn  = *(const uint4*)(pB);
            uint4 wB2n = *(const uint4*)(pB + 4);
            uint4 wCn  = *(const uint4*)(pB + 8);
            uint4 wC2n = *(const uint4*)(pB + 12);
            float xc = silu_hw(cb + wcv.x * xm3 + wcv.y * xm2
                             + wcv.z * xm1 + wcv.w * xraw);
            xm3 = xm2; xm2 = xm1; xm1 = xraw;
            float dx = dt * xc;
            float dA[DSTATE];
            pow_dA(__builtin_amdgcn_exp2f(dt * ab), dA);
            float Bv[DSTATE], Cv[DSTATE];
            unpack8(wB, Bv); unpack8(wB2, Bv + 8);
            unpack8(wC, Cv); unpack8(wC2, Cv + 8);
            float y0 = 0.f, y1 = 0.f, y2 = 0.f, y3 = 0.f;
#pragma unroll
            for (int s = 0; s < DSTATE; ++s)
                h[s] = __builtin_fmaf(h[s], dA[s], dx * Bv[s]);
#pragma unroll
            for (int s = 0; s < DSTATE; s += 4) {
                y0 = __builtin_fmaf(h[s],     Cv[s],     y0);
                y1 = __builtin_fmaf(h[s + 1], Cv[s + 1], y1);
                y2 = __builtin_fmaf(h[s + 2], Cv[s + 2], y2);
                y3 = __builtin_fmaf(h[s + 3], Cv[s + 3], y3);
            }
            float yv = ((y0 + y1) + (y2 + y3)) + Dd * xc;
            *py = f2bf(yv * zs); py += DINNER;
            dt = dt_n; xraw = xraw_n; zs = zs_n;
            wB = wBn; wB2 = wB2n; wC = wCn; wC2 = wC2n;
        }
    } else {
        for (int j = 0; j < CLEN; ++j) {
            pd += DINNER; pxz += 2 * DINNER; pz += 2 * DINNER; pB += 32;
            float dt_n = bf2f(*pd), xraw_n = bf2f(*pxz), zs_n = bf2f(*pz);
            uint4 wBn  = *(const uint4*)(pB);
            uint4 wB2n = *(const uint4*)(pB + 4);
            uint4 wCn  = *(const uint4*)(pB + 8);
            uint4 wC2n = *(const uint4*)(pB + 12);
            float xc = silu_hw(cb + wcv.x * xm3 + wcv.y * xm2
                             + wcv.z * xm1 + wcv.w * xraw);
            xm3 = xm2; xm2 = xm1; xm1 = xraw;
            float dx = dt * xc;
            float Bv[DSTATE], Cv[DSTATE];
            unpack8(wB, Bv); unpack8(wB2, Bv + 8);
            unpack8(wC, Cv); unpack8(wC2, Cv + 8);
            float y0 = 0.f, y1 = 0.f, y2 = 0.f, y3 = 0.f;
#pragma unroll
            for (int s = 0; s < DSTATE; ++s) {
                h[s] = __builtin_fmaf(h[s], __builtin_amdgcn_exp2f(dt * a2[s]),
                                      dx * Bv[s]);
            }
#pragma unroll
            for (int s = 0; s < DSTATE; s += 4) {
                y0 = __builtin_fmaf(h[s],     Cv[s],     y0);
                y1 = __builtin_fmaf(h[s + 1], Cv[s + 1], y1);
                y2 = __builtin_fmaf(h[s + 2], Cv[s + 2], y2);
                y3 = __builtin_fmaf(h[s + 3], Cv[s + 3], y3);
            }
            float yv = ((y0 + y1) + (y2 + y3)) + Dd * xc;
            *py = f2bf(yv * zs); py += DINNER;
            dt = dt_n; xraw = xraw_n; zs = zs_n;
            wB = wBn; wB2 = wB2n; wC = wCn; wC2 = wC2n;
        }
    }
}

// masked-mean partials: grid (8 chunks, 32 b)
__global__ __launch_bounds__(256) void pool_partial_kernel(
    const float* __restrict__ subg, const float* __restrict__ incl,
    float* __restrict__ part, float* __restrict__ msump)
{
    int chunk = blockIdx.x, b = blockIdx.y, tid = threadIdx.x;
    float a0 = 0.f, a1 = 0.f, ms = 0.f;
    for (int l0 = 0; l0 < 128; ++l0) {
        int l = chunk * 128 + l0;
        float m = incl[b * LSEQ + l];
        const float* row = subg + ((size_t)b * LSEQ + l) * DMODEL;
        a0 += m * row[tid];
        a1 += m * row[tid + 256];
        ms += m;
    }
    int pi = (b * 8 + chunk) * DMODEL;
    part[pi + tid] = a0;
    part[pi + tid + 256] = a1;
    if (tid == 0) msump[b * 8 + chunk] = ms;
}

__global__ __launch_bounds__(256) void fc2_kernel(
    const float* __restrict__ part, const float* __restrict__ msump,
    const float* __restrict__ fc2w, const float* __restrict__ fc2b,
    float* __restrict__ out)
{
    int b = blockIdx.x, tid = threadIdx.x;
    __shared__ float pooled[DMODEL];
    float s0 = 0.f, s1 = 0.f, ms = 0.f;
#pragma unroll
    for (int c = 0; c < 8; ++c) {
        s0 += part[(b * 8 + c) * DMODEL + tid];
        s1 += part[(b * 8 + c) * DMODEL + tid + 256];
        ms += msump[b * 8 + c];
    }
    float inv = 1.f / (ms + 1e-5f);
    pooled[tid] = s0 * inv; pooled[tid + 256] = s1 * inv;
    __syncthreads();
    int wave = tid >> 6, lane = tid & 63;
    for (int c = wave; c < NCLASS; c += 4) {
        float s = 0.f;
#pragma unroll
        for (int k = lane; k < DMODEL; k += 64) s += pooled[k] * fc2w[c * DMODEL + k];
#pragma unroll
        for (int off = 32; off; off >>= 1) s += __shfl_xor(s, off, 64);
        if (lane == 0) out[b * NCLASS + c] = s + fc2b[c];
    }
}

// ---------------------------------------------------------------------------

extern "C" void kernel_launch(void* const* d_in, const int* in_sizes, int n_in,
                              void* d_out, int out_size, void* d_ws, size_t ws_size,
                              hipStream_t stream)
{
    (void)in_sizes; (void)n_in; (void)out_size; (void)ws_size;
    const int*   seq    = (const int*)  d_in[0];
    const float* incl   = (const float*)d_in[1];
    const float* emb    = (const float*)d_in[2];
    const float* fc1w   = (const float*)d_in[3];
    const float* fc1b   = (const float*)d_in[4];
    const float* fc2w   = (const float*)d_in[5];
    const float* fc2b   = (const float*)d_in[6];
    const float* nscale = (const float*)d_in[7];
    const float* ipw    = (const float*)d_in[8];
    const float* cw     = (const float*)d_in[9];
    const float* cbv    = (const float*)d_in[10];
    const float* xpw    = (const float*)d_in[11];
    const float* dtw    = (const float*)d_in[12];
    const float* dtb    = (const float*)d_in[13];
    const float* alog   = (const float*)d_in[14];
    const float* Dvec   = (const float*)d_in[15];
    const float* opw    = (const float*)d_in[16];
    float* outp = (float*)d_out;

    char* w = (char*)d_ws;
    size_t off = 0;
    auto take = [&](size_t bytes) {
        char* p = w + off; off += (bytes + 255) & ~(size_t)255; return p;
    };
    float* subg  = (float*)take((size_t)MROWS * DMODEL * 4);       // fp32 residual stream
    u16*   zi    = (u16*)  take((size_t)MROWS * DMODEL * 2);       // rmsnorm out (33.5MB)
    u16*   xzb   = (u16*)  take((size_t)MROWS * 2 * DINNER * 2);   // in_proj out (xin|silu(z))
    u16*   xdbl  = (u16*)  take((size_t)MROWS * 64 * 2);           // x_proj out (64-wide)
    u16*   delta = (u16*)  take((size_t)MROWS * DINNER * 2);       // softplus(dt_proj)
    u16*   ybuf  = (u16*)  take((size_t)MROWS * DINNER * 2);       // scan out (gated)
    u16*   wip   = (u16*)  take((size_t)2 * 2 * DINNER * DMODEL * 2);
    u16*   wop   = (u16*)  take((size_t)2 * DMODEL * DINNER * 2);
    u16*   wfc1  = (u16*)  take((size_t)DMODEL * NFEAT * 2);
    float* part  = (float*)take((size_t)BATCH * 8 * DMODEL * 4);
    float* msump = (float*)take((size_t)BATCH * 8 * 4);
    float* dtsums= (float*)take((size_t)BATCH * NCHUNK * DINNER * 4);  // 2 MB
    u16*   gemb  = (u16*)delta;   // alias: gathered emb consumed before delta written
    float* states= (float*)zi;    // alias: zi dead after in_proj GEMM each layer (same 33.5MB)

    const int NOSILU = 0x7fffffff;

    // weight prep (ws re-poisoned every call, so redo each call)
    prep_weights_kernel<<<(CVT_TOTAL + 255) / 256, 256, 0, stream>>>(
        fc1w, wfc1, ipw, wip, opw, wop);
    gather_kernel<<<MROWS * (NFEAT / 4) / 256, 256, 0, stream>>>(seq, emb, gemb);

    // subg = gathered_emb @ fc1_w^T + fc1_b   (f32 out)  [256^2 8-phase]
    gemm256<0, 0><<<dim3(MROWS / 256, DMODEL / 256), 512, 0, stream>>>(
        gemb, NFEAT, wfc1, NFEAT, subg, DMODEL, fc1b, NFEAT, NOSILU);

    const int scan_blocks = (BATCH * NCHUNK * DINNER) / 256;   // 2048
    for (int i = 0; i < 2; ++i) {
        const float* al  = alog + i * DINNER * DSTATE;
        const float* cwl = cw  + i * DINNER * 4;
        const float* cbl = cbv + i * DINNER;
        rmsnorm_kernel<<<MROWS / 4, 256, 0, stream>>>(subg, nscale + i * DMODEL, zi);
        // xz = zi @ in_proj_w^T  (bf16 out; silu fused on z-half cols >= DINNER)
        gemm256<1, 0><<<dim3(MROWS / 256, 2 * DINNER / 256), 512, 0, stream>>>(
            zi, DMODEL, wip + (size_t)i * 2 * DINNER * DMODEL, DMODEL,
            xzb, 2 * DINNER, nullptr, DMODEL, DINNER);
        // x_dbl = x_proj(silu(conv(x)))  [fused conv + LDS-resident B]
        xp_conv_kernel<<<MROWS / 64, 256, 0, stream>>>(
            xzb, xpw + (size_t)i * 64 * DINNER, cwl, cbl, xdbl);
        // delta = softplus(x_dbl[:, :32] @ dtw^T + dtb)   [K=32 one-step]
        dt_kernel<<<dim3(MROWS / 64, DINNER / 256), 256, 0, stream>>>(
            xdbl, dtw + (size_t)i * DINNER * DTRANK, dtb + i * DINNER, delta);
        // chunked scan (conv inline from xzb)
        scan_p1<<<scan_blocks, 256, 0, stream>>>(delta, xzb, xdbl, cwl, cbl,
                                                 al, states, dtsums);
        scan_p2<<<scan_blocks, 256, 0, stream>>>(states, dtsums, al);
        scan_p3<<<scan_blocks, 256, 0, stream>>>(delta, xzb, xdbl, cwl, cbl, al,
                                                 Dvec + i * DINNER, states, ybuf);
        // subg += y @ out_proj_w^T  (f32 accumulate)  [256^2 8-phase]
        gemm256<0, 1><<<dim3(MROWS / 256, DMODEL / 256), 512, 0, stream>>>(
            ybuf, DINNER, wop + (size_t)i * DMODEL * DINNER, DINNER,
            subg, DMODEL, nullptr, DINNER, NOSILU);
    }

    pool_partial_kernel<<<dim3(8, BATCH), 256, 0, stream>>>(subg, incl, part, msump);
    fc2_kernel<<<BATCH, 256, 0, stream>>>(part, msump, fc2w, fc2b, outp);
}

// Round 8
// 1274.913 us; speedup vs baseline: 1.5666x; 1.0036x over previous
//
#include <hip/hip_runtime.h>
#include <cstdint>
#include <cstddef>

#define LSEQ   1024
#define BATCH  32
#define NFEAT  512
#define DMODEL 512
#define DINNER 1024
#define DSTATE 16
#define DTRANK 32
#define NCLASS 40
#define MROWS  (BATCH * LSEQ)   // 32768
#define NCHUNK 16
#define CLEN   (LSEQ / NCHUNK)  // 64

typedef unsigned short u16;
typedef __attribute__((ext_vector_type(8))) __bf16 bf16x8;
typedef __attribute__((ext_vector_type(4))) float f32x4;
typedef __attribute__((ext_vector_type(8))) unsigned short u16x8;

__device__ __forceinline__ u16 f2bf(float x) {
    union { float f; unsigned u; } v; v.f = x;
    unsigned r = v.u + 0x7fffu + ((v.u >> 16) & 1u);   // round-to-nearest-even
    return (u16)(r >> 16);
}
__device__ __forceinline__ float bf2f(u16 h) {
    union { unsigned u; float f; } v; v.u = ((unsigned)h) << 16;
    return v.f;
}

// hw-approx silu: x * rcp(1 + exp2(-x*log2e)).
__device__ __forceinline__ float silu_hw(float x) {
    float e = __builtin_amdgcn_exp2f(-1.44269504089f * x);
    return x * __builtin_amdgcn_rcpf(1.f + e);
}
// hw-approx softplus: ln2 * log2(1 + exp2(x*log2e)); branch for large x.
__device__ __forceinline__ float softplus_hw(float x) {
    if (x > 15.f) return x;
    float e = __builtin_amdgcn_exp2f(1.44269504089f * x);
    return 0.69314718056f * __builtin_amdgcn_logf(1.f + e);
}

// dA[s] = g^(s+1), s=0..15, via 4-deep multiply tree (18 muls, no trans).
__device__ __forceinline__ void pow_dA(float g, float* dA) {
    float p2 = g * g, p4 = p2 * p2, p8 = p4 * p4;
    dA[0] = g;        dA[1] = p2;       dA[2] = p2 * g;   dA[3] = p4;
    dA[4] = p4 * g;   dA[5] = p4 * p2;  dA[6] = p4 * dA[2]; dA[7] = p8;
    dA[8] = p8 * g;   dA[9] = p8 * p2;  dA[10] = p8 * dA[2]; dA[11] = p8 * p4;
    dA[12] = p8 * dA[4]; dA[13] = p8 * dA[5]; dA[14] = p8 * dA[6]; dA[15] = p8 * p8;
}

// unpack 8 bf16 (packed in uint4) -> 8 floats; scalar-friendly (shift/and)
__device__ __forceinline__ void unpack8(uint4 w, float* f) {
    union { unsigned u; float v; } c;
    c.u = w.x << 16;         f[0] = c.v;
    c.u = w.x & 0xffff0000u; f[1] = c.v;
    c.u = w.y << 16;         f[2] = c.v;
    c.u = w.y & 0xffff0000u; f[3] = c.v;
    c.u = w.z << 16;         f[4] = c.v;
    c.u = w.z & 0xffff0000u; f[5] = c.v;
    c.u = w.w << 16;         f[6] = c.v;
    c.u = w.w & 0xffff0000u; f[7] = c.v;
}

#define GLL16(g, l) __builtin_amdgcn_global_load_lds( \
    (__attribute__((address_space(1))) void*)(g),     \
    (__attribute__((address_space(3))) void*)(l), 16, 0, 0)

// ---------------------------------------------------------------------------
// 256x256 8-phase GEMM (HK-style schedule, plain HIP).  Round-4 verified
// form: runtime K, epilogue after the K-loop (no mid-loop epilogue).
// silu fused on cols >= silu_from.
// ---------------------------------------------------------------------------
template<int OUT_BF16, int ACCUM>
__global__ __launch_bounds__(512, 2) void gemm256(
    const u16* __restrict__ A, int lda,
    const u16* __restrict__ B, int ldb,
    void* __restrict__ Cv, int ldc,
    const float* __restrict__ bias, int K, int silu_from)
{
    __shared__ __align__(16) u16 As[2][256 * 64];
    __shared__ __align__(16) u16 Bs[2][256 * 64];
    const int tid  = threadIdx.x;
    const int lane = tid & 63;
    const int wave = tid >> 6;            // 0..7
    const int wr   = (wave >> 2) * 128;   // 0 or 128
    const int wc   = (wave & 3) * 64;     // 0,64,128,192
    const int frow = lane & 15;
    const int quad = lane >> 4;
    const int m0   = blockIdx.x * 256;
    const int n0   = blockIdx.y * 256;

    // staging map (constant per thread): one GLL sweep = 8KB = 64 rows
    const int srow = tid >> 3;                   // row within quarter (0..63)
    const int slb  = (tid & 7) ^ (srow & 7);     // logical 16B-block (inverse swz)
    const u16* gA = A + (size_t)(m0 + srow) * lda + slb * 8;
    const u16* gB = B + (size_t)(n0 + srow) * ldb + slb * 8;

    // read-side per-lane swizzled k-offsets (u16 units)
    const int cb0 = ((quad)     ^ (frow & 7)) * 8;   // kk=0
    const int cb1 = ((4 + quad) ^ (frow & 7)) * 8;   // kk=1

#define STAGE_A(sb, tt, q) GLL16(gA + (size_t)(q) * 64 * lda + (size_t)(tt) * 64, \
                                 &As[sb][(q) * 4096 + tid * 8])
#define STAGE_B(sb, tt, q) GLL16(gB + (size_t)(q) * 64 * ldb + (size_t)(tt) * 64, \
                                 &Bs[sb][(q) * 4096 + tid * 8])

    f32x4 acc[8][4];
#pragma unroll
    for (int i = 0; i < 8; ++i)
#pragma unroll
        for (int j = 0; j < 4; ++j) acc[i][j] = (f32x4){0.f, 0.f, 0.f, 0.f};

    const int NT = K >> 6;

    // prologue: stage tiles 0 and 1 (8 loads each), wait tile 0
#pragma unroll
    for (int q = 0; q < 4; ++q) STAGE_A(0, 0, q);
#pragma unroll
    for (int q = 0; q < 4; ++q) STAGE_B(0, 0, q);
#pragma unroll
    for (int q = 0; q < 4; ++q) STAGE_A(1, 1, q);
#pragma unroll
    for (int q = 0; q < 4; ++q) STAGE_B(1, 1, q);
    asm volatile("s_waitcnt vmcnt(8)" ::: "memory");
    __builtin_amdgcn_s_barrier();

    for (int t = 0; t < NT; ++t) {
        const int bsel = t & 1;
        const u16* __restrict__ Ab = &As[bsel][0];
        const u16* __restrict__ Bb = &Bs[bsel][0];
        const int stage = (t + 2 < NT);
        const int t2 = t + 2;
        const int rA = wr + frow;
        const int rB = wc + frow;
        bf16x8 af[4][2], b0[2][2], b1[2][2];

        // ---- P1: read af0 (M-half0) + bf0 (N-half0); stage Aq0,Aq2 ----
#pragma unroll
        for (int m = 0; m < 4; ++m) {
            const u16* p = Ab + (rA + m * 16) * 64;
            af[m][0] = *(const bf16x8*)(p + cb0);
            af[m][1] = *(const bf16x8*)(p + cb1);
        }
#pragma unroll
        for (int n = 0; n < 2; ++n) {
            const u16* p = Bb + (rB + n * 16) * 64;
            b0[n][0] = *(const bf16x8*)(p + cb0);
            b0[n][1] = *(const bf16x8*)(p + cb1);
        }
        if (stage) { STAGE_A(bsel, t2, 0); STAGE_A(bsel, t2, 2); }
        __builtin_amdgcn_s_barrier();
        asm volatile("s_waitcnt lgkmcnt(0)" ::: "memory");
        __builtin_amdgcn_sched_barrier(0);
        __builtin_amdgcn_s_setprio(1);
#pragma unroll
        for (int m = 0; m < 4; ++m)
#pragma unroll
            for (int n = 0; n < 2; ++n) {
                acc[m][n] = __builtin_amdgcn_mfma_f32_16x16x32_bf16(af[m][0], b0[n][0], acc[m][n], 0, 0, 0);
                acc[m][n] = __builtin_amdgcn_mfma_f32_16x16x32_bf16(af[m][1], b0[n][1], acc[m][n], 0, 0, 0);
            }
        __builtin_amdgcn_s_setprio(0);
        __builtin_amdgcn_s_barrier();

        // ---- P2: read bf1 (N-half1); stage Bq0,Bq1 ----
#pragma unroll
        for (int n = 0; n < 2; ++n) {
            const u16* p = Bb + (rB + 32 + n * 16) * 64;
            b1[n][0] = *(const bf16x8*)(p + cb0);
            b1[n][1] = *(const bf16x8*)(p + cb1);
        }
        if (stage) { STAGE_B(bsel, t2, 0); STAGE_B(bsel, t2, 1); }
        __builtin_amdgcn_s_barrier();
        asm volatile("s_waitcnt lgkmcnt(0)" ::: "memory");
        __builtin_amdgcn_sched_barrier(0);
        __builtin_amdgcn_s_setprio(1);
#pragma unroll
        for (int m = 0; m < 4; ++m)
#pragma unroll
            for (int n = 0; n < 2; ++n) {
                acc[m][2 + n] = __builtin_amdgcn_mfma_f32_16x16x32_bf16(af[m][0], b1[n][0], acc[m][2 + n], 0, 0, 0);
                acc[m][2 + n] = __builtin_amdgcn_mfma_f32_16x16x32_bf16(af[m][1], b1[n][1], acc[m][2 + n], 0, 0, 0);
            }
        __builtin_amdgcn_s_setprio(0);
        __builtin_amdgcn_s_barrier();

        // ---- P3: read af1 (M-half1, overwrite af regs); stage Aq1,Aq3 ----
#pragma unroll
        for (int m = 0; m < 4; ++m) {
            const u16* p = Ab + (rA + 64 + m * 16) * 64;
            af[m][0] = *(const bf16x8*)(p + cb0);
            af[m][1] = *(const bf16x8*)(p + cb1);
        }
        if (stage) { STAGE_A(bsel, t2, 1); STAGE_A(bsel, t2, 3); }
        __builtin_amdgcn_s_barrier();
        asm volatile("s_waitcnt lgkmcnt(0)" ::: "memory");
        __builtin_amdgcn_sched_barrier(0);
        __builtin_amdgcn_s_setprio(1);
#pragma unroll
        for (int m = 0; m < 4; ++m)
#pragma unroll
            for (int n = 0; n < 2; ++n) {
                acc[4 + m][2 + n] = __builtin_amdgcn_mfma_f32_16x16x32_bf16(af[m][0], b1[n][0], acc[4 + m][2 + n], 0, 0, 0);
                acc[4 + m][2 + n] = __builtin_amdgcn_mfma_f32_16x16x32_bf16(af[m][1], b1[n][1], acc[4 + m][2 + n], 0, 0, 0);
            }
        __builtin_amdgcn_s_setprio(0);
        __builtin_amdgcn_s_barrier();

        // ---- P4: no reads (bf0 live); stage Bq2,Bq3; counted vmcnt ----
        if (stage) {
            STAGE_B(bsel, t2, 2); STAGE_B(bsel, t2, 3);
            asm volatile("s_waitcnt vmcnt(8)" ::: "memory");
        } else {
            asm volatile("s_waitcnt vmcnt(0)" ::: "memory");
        }
        __builtin_amdgcn_s_barrier();
        __builtin_amdgcn_s_setprio(1);
#pragma unroll
        for (int m = 0; m < 4; ++m)
#pragma unroll
            for (int n = 0; n < 2; ++n) {
                acc[4 + m][n] = __builtin_amdgcn_mfma_f32_16x16x32_bf16(af[m][0], b0[n][0], acc[4 + m][n], 0, 0, 0);
                acc[4 + m][n] = __builtin_amdgcn_mfma_f32_16x16x32_bf16(af[m][1], b0[n][1], acc[4 + m][n], 0, 0, 0);
            }
        __builtin_amdgcn_s_setprio(0);
        __builtin_amdgcn_s_barrier();
    }
#undef STAGE_A
#undef STAGE_B

    // epilogue
    float bv[4];
#pragma unroll
    for (int n = 0; n < 4; ++n) {
        int col = n0 + wc + (n >> 1) * 32 + (n & 1) * 16 + frow;
        bv[n] = bias ? bias[col] : 0.f;
    }
#pragma unroll
    for (int m = 0; m < 8; ++m) {
        size_t row0 = (size_t)(m0 + wr + (m >> 2) * 64 + (m & 3) * 16 + quad * 4);
#pragma unroll
        for (int r = 0; r < 4; ++r) {
#pragma unroll
            for (int n = 0; n < 4; ++n) {
                int col = n0 + wc + (n >> 1) * 32 + (n & 1) * 16 + frow;
                size_t cidx = (row0 + r) * (size_t)ldc + (size_t)col;
                float v = acc[m][n][r] + bv[n];
                if (col >= silu_from) v = silu_hw(v);
                if (OUT_BF16)      ((u16*)Cv)[cidx] = f2bf(v);
                else if (ACCUM)    ((float*)Cv)[cidx] += v;
                else               ((float*)Cv)[cidx] = v;
            }
        }
    }
}

// ---------------------------------------------------------------------------
// x_dbl = x_proj( silu(conv(x)) ), conv fused into A-operand staging.
// B = x_proj_w (64x1024 f32) cvt->bf16, fully LDS-resident (128KB, XOR-swz).
// Out: xdbl[M][64] bf16 (cols: dt32 | B16 | C16).
// Block: 256 thr / 4 waves; 64 rows/block; grid M/64 = 512.
// ---------------------------------------------------------------------------
__global__ __launch_bounds__(256) void xp_conv_kernel(
    const u16* __restrict__ xz, const float* __restrict__ xpw_l,
    const float* __restrict__ cw, const float* __restrict__ cbv,
    u16* __restrict__ xdbl)
{
    __shared__ __align__(16) u16 Bs[64 * 1024];   // 128KB
    const int tid  = threadIdx.x;
    const int lane = tid & 63;
    const int wave = tid >> 6;
    const int frow = lane & 15;
    const int quad = lane >> 4;

    // stage B: thread t -> row n = t>>2, 8-elt blocks kb = (t&3)*32..+31
    {
        const int n   = tid >> 2;
        const int kb0 = (tid & 3) * 32;
        const float* src = xpw_l + (size_t)n * 1024 + (size_t)kb0 * 8;
        u16* dstrow = Bs + n * 1024;
        for (int i = 0; i < 32; ++i) {
            float4 a = ((const float4*)src)[i * 2];
            float4 b = ((const float4*)src)[i * 2 + 1];
            u16x8 o;
            o[0] = f2bf(a.x); o[1] = f2bf(a.y); o[2] = f2bf(a.z); o[3] = f2bf(a.w);
            o[4] = f2bf(b.x); o[5] = f2bf(b.y); o[6] = f2bf(b.z); o[7] = f2bf(b.w);
            int kb = kb0 + i;
            *(u16x8*)(dstrow + ((kb ^ (n & 7)) << 3)) = o;
        }
    }
    __syncthreads();

    const int r0 = blockIdx.x * 64;
    const int ra = r0 + wave * 16 + frow;            // this lane's A row
    const int l  = ra & (LSEQ - 1);
    const u16* xrow = xz + (size_t)ra * (2 * DINNER);  // x-half base
    f32x4 acc[4];
#pragma unroll
    for (int c = 0; c < 4; ++c) acc[c] = (f32x4){0.f, 0.f, 0.f, 0.f};

    for (int kk = 0; kk < 32; ++kk) {
        const int d0 = kk * 32 + quad * 8;
        u16x8 zero{};
        u16x8 t3 = *(const u16x8*)(xrow + d0);
        u16x8 t2 = (l >= 1) ? *(const u16x8*)(xrow - 2 * DINNER + d0) : zero;
        u16x8 t1 = (l >= 2) ? *(const u16x8*)(xrow - 4 * DINNER + d0) : zero;
        u16x8 t0 = (l >= 3) ? *(const u16x8*)(xrow - 6 * DINNER + d0) : zero;
        u16x8 afr;
#pragma unroll
        for (int c = 0; c < 8; ++c) {
            float4 wv = ((const float4*)cw)[d0 + c];
            float a = cbv[d0 + c]
                    + wv.x * bf2f(t0[c]) + wv.y * bf2f(t1[c])
                    + wv.z * bf2f(t2[c]) + wv.w * bf2f(t3[c]);
            afr[c] = f2bf(silu_hw(a));
        }
        bf16x8 af = *(bf16x8*)&afr;
#pragma unroll
        for (int c = 0; c < 4; ++c) {
            const int col = c * 16 + frow;
            const int kb  = (kk * 4 + quad) ^ (col & 7);
            bf16x8 bf = *(const bf16x8*)(Bs + col * 1024 + kb * 8);
            acc[c] = __builtin_amdgcn_mfma_f32_16x16x32_bf16(af, bf, acc[c], 0, 0, 0);
        }
    }
#pragma unroll
    for (int c = 0; c < 4; ++c)
#pragma unroll
        for (int r = 0; r < 4; ++r) {
            int row = r0 + wave * 16 + quad * 4 + r;
            xdbl[(size_t)row * 64 + c * 16 + frow] = f2bf(acc[c][r]);
        }
}

// ---------------------------------------------------------------------------
// delta = softplus(xdbl[:, :32] @ dtw^T + dtb).  K=32 = ONE MFMA step.
// dtw 256-col tile LDS-resident (16KB).  Grid (512, 4).
// ---------------------------------------------------------------------------
__global__ __launch_bounds__(256) void dt_kernel(
    const u16* __restrict__ xdbl, const float* __restrict__ dtw_l,
    const float* __restrict__ dtb_l, u16* __restrict__ delta)
{
    __shared__ __align__(16) u16 Bs[256 * 32];    // 16KB
    const int tid  = threadIdx.x;
    const int lane = tid & 63;
    const int wave = tid >> 6;
    const int frow = lane & 15;
    const int quad = lane >> 4;
    const int n0   = blockIdx.y * 256;
    {
        const int n = tid;                        // one 32-elt row per thread
        const float* src = dtw_l + (size_t)(n0 + n) * 32;
        u16* dstrow = Bs + n * 32;
        for (int i = 0; i < 4; ++i) {
            float4 a = ((const float4*)src)[i * 2];
            float4 b = ((const float4*)src)[i * 2 + 1];
            u16x8 o;
            o[0] = f2bf(a.x); o[1] = f2bf(a.y); o[2] = f2bf(a.z); o[3] = f2bf(a.w);
            o[4] = f2bf(b.x); o[5] = f2bf(b.y); o[6] = f2bf(b.z); o[7] = f2bf(b.w);
            *(u16x8*)(dstrow + ((i ^ (n & 3)) << 3)) = o;
        }
    }
    __syncthreads();

    const int r0 = blockIdx.x * 64 + wave * 16;
    bf16x8 af = *(const bf16x8*)(xdbl + (size_t)(r0 + frow) * 64 + quad * 8);
    f32x4 acc[16];
#pragma unroll
    for (int c = 0; c < 16; ++c) acc[c] = (f32x4){0.f, 0.f, 0.f, 0.f};
#pragma unroll
    for (int c = 0; c < 16; ++c) {
        const int col = c * 16 + frow;
        const int kb  = quad ^ (col & 3);
        bf16x8 bf = *(const bf16x8*)(Bs + col * 32 + kb * 8);
        acc[c] = __builtin_amdgcn_mfma_f32_16x16x32_bf16(af, bf, acc[c], 0, 0, 0);
    }
#pragma unroll
    for (int c = 0; c < 16; ++c) {
        float bv = dtb_l[n0 + c * 16 + frow];
#pragma unroll
        for (int r = 0; r < 4; ++r) {
            int row = r0 + quad * 4 + r;
            float v = softplus_hw(acc[c][r] + bv);
            delta[(size_t)row * DINNER + n0 + c * 16 + frow] = f2bf(v);
        }
    }
}

// --------------------------- elementwise / prep ----------------------------

// merged f32->bf16 weight conversion: fc1 | ip | op ranges (float4 units)
#define CVT_N_FC1 65536      // 512*512/4
#define CVT_N_IP  524288     // 2*2048*512/4
#define CVT_N_OP  262144     // 2*512*1024/4
#define CVT_TOTAL (CVT_N_FC1 + CVT_N_IP + CVT_N_OP)

__global__ __launch_bounds__(256) void prep_weights_kernel(
    const float* __restrict__ fc1w, u16* __restrict__ wfc1,
    const float* __restrict__ ipw,  u16* __restrict__ wip,
    const float* __restrict__ opw,  u16* __restrict__ wop)
{
    int i = blockIdx.x * 256 + threadIdx.x;
    if (i >= CVT_TOTAL) return;
    const float* src; u16* dst; int j = i;
    if (j < CVT_N_FC1)                    { src = fc1w; dst = wfc1; }
    else if ((j -= CVT_N_FC1) < CVT_N_IP) { src = ipw;  dst = wip;  }
    else { j -= CVT_N_IP;                   src = opw;  dst = wop;  }
    float4 v = ((const float4*)src)[j];
    ushort4 o; o.x = f2bf(v.x); o.y = f2bf(v.y); o.z = f2bf(v.z); o.w = f2bf(v.w);
    ((ushort4*)dst)[j] = o;
}

// gathered_emb[m,:] = bf16(embeddings[sequence[m],:])
__global__ __launch_bounds__(256) void gather_kernel(
    const int* __restrict__ seq, const float* __restrict__ emb, u16* __restrict__ g)
{
    int i   = blockIdx.x * 256 + threadIdx.x;  // per float4; total MROWS*128
    int row = i >> 7, c = i & 127;
    int node = seq[row];
    float4 v = ((const float4*)(emb + (size_t)node * NFEAT))[c];
    ushort4 o; o.x = f2bf(v.x); o.y = f2bf(v.y); o.z = f2bf(v.z); o.w = f2bf(v.w);
    ((ushort4*)g)[i] = o;
}

// zi = scale * x / (||x||/sqrt(512) + 1e-8), one wave per row
__global__ __launch_bounds__(256) void rmsnorm_kernel(
    const float* __restrict__ x, const float* __restrict__ scale, u16* __restrict__ o)
{
    int wave = threadIdx.x >> 6, lane = threadIdx.x & 63;
    size_t row = (size_t)blockIdx.x * 4 + wave;
    const float4* xr = (const float4*)(x + row * DMODEL);
    float4 v0 = xr[lane], v1 = xr[lane + 64];
    float ss = v0.x*v0.x + v0.y*v0.y + v0.z*v0.z + v0.w*v0.w
             + v1.x*v1.x + v1.y*v1.y + v1.z*v1.z + v1.w*v1.w;
#pragma unroll
    for (int off = 32; off; off >>= 1) ss += __shfl_xor(ss, off, 64);
    float inv = 1.f / (sqrtf(ss * (1.f / DMODEL)) + 1e-8f);
    const float4* sc = (const float4*)scale;
    float4 s0 = sc[lane], s1 = sc[lane + 64];
    ushort4 o0, o1;
    o0.x = f2bf(v0.x * s0.x * inv); o0.y = f2bf(v0.y * s0.y * inv);
    o0.z = f2bf(v0.z * s0.z * inv); o0.w = f2bf(v0.w * s0.w * inv);
    o1.x = f2bf(v1.x * s1.x * inv); o1.y = f2bf(v1.y * s1.y * inv);
    o1.z = f2bf(v1.z * s1.z * inv); o1.w = f2bf(v1.w * s1.w * inv);
    ushort4* op = (ushort4*)(o + row * DMODEL);
    op[lane] = o0; op[lane + 64] = o1;
}

// ---------------------------------------------------------------------------
// Chunked selective scan; conv+silu computed INLINE from xzb (3-reg rolling
// window) -- xconv is never materialized.
// ---------------------------------------------------------------------------
__device__ __forceinline__ int detect_s4d(const float* a2) {
    int fast = 1;
#pragma unroll
    for (int s = 1; s < DSTATE; ++s)
        fast &= (__builtin_fabsf(a2[s] - (float)(s + 1) * a2[0]) <=
                 1e-4f * (float)(s + 1) * __builtin_fabsf(a2[0]) + 1e-6f);
    return fast;
}

__global__ __launch_bounds__(256) void scan_p1(
    const u16* __restrict__ delta, const u16* __restrict__ xz,
    const u16* __restrict__ xdbl, const float* __restrict__ cw,
    const float* __restrict__ cbv, const float* __restrict__ alog,
    float* __restrict__ states, float* __restrict__ dtsums)
{
    const int bid = blockIdx.x;
    const int d0  = (bid & 3) << 8;
    const int k   = (bid >> 2) & (NCHUNK - 1);
    const int b   = bid >> 6;
    const int d   = d0 + threadIdx.x;

    float a2[DSTATE];
#pragma unroll
    for (int s = 0; s < DSTATE; ++s)
        a2[s] = -expf(alog[d * DSTATE + s]) * 1.44269504f;
    const int fastA = detect_s4d(a2);
    const float ab = a2[0];
    const float4 wcv = ((const float4*)cw)[d];
    const float cb = cbv[d];

    float h[DSTATE];
#pragma unroll
    for (int s = 0; s < DSTATE; ++s) h[s] = 0.f;
    float dtsum = 0.f;

    const size_t r0 = (size_t)b * LSEQ + (size_t)k * CLEN;
    const u16* pd  = delta + r0 * DINNER + d;
    const u16* pxz = xz + r0 * (2 * DINNER) + d;
    const unsigned* pB = (const unsigned*)(xdbl + r0 * 64) + 16;  // uniform

    // conv window (rows before chunk start; zero only for k==0)
    float xm3 = (k > 0) ? bf2f(pxz[-6 * DINNER]) : 0.f;
    float xm2 = (k > 0) ? bf2f(pxz[-4 * DINNER]) : 0.f;
    float xm1 = (k > 0) ? bf2f(pxz[-2 * DINNER]) : 0.f;

    float dt = bf2f(*pd), xraw = bf2f(*pxz);
    uint4 wB  = *(const uint4*)(pB);
    uint4 wB2 = *(const uint4*)(pB + 4);

    if (fastA) {
        for (int j = 0; j < CLEN; ++j) {
            pd += DINNER; pxz += 2 * DINNER; pB += 32;
            float dt_n = bf2f(*pd), xraw_n = bf2f(*pxz);
            uint4 wBn  = *(const uint4*)(pB);
            uint4 wB2n = *(const uint4*)(pB + 4);
            float xc = silu_hw(cb + wcv.x * xm3 + wcv.y * xm2
                             + wcv.z * xm1 + wcv.w * xraw);
            xm3 = xm2; xm2 = xm1; xm1 = xraw;
            float dx = dt * xc;
            dtsum += dt;
            float dA[DSTATE];
            pow_dA(__builtin_amdgcn_exp2f(dt * ab), dA);
            float Bv[DSTATE];
            unpack8(wB, Bv); unpack8(wB2, Bv + 8);
#pragma unroll
            for (int s = 0; s < DSTATE; ++s)
                h[s] = __builtin_fmaf(h[s], dA[s], dx * Bv[s]);
            dt = dt_n; xraw = xraw_n; wB = wBn; wB2 = wB2n;
        }
    } else {
        for (int j = 0; j < CLEN; ++j) {
            pd += DINNER; pxz += 2 * DINNER; pB += 32;
            float dt_n = bf2f(*pd), xraw_n = bf2f(*pxz);
            uint4 wBn  = *(const uint4*)(pB);
            uint4 wB2n = *(const uint4*)(pB + 4);
            float xc = silu_hw(cb + wcv.x * xm3 + wcv.y * xm2
                             + wcv.z * xm1 + wcv.w * xraw);
            xm3 = xm2; xm2 = xm1; xm1 = xraw;
            float dx = dt * xc;
            dtsum += dt;
            float Bv[DSTATE];
            unpack8(wB, Bv); unpack8(wB2, Bv + 8);
#pragma unroll
            for (int s = 0; s < DSTATE; ++s)
                h[s] = __builtin_fmaf(h[s], __builtin_amdgcn_exp2f(dt * a2[s]),
                                      dx * Bv[s]);
            dt = dt_n; xraw = xraw_n; wB = wBn; wB2 = wB2n;
        }
    }

    size_t t = (size_t)(b * NCHUNK + k) * DINNER + d;
    f32x4* st = (f32x4*)(states + t * DSTATE);
#pragma unroll
    for (int q = 0; q < 4; ++q)
        st[q] = (f32x4){h[q * 4], h[q * 4 + 1], h[q * 4 + 2], h[q * 4 + 3]};
    dtsums[t] = dtsum;
}

__global__ __launch_bounds__(256) void scan_p2(
    float* __restrict__ states, const float* __restrict__ dtsums,
    const float* __restrict__ alog)
{
    int t = blockIdx.x * 256 + threadIdx.x;   // 0 .. B*DINNER*DSTATE-1
    int s = t & (DSTATE - 1);
    int d = (t >> 4) & (DINNER - 1);
    int b = t >> 14;
    float a2 = -expf(alog[d * DSTATE + s]) * 1.44269504f;
    float H = 0.f;
    for (int k = 0; k < NCHUNK; ++k) {
        size_t ci = ((size_t)b * NCHUNK + k) * DINNER + d;
        size_t idx = ci * DSTATE + s;
        float hk = states[idx];
        float P = __builtin_amdgcn_exp2f(a2 * dtsums[ci]);
        states[idx] = H;                 // exclusive incoming state for chunk k
        H = hk + P * H;
    }
}

__global__ __launch_bounds__(256) void scan_p3(
    const u16* __restrict__ delta, const u16* __restrict__ xz,
    const u16* __restrict__ xdbl, const float* __restrict__ cw,
    const float* __restrict__ cbv, const float* __restrict__ alog,
    const float* __restrict__ Dvec, const float* __restrict__ states,
    u16* __restrict__ ybuf)
{
    const int bid = blockIdx.x;
    const int d0  = (bid & 3) << 8;
    const int k   = (bid >> 2) & (NCHUNK - 1);
    const int b   = bid >> 6;
    const int d   = d0 + threadIdx.x;

    float a2[DSTATE];
#pragma unroll
    for (int s = 0; s < DSTATE; ++s)
        a2[s] = -expf(alog[d * DSTATE + s]) * 1.44269504f;
    const int fastA = detect_s4d(a2);
    const float ab = a2[0];
    const float Dd = Dvec[d];
    const float4 wcv = ((const float4*)cw)[d];
    const float cb = cbv[d];

    float h[DSTATE];
    size_t t = (size_t)(b * NCHUNK + k) * DINNER + d;
    const f32x4* st = (const f32x4*)(states + t * DSTATE);
#pragma unroll
    for (int q = 0; q < 4; ++q) {
        f32x4 v = st[q];
        h[q * 4] = v[0]; h[q * 4 + 1] = v[1]; h[q * 4 + 2] = v[2]; h[q * 4 + 3] = v[3];
    }

    const size_t r0 = (size_t)b * LSEQ + (size_t)k * CLEN;
    const u16* pd  = delta + r0 * DINNER + d;
    const u16* pxz = xz + r0 * (2 * DINNER) + d;
    const u16* pz  = xz + r0 * (2 * DINNER) + DINNER + d;
    const unsigned* pB = (const unsigned*)(xdbl + r0 * 64) + 16;  // uniform
    u16* py = ybuf + r0 * DINNER + d;

    float xm3 = (k > 0) ? bf2f(pxz[-6 * DINNER]) : 0.f;
    float xm2 = (k > 0) ? bf2f(pxz[-4 * DINNER]) : 0.f;
    float xm1 = (k > 0) ? bf2f(pxz[-2 * DINNER]) : 0.f;

    float dt = bf2f(*pd), xraw = bf2f(*pxz), zs = bf2f(*pz);
    uint4 wB  = *(const uint4*)(pB);
    uint4 wB2 = *(const uint4*)(pB + 4);
    uint4 wC  = *(const uint4*)(pB + 8);
    uint4 wC2 = *(const uint4*)(pB + 12);

    if (fastA) {
        for (int j = 0; j < CLEN; ++j) {
            pd += DINNER; pxz += 2 * DINNER; pz += 2 * DINNER; pB += 32;
            float dt_n = bf2f(*pd), xraw_n = bf2f(*pxz), zs_n = bf2f(*pz);
            uint4 wBn  = *(const uint4*)(pB);
            uint4 wB2n = *(const uint4*)(pB + 4);
            uint4 wCn  = *(const uint4*)(pB + 8);
            uint4 wC2n = *(const uint4*)(pB + 12);
            float xc = silu_hw(cb + wcv.x * xm3 + wcv.y * xm2
                             + wcv.z * xm1 + wcv.w * xraw);
            xm3 = xm2; xm2 = xm1; xm1 = xraw;
            float dx = dt * xc;
            float dA[DSTATE];
            pow_dA(__builtin_amdgcn_exp2f(dt * ab), dA);
            float Bv[DSTATE], Cv[DSTATE];
            unpack8(wB, Bv); unpack8(wB2, Bv + 8);
            unpack8(wC, Cv); unpack8(wC2, Cv + 8);
            float y0 = 0.f, y1 = 0.f, y2 = 0.f, y3 = 0.f;
#pragma unroll
            for (int s = 0; s < DSTATE; ++s)
                h[s] = __builtin_fmaf(h[s], dA[s], dx * Bv[s]);
#pragma unroll
            for (int s = 0; s < DSTATE; s += 4) {
                y0 = __builtin_fmaf(h[s],     Cv[s],     y0);
                y1 = __builtin_fmaf(h[s + 1], Cv[s + 1], y1);
                y2 = __builtin_fmaf(h[s + 2], Cv[s + 2], y2);
                y3 = __builtin_fmaf(h[s + 3], Cv[s + 3], y3);
            }
            float yv = ((y0 + y1) + (y2 + y3)) + Dd * xc;
            *py = f2bf(yv * zs); py += DINNER;
            dt = dt_n; xraw = xraw_n; zs = zs_n;
            wB = wBn; wB2 = wB2n; wC = wCn; wC2 = wC2n;
        }
    } else {
        for (int j = 0; j < CLEN; ++j) {
            pd += DINNER; pxz += 2 * DINNER; pz += 2 * DINNER; pB += 32;
            float dt_n = bf2f(*pd), xraw_n = bf2f(*pxz), zs_n = bf2f(*pz);
            uint4 wBn  = *(const uint4*)(pB);
            uint4 wB2n = *(const uint4*)(pB + 4);
            uint4 wCn  = *(const uint4*)(pB + 8);
            uint4 wC2n = *(const uint4*)(pB + 12);
            float xc = silu_hw(cb + wcv.x * xm3 + wcv.y * xm2
                             + wcv.z * xm1 + wcv.w * xraw);
            xm3 = xm2; xm2 = xm1; xm1 = xraw;
            float dx = dt * xc;
            float Bv[DSTATE], Cv[DSTATE];
            unpack8(wB, Bv); unpack8(wB2, Bv + 8);
            unpack8(wC, Cv); unpack8(wC2, Cv + 8);
            float y0 = 0.f, y1 = 0.f, y2 = 0.f, y3 = 0.f;
#pragma unroll
            for (int s = 0; s < DSTATE; ++s) {
                h[s] = __builtin_fmaf(h[s], __builtin_amdgcn_exp2f(dt * a2[s]),
                                      dx * Bv[s]);
            }
#pragma unroll
            for (int s = 0; s < DSTATE; s += 4) {
                y0 = __builtin_fmaf(h[s],     Cv[s],     y0);
                y1 = __builtin_fmaf(h[s + 1], Cv[s + 1], y1);
                y2 = __builtin_fmaf(h[s + 2], Cv[s + 2], y2);
                y3 = __builtin_fmaf(h[s + 3], Cv[s + 3], y3);
            }
            float yv = ((y0 + y1) + (y2 + y3)) + Dd * xc;
            *py = f2bf(yv * zs); py += DINNER;
            dt = dt_n; xraw = xraw_n; zs = zs_n;
            wB = wBn; wB2 = wB2n; wC = wCn; wC2 = wC2n;
        }
    }
}

// masked-mean partials: grid (8 chunks, 32 b)
__global__ __launch_bounds__(256) void pool_partial_kernel(
    const float* __restrict__ subg, const float* __restrict__ incl,
    float* __restrict__ part, float* __restrict__ msump)
{
    int chunk = blockIdx.x, b = blockIdx.y, tid = threadIdx.x;
    float a0 = 0.f, a1 = 0.f, ms = 0.f;
    for (int l0 = 0; l0 < 128; ++l0) {
        int l = chunk * 128 + l0;
        float m = incl[b * LSEQ + l];
        const float* row = subg + ((size_t)b * LSEQ + l) * DMODEL;
        a0 += m * row[tid];
        a1 += m * row[tid + 256];
        ms += m;
    }
    int pi = (b * 8 + chunk) * DMODEL;
    part[pi + tid] = a0;
    part[pi + tid + 256] = a1;
    if (tid == 0) msump[b * 8 + chunk] = ms;
}

__global__ __launch_bounds__(256) void fc2_kernel(
    const float* __restrict__ part, const float* __restrict__ msump,
    const float* __restrict__ fc2w, const float* __restrict__ fc2b,
    float* __restrict__ out)
{
    int b = blockIdx.x, tid = threadIdx.x;
    __shared__ float pooled[DMODEL];
    float s0 = 0.f, s1 = 0.f, ms = 0.f;
#pragma unroll
    for (int c = 0; c < 8; ++c) {
        s0 += part[(b * 8 + c) * DMODEL + tid];
        s1 += part[(b * 8 + c) * DMODEL + tid + 256];
        ms += msump[b * 8 + c];
    }
    float inv = 1.f / (ms + 1e-5f);
    pooled[tid] = s0 * inv; pooled[tid + 256] = s1 * inv;
    __syncthreads();
    int wave = tid >> 6, lane = tid & 63;
    for (int c = wave; c < NCLASS; c += 4) {
        float s = 0.f;
#pragma unroll
        for (int k = lane; k < DMODEL; k += 64) s += pooled[k] * fc2w[c * DMODEL + k];
#pragma unroll
        for (int off = 32; off; off >>= 1) s += __shfl_xor(s, off, 64);
        if (lane == 0) out[b * NCLASS + c] = s + fc2b[c];
    }
}

// ---------------------------------------------------------------------------

extern "C" void kernel_launch(void* const* d_in, const int* in_sizes, int n_in,
                              void* d_out, int out_size, void* d_ws, size_t ws_size,
                              hipStream_t stream)
{
    (void)in_sizes; (void)n_in; (void)out_size; (void)ws_size;
    const int*   seq    = (const int*)  d_in[0];
    const float* incl   = (const float*)d_in[1];
    const float* emb    = (const float*)d_in[2];
    const float* fc1w   = (const float*)d_in[3];
    const float* fc1b   = (const float*)d_in[4];
    const float* fc2w   = (const float*)d_in[5];
    const float* fc2b   = (const float*)d_in[6];
    const float* nscale = (const float*)d_in[7];
    const float* ipw    = (const float*)d_in[8];
    const float* cw     = (const float*)d_in[9];
    const float* cbv    = (const float*)d_in[10];
    const float* xpw    = (const float*)d_in[11];
    const float* dtw    = (const float*)d_in[12];
    const float* dtb    = (const float*)d_in[13];
    const float* alog   = (const float*)d_in[14];
    const float* Dvec   = (const float*)d_in[15];
    const float* opw    = (const float*)d_in[16];
    float* outp = (float*)d_out;

    char* w = (char*)d_ws;
    size_t off = 0;
    auto take = [&](size_t bytes) {
        char* p = w + off; off += (bytes + 255) & ~(size_t)255; return p;
    };
    float* subg  = (float*)take((size_t)MROWS * DMODEL * 4);       // fp32 residual stream
    u16*   zi    = (u16*)  take((size_t)MROWS * DMODEL * 2);       // rmsnorm out (33.5MB)
    u16*   xzb   = (u16*)  take((size_t)MROWS * 2 * DINNER * 2);   // in_proj out (xin|silu(z))
    u16*   xdbl  = (u16*)  take((size_t)MROWS * 64 * 2);           // x_proj out (64-wide)
    u16*   delta = (u16*)  take((size_t)MROWS * DINNER * 2);       // softplus(dt_proj)
    u16*   ybuf  = (u16*)  take((size_t)MROWS * DINNER * 2);       // scan out (gated)
    u16*   wip   = (u16*)  take((size_t)2 * 2 * DINNER * DMODEL * 2);
    u16*   wop   = (u16*)  take((size_t)2 * DMODEL * DINNER * 2);
    u16*   wfc1  = (u16*)  take((size_t)DMODEL * NFEAT * 2);
    float* part  = (float*)take((size_t)BATCH * 8 * DMODEL * 4);
    float* msump = (float*)take((size_t)BATCH * 8 * 4);
    float* dtsums= (float*)take((size_t)BATCH * NCHUNK * DINNER * 4);  // 2 MB
    u16*   gemb  = (u16*)delta;   // alias: gathered emb consumed before delta written
    float* states= (float*)zi;    // alias: zi dead after in_proj GEMM each layer (same 33.5MB)

    const int NOSILU = 0x7fffffff;

    // weight prep (ws re-poisoned every call, so redo each call)
    prep_weights_kernel<<<(CVT_TOTAL + 255) / 256, 256, 0, stream>>>(
        fc1w, wfc1, ipw, wip, opw, wop);
    gather_kernel<<<MROWS * (NFEAT / 4) / 256, 256, 0, stream>>>(seq, emb, gemb);

    // subg = gathered_emb @ fc1_w^T + fc1_b   (f32 out)  [256^2 8-phase]
    gemm256<0, 0><<<dim3(MROWS / 256, DMODEL / 256), 512, 0, stream>>>(
        gemb, NFEAT, wfc1, NFEAT, subg, DMODEL, fc1b, NFEAT, NOSILU);

    const int scan_blocks = (BATCH * NCHUNK * DINNER) / 256;   // 2048
    for (int i = 0; i < 2; ++i) {
        const float* al  = alog + i * DINNER * DSTATE;
        const float* cwl = cw  + i * DINNER * 4;
        const float* cbl = cbv + i * DINNER;
        rmsnorm_kernel<<<MROWS / 4, 256, 0, stream>>>(subg, nscale + i * DMODEL, zi);
        // xz = zi @ in_proj_w^T  (bf16 out; silu fused on z-half cols >= DINNER)
        gemm256<1, 0><<<dim3(MROWS / 256, 2 * DINNER / 256), 512, 0, stream>>>(
            zi, DMODEL, wip + (size_t)i * 2 * DINNER * DMODEL, DMODEL,
            xzb, 2 * DINNER, nullptr, DMODEL, DINNER);
        // x_dbl = x_proj(silu(conv(x)))  [fused conv + LDS-resident B]
        xp_conv_kernel<<<MROWS / 64, 256, 0, stream>>>(
            xzb, xpw + (size_t)i * 64 * DINNER, cwl, cbl, xdbl);
        // delta = softplus(x_dbl[:, :32] @ dtw^T + dtb)   [K=32 one-step]
        dt_kernel<<<dim3(MROWS / 64, DINNER / 256), 256, 0, stream>>>(
            xdbl, dtw + (size_t)i * DINNER * DTRANK, dtb + i * DINNER, delta);
        // chunked scan (conv inline from xzb)
        scan_p1<<<scan_blocks, 256, 0, stream>>>(delta, xzb, xdbl, cwl, cbl,
                                                 al, states, dtsums);
        scan_p2<<<scan_blocks, 256, 0, stream>>>(states, dtsums, al);
        scan_p3<<<scan_blocks, 256, 0, stream>>>(delta, xzb, xdbl, cwl, cbl, al,
                                                 Dvec + i * DINNER, states, ybuf);
        // subg += y @ out_proj_w^T  (f32 accumulate)  [256^2 8-phase]
        gemm256<0, 1><<<dim3(MROWS / 256, DMODEL / 256), 512, 0, stream>>>(
            ybuf, DINNER, wop + (size_t)i * DMODEL * DINNER, DINNER,
            subg, DMODEL, nullptr, DINNER, NOSILU);
    }

    pool_partial_kernel<<<dim3(8, BATCH), 256, 0, stream>>>(subg, incl, part, msump);
    fc2_kernel<<<BATCH, 256, 0, stream>>>(part, msump, fc2w, fc2b, outp);
}